// Round 3
// baseline (12217.546 us; speedup 1.0000x reference)
//
#include <hip/hip_runtime.h>
#include <hip/hip_bf16.h>

typedef __hip_bfloat16 bf16;

// Problem constants
constexpr int kB = 16;    // batch
constexpr int kN = 2048;  // points
constexpr int kF = 1024;  // feat dims
constexpr int kC = 256;   // channels
constexpr int kH = 64;    // head dim

__device__ __forceinline__ float us2f(unsigned short u) {
  union { unsigned int i; float f; } w;
  w.i = ((unsigned int)u) << 16;
  return w.f;
}
__device__ __forceinline__ unsigned short f2bu(float f) {
  union { bf16 h; unsigned short s; } u;
  u.h = __float2bfloat16(f);
  return u.s;
}

// ---------------------------------------------------------------------------
// fb[b,c] = mlp_b[c] + sum_f mlp_w[c,f] * feature[b,f]
// ---------------------------------------------------------------------------
__global__ __launch_bounds__(256) void k_fb(const float* __restrict__ feat,
                                            const float* __restrict__ mlp_w,
                                            const float* __restrict__ mlp_b,
                                            float* __restrict__ fb) {
  const int b = blockIdx.x >> 8;
  const int c = blockIdx.x & 255;
  const int t = threadIdx.x;
  const float* wr = mlp_w + (size_t)c * (kF + 3);
  const float* fr = feat + (size_t)b * kF;
  float s = 0.f;
  for (int f = t; f < kF; f += 256) s += wr[f] * fr[f];
  __shared__ float red[256];
  red[t] = s;
  __syncthreads();
  for (int k = 128; k > 0; k >>= 1) {
    if (t < k) red[t] += red[t + k];
    __syncthreads();
  }
  if (t == 0) fb[blockIdx.x] = red[0] + mlp_b[c];
}

// ---------------------------------------------------------------------------
// p[b,c,n] = fb[b,c] + sum_{j<3} mlp_w[c,1024+j] * prior[b,j,n]   (fp32)
// ---------------------------------------------------------------------------
__global__ __launch_bounds__(256) void k_p0(const float* __restrict__ prior,
                                            const float* __restrict__ mlp_w,
                                            const float* __restrict__ fb,
                                            float* __restrict__ p) {
  const size_t i = (size_t)blockIdx.x * 256 + threadIdx.x;  // over B*C*N
  const int n = (int)(i % kN);
  const size_t bc = i / kN;
  const int b = (int)(bc / kC);
  const int c = (int)(bc % kC);
  const float* pr = prior + (size_t)b * 3 * kN + n;
  const float* wr = mlp_w + (size_t)c * (kF + 3) + kF;
  p[i] = fb[bc] + wr[0] * pr[0] + wr[1] * pr[kN] + wr[2] * pr[2 * kN];
}

// ---------------------------------------------------------------------------
// Full-column 1x1 conv: y[b,o,n] = bias[o] + sum_{c<256} w[o,c]*x[b,c,n]
// Block owns 32 n for ALL O outputs; X panel resident in LDS (in-place safe).
// OMODE: 0 = fp32 transposed [b][n][64] (Q); 1 = bf16 [b][o][N] (V);
//        2 = fp32 [b][o][N] (T-conv, y may alias x); 3 = fp32 accumulate.
// ---------------------------------------------------------------------------
template <int O, int OMODE>
__global__ __launch_bounds__(256) void k_fc(const float* __restrict__ x,
                                            const float* __restrict__ w, int wstride,
                                            const float* __restrict__ bias,
                                            void* __restrict__ yv, int first) {
  constexpr int OT = O / 16;  // outputs per thread (16 or 4)
  __shared__ float Xs[32][257];
  __shared__ float Ws[16][O];
  const int t = threadIdx.x;
  const int b = blockIdx.y;
  const int n0 = blockIdx.x * 32;
  const float* xb = x + (size_t)b * kC * kN + n0;
  {  // load X panel [256c][32n] -> Xs[n][c]
    const int n4 = t & 7;
    const int cg = t >> 3;
#pragma unroll
    for (int it = 0; it < 8; ++it) {
      const int c = it * 32 + cg;
      const float4 v = *(const float4*)(xb + (size_t)c * kN + n4 * 4);
      Xs[n4 * 4 + 0][c] = v.x;
      Xs[n4 * 4 + 1][c] = v.y;
      Xs[n4 * 4 + 2][c] = v.z;
      Xs[n4 * 4 + 3][c] = v.w;
    }
  }
  const int tn = t & 15, to = t >> 4;
  float acc[OT][2] = {};
  for (int c0 = 0; c0 < kC; c0 += 16) {
    __syncthreads();  // protect Ws from previous chunk's readers
    if (O == 256) {
      const float* wr = w + (size_t)t * wstride + c0;
      const float4 a = *(const float4*)(wr);
      const float4 b4 = *(const float4*)(wr + 4);
      const float4 c4 = *(const float4*)(wr + 8);
      const float4 d4 = *(const float4*)(wr + 12);
      Ws[0][t] = a.x;  Ws[1][t] = a.y;  Ws[2][t] = a.z;  Ws[3][t] = a.w;
      Ws[4][t] = b4.x; Ws[5][t] = b4.y; Ws[6][t] = b4.z; Ws[7][t] = b4.w;
      Ws[8][t] = c4.x; Ws[9][t] = c4.y; Ws[10][t] = c4.z; Ws[11][t] = c4.w;
      Ws[12][t] = d4.x; Ws[13][t] = d4.y; Ws[14][t] = d4.z; Ws[15][t] = d4.w;
    } else if (t < O) {
      const float* wr = w + (size_t)t * wstride + c0;
      const float4 a = *(const float4*)(wr);
      const float4 b4 = *(const float4*)(wr + 4);
      const float4 c4 = *(const float4*)(wr + 8);
      const float4 d4 = *(const float4*)(wr + 12);
      Ws[0][t] = a.x;  Ws[1][t] = a.y;  Ws[2][t] = a.z;  Ws[3][t] = a.w;
      Ws[4][t] = b4.x; Ws[5][t] = b4.y; Ws[6][t] = b4.z; Ws[7][t] = b4.w;
      Ws[8][t] = c4.x; Ws[9][t] = c4.y; Ws[10][t] = c4.z; Ws[11][t] = c4.w;
      Ws[12][t] = d4.x; Ws[13][t] = d4.y; Ws[14][t] = d4.z; Ws[15][t] = d4.w;
    }
    __syncthreads();
#pragma unroll
    for (int cc = 0; cc < 16; ++cc) {
      const float xa = Xs[2 * tn + 0][c0 + cc];
      const float xc2 = Xs[2 * tn + 1][c0 + cc];
#pragma unroll
      for (int q = 0; q < OT / 4; ++q) {
        const float4 wv = *(const float4*)&Ws[cc][to * OT + q * 4];
        acc[q * 4 + 0][0] += wv.x * xa; acc[q * 4 + 0][1] += wv.x * xc2;
        acc[q * 4 + 1][0] += wv.y * xa; acc[q * 4 + 1][1] += wv.y * xc2;
        acc[q * 4 + 2][0] += wv.z * xa; acc[q * 4 + 2][1] += wv.z * xc2;
        acc[q * 4 + 3][0] += wv.w * xa; acc[q * 4 + 3][1] += wv.w * xc2;
      }
    }
  }
  const int n = n0 + 2 * tn;
  if (OMODE == 0) {  // Q fp32 transposed [b][n][64]
    float* y = (float*)yv;
#pragma unroll
    for (int i = 0; i < OT; ++i) {
      const int o = to * OT + i;
      const float bz = bias[o];
      y[((size_t)b * kN + n + 0) * kH + o] = acc[i][0] + bz;
      y[((size_t)b * kN + n + 1) * kH + o] = acc[i][1] + bz;
    }
  } else if (OMODE == 1) {  // V bf16 [b][o][N]
    bf16* y = (bf16*)yv;
#pragma unroll
    for (int i = 0; i < OT; ++i) {
      const int o = to * OT + i;
      const float bz = bias[o];
      ushort2 u2;
      u2.x = f2bu(acc[i][0] + bz);
      u2.y = f2bu(acc[i][1] + bz);
      *(ushort2*)(y + ((size_t)b * kC + o) * kN + n) = u2;
    }
  } else if (OMODE == 2) {  // fp32 [b][o][N], may alias x (panel is in LDS)
    float* y = (float*)yv;
#pragma unroll
    for (int i = 0; i < OT; ++i) {
      const int o = to * OT + i;
      const float bz = bias[o];
      *(float2*)(y + ((size_t)b * kC + o) * kN + n) =
          make_float2(acc[i][0] + bz, acc[i][1] + bz);
    }
  } else {  // fp32 accumulate (dc1)
    float* y = (float*)yv;
#pragma unroll
    for (int i = 0; i < OT; ++i) {
      const int o = to * OT + i;
      float2* p2 = (float2*)(y + ((size_t)b * kC + o) * kN + n);
      if (first) {
        *p2 = make_float2(acc[i][0], acc[i][1]);
      } else {
        const float2 old = *p2;
        *p2 = make_float2(old.x + acc[i][0], old.y + acc[i][1]);
      }
    }
  }
}

// ---------------------------------------------------------------------------
// Row softmax stats: e[n,m] = Q[n]·Q[m]; per row n: rmx = max, rsn = 1/sum exp
// ---------------------------------------------------------------------------
__global__ __launch_bounds__(256) void k_rowstats(const float* __restrict__ Q,
                                                  float* __restrict__ rmx,
                                                  float* __restrict__ rsn) {
  const int b = blockIdx.y, t = threadIdx.x;
  const int r = t >> 4, ml = t & 15;
  const int row = blockIdx.x * 16 + r;
  const float* Qb_ = Q + (size_t)b * kN * kH;
  float qr[kH];
  {
    const float4* qp = (const float4*)(Qb_ + (size_t)row * kH);
#pragma unroll
    for (int h4 = 0; h4 < kH / 4; ++h4) {
      const float4 v = qp[h4];
      qr[4 * h4] = v.x; qr[4 * h4 + 1] = v.y; qr[4 * h4 + 2] = v.z; qr[4 * h4 + 3] = v.w;
    }
  }
  float mx = -3.0e38f, s = 0.f;
  for (int m = ml; m < kN; m += 16) {
    const float4* qp = (const float4*)(Qb_ + (size_t)m * kH);
    float e = 0.f;
#pragma unroll
    for (int h4 = 0; h4 < kH / 4; ++h4) {
      const float4 v = qp[h4];
      e += qr[4 * h4] * v.x + qr[4 * h4 + 1] * v.y + qr[4 * h4 + 2] * v.z + qr[4 * h4 + 3] * v.w;
    }
    if (e <= mx) {
      s += __expf(e - mx);
    } else {
      s = s * __expf(mx - e) + 1.f;
      mx = e;
    }
  }
#pragma unroll
  for (int mask = 1; mask < 16; mask <<= 1) {
    const float om = __shfl_xor(mx, mask);
    const float os = __shfl_xor(s, mask);
    const float nm = fmaxf(mx, om);
    s = s * __expf(mx - nm) + os * __expf(om - nm);
    mx = nm;
  }
  if (ml == 0) {
    rmx[(size_t)b * kN + row] = mx;
    rsn[(size_t)b * kN + row] = 1.f / s;
  }
}

// ---------------------------------------------------------------------------
// Column pass: recompute e, p = exp(e-rmx[n])*rsn[n]; colsum[m] = sum_n p;
// x_r[c,m] = (sum_n V[c,n] p[n,m]) / (1e-9+colsum[m]); u = x - x_r (fp32).
// ---------------------------------------------------------------------------
__global__ __launch_bounds__(256) void k_colpass(const float* __restrict__ Q,
                                                 const bf16* __restrict__ V,
                                                 const float* __restrict__ rmx,
                                                 const float* __restrict__ rsn,
                                                 const float* __restrict__ x,
                                                 float* __restrict__ u) {
  constexpr int MT = 16, NT = 32;
  __shared__ float Vt[NT][kC + 4];   // [n][c]
  __shared__ float QnS[NT][kH + 4];  // row-Q tile
  __shared__ float Pl[NT][MT + 4];   // p tile
  __shared__ float RmS[NT], RsS[NT];
  __shared__ float CsI[MT];
  const int t = threadIdx.x;
  const int b = blockIdx.y;
  const int mBase = blockIdx.x * MT;
  const float* Qb_ = Q + (size_t)b * kN * kH;
  const bf16* Vb_ = V + (size_t)b * kC * kN;
  const int ml = t & 15, ng = t >> 4;
  float qc[kH];
  {
    const float4* qp = (const float4*)(Qb_ + (size_t)(mBase + ml) * kH);
#pragma unroll
    for (int h4 = 0; h4 < kH / 4; ++h4) {
      const float4 v = qp[h4];
      qc[4 * h4] = v.x; qc[4 * h4 + 1] = v.y; qc[4 * h4 + 2] = v.z; qc[4 * h4 + 3] = v.w;
    }
  }
  const int cg = t & 63, mg = t >> 6;
  float acc[4][4] = {};
  float csloc = 0.f;
  const int vrow = t >> 3, vq = t & 7;
  for (int n0 = 0; n0 < kN; n0 += NT) {
    __syncthreads();
    {
      const int rr = t >> 3, hh = (t & 7) * 8;
      const float* qp = Qb_ + (size_t)(n0 + rr) * kH + hh;
      *(float4*)&QnS[rr][hh] = *(const float4*)qp;
      *(float4*)&QnS[rr][hh + 4] = *(const float4*)(qp + 4);
    }
    if (t < NT) {
      RmS[t] = rmx[(size_t)b * kN + n0 + t];
      RsS[t] = rsn[(size_t)b * kN + n0 + t];
    }
#pragma unroll
    for (int it = 0; it < 8; ++it) {
      const int cc = it * 32 + vrow;
      const ushort4 v = *(const ushort4*)(Vb_ + (size_t)cc * kN + n0 + vq * 4);
      Vt[vq * 4 + 0][cc] = us2f(v.x);
      Vt[vq * 4 + 1][cc] = us2f(v.y);
      Vt[vq * 4 + 2][cc] = us2f(v.z);
      Vt[vq * 4 + 3][cc] = us2f(v.w);
    }
    __syncthreads();
#pragma unroll
    for (int half = 0; half < 2; ++half) {
      const int n = ng + half * 16;
      float e = 0.f;
#pragma unroll
      for (int h4 = 0; h4 < kH / 4; ++h4) {
        const float4 v = *(const float4*)&QnS[n][h4 * 4];
        e += qc[4 * h4] * v.x + qc[4 * h4 + 1] * v.y + qc[4 * h4 + 2] * v.z + qc[4 * h4 + 3] * v.w;
      }
      const float p = __expf(e - RmS[n]) * RsS[n];
      Pl[n][ml] = p;
      csloc += p;
    }
    __syncthreads();
#pragma unroll 8
    for (int nn = 0; nn < NT; ++nn) {
      const float4 v4 = *(const float4*)&Vt[nn][cg * 4];
      const float4 p4 = *(const float4*)&Pl[nn][mg * 4];
      acc[0][0] += v4.x * p4.x; acc[0][1] += v4.x * p4.y; acc[0][2] += v4.x * p4.z; acc[0][3] += v4.x * p4.w;
      acc[1][0] += v4.y * p4.x; acc[1][1] += v4.y * p4.y; acc[1][2] += v4.y * p4.z; acc[1][3] += v4.y * p4.w;
      acc[2][0] += v4.z * p4.x; acc[2][1] += v4.z * p4.y; acc[2][2] += v4.z * p4.z; acc[2][3] += v4.z * p4.w;
      acc[3][0] += v4.w * p4.x; acc[3][1] += v4.w * p4.y; acc[3][2] += v4.w * p4.z; acc[3][3] += v4.w * p4.w;
    }
  }
  __syncthreads();
  Pl[ng][ml] = csloc;
  __syncthreads();
  if (t < MT) {
    float cs = 0.f;
#pragma unroll
    for (int k = 0; k < 16; ++k) cs += Pl[k][t];
    CsI[t] = 1.f / (1e-9f + cs);
  }
  __syncthreads();
  const float inv0 = CsI[mg * 4 + 0], inv1 = CsI[mg * 4 + 1];
  const float inv2 = CsI[mg * 4 + 2], inv3 = CsI[mg * 4 + 3];
  const float* xb = x + (size_t)b * kC * kN;
#pragma unroll
  for (int i = 0; i < 4; ++i) {
    const int c = cg * 4 + i;
    const float4 xv = *(const float4*)(xb + (size_t)c * kN + mBase + mg * 4);
    float4 o4;
    o4.x = xv.x - acc[i][0] * inv0;
    o4.y = xv.y - acc[i][1] * inv1;
    o4.z = xv.z - acc[i][2] * inv2;
    o4.w = xv.w - acc[i][3] * inv3;
    *(float4*)(u + (size_t)b * kC * kN + (size_t)c * kN + mBase + mg * 4) = o4;
  }
}

// ---------------------------------------------------------------------------
// BN stats per channel over (B, N), fp32 input, biased var.
// ---------------------------------------------------------------------------
__global__ __launch_bounds__(256) void k_bnstats(const float* __restrict__ y, int nch,
                                                 float* __restrict__ mean,
                                                 float* __restrict__ rsig) {
  const int c = blockIdx.x, t = threadIdx.x;
  float s = 0.f, s2 = 0.f;
  for (int b = 0; b < kB; ++b) {
    const float* p = y + ((size_t)b * nch + c) * kN;
    for (int n = t; n < kN; n += 256) {
      const float v = p[n];
      s += v;
      s2 += v * v;
    }
  }
  __shared__ float r1[256], r2[256];
  r1[t] = s;
  r2[t] = s2;
  __syncthreads();
  for (int k = 128; k > 0; k >>= 1) {
    if (t < k) {
      r1[t] += r1[t + k];
      r2[t] += r2[t + k];
    }
    __syncthreads();
  }
  if (t == 0) {
    const float im = 1.f / (float)(kB * kN);
    const float m = r1[0] * im;
    const float var = r2[0] * im - m * m;
    mean[c] = m;
    rsig[c] = rsqrtf(var + 1e-5f);
  }
}

// ---------------------------------------------------------------------------
// p += leaky(g*(y-mean)*rsig + b)    (in-place residual update, all fp32)
// ---------------------------------------------------------------------------
__global__ __launch_bounds__(256) void k_bnapply(const float* __restrict__ y,
                                                 float* __restrict__ p,
                                                 const float* __restrict__ mean,
                                                 const float* __restrict__ rsig,
                                                 const float* __restrict__ g,
                                                 const float* __restrict__ bb) {
  const size_t i = (size_t)blockIdx.x * 256 + threadIdx.x;
  const int c = (int)((i / kN) % kC);
  float z = g[c] * (y[i] - mean[c]) * rsig[c] + bb[c];
  z = z > 0.f ? z : 0.2f * z;
  p[i] = p[i] + z;
}

// ---------------------------------------------------------------------------
// dc2: tpre[b,j,n] = dc2_b[j] + sum_c dc2_w[j,c] * leaky(bn(h[b,c,n]))
// ---------------------------------------------------------------------------
__global__ __launch_bounds__(256) void k_dc2(const float* __restrict__ h,
                                             const float* __restrict__ mean,
                                             const float* __restrict__ rsig,
                                             const float* __restrict__ g,
                                             const float* __restrict__ bb,
                                             const float* __restrict__ w,
                                             const float* __restrict__ d2b,
                                             float* __restrict__ tpre) {
  __shared__ float wS[3][kC];
  __shared__ float aS[kC], cS[kC];
  const int t = threadIdx.x, b = blockIdx.y;
  const int n = blockIdx.x * 256 + t;
  {
    const float a = g[t] * rsig[t];
    aS[t] = a;
    cS[t] = bb[t] - a * mean[t];
    wS[0][t] = w[t];
    wS[1][t] = w[kC + t];
    wS[2][t] = w[2 * kC + t];
  }
  __syncthreads();
  float a0 = d2b[0], a1 = d2b[1], a2 = d2b[2];
  const float* hb = h + (size_t)b * kC * kN + n;
  for (int c = 0; c < kC; ++c) {
    float z = hb[(size_t)c * kN] * aS[c] + cS[c];
    z = z > 0.f ? z : 0.2f * z;
    a0 += wS[0][c] * z;
    a1 += wS[1][c] * z;
    a2 += wS[2][c] * z;
  }
  tpre[((size_t)b * 3 + 0) * kN + n] = a0;
  tpre[((size_t)b * 3 + 1) * kN + n] = a1;
  tpre[((size_t)b * 3 + 2) * kN + n] = a2;
}

// ---------------------------------------------------------------------------
// Final: out[b,n,j] = tanh(g[j]*(tpre[b,j,n]-mean[j])*rsig[j] + b[j])
// ---------------------------------------------------------------------------
__global__ __launch_bounds__(256) void k_final(const float* __restrict__ tpre,
                                               const float* __restrict__ mean,
                                               const float* __restrict__ rsig,
                                               const float* __restrict__ g,
                                               const float* __restrict__ bb,
                                               float* __restrict__ out) {
  const int i = blockIdx.x * 256 + threadIdx.x;  // over B*N
  const int n = i & (kN - 1), b = i >> 11;
#pragma unroll
  for (int j = 0; j < 3; ++j) {
    const float v = tpre[((size_t)b * 3 + j) * kN + n];
    const float z = g[j] * (v - mean[j]) * rsig[j] + bb[j];
    out[(size_t)i * 3 + j] = tanhf(z);
  }
}

// ---------------------------------------------------------------------------
extern "C" void kernel_launch(void* const* d_in, const int* in_sizes, int n_in,
                              void* d_out, int out_size, void* d_ws, size_t ws_size,
                              hipStream_t stream) {
  const float* feature  = (const float*)d_in[0];
  const float* prior    = (const float*)d_in[1];
  const float* mlp_w    = (const float*)d_in[2];
  const float* mlp_b    = (const float*)d_in[3];
  const float* qk_w     = (const float*)d_in[4];
  const float* qk_b     = (const float*)d_in[5];
  const float* v_w      = (const float*)d_in[6];
  const float* v_b      = (const float*)d_in[7];
  const float* t_w      = (const float*)d_in[8];
  const float* t_b      = (const float*)d_in[9];
  const float* bn_g     = (const float*)d_in[10];
  const float* bn_b     = (const float*)d_in[11];
  const float* dc1_w    = (const float*)d_in[12];
  const float* dc1_bn_g = (const float*)d_in[13];
  const float* dc1_bn_b = (const float*)d_in[14];
  const float* dc2_w    = (const float*)d_in[15];
  const float* dc2_b    = (const float*)d_in[16];
  const float* dc2_bn_g = (const float*)d_in[17];
  const float* dc2_bn_b = (const float*)d_in[18];
  float* out = (float*)d_out;

  // Workspace carve. Total ~126.6 MB (fits 128 MiB).
  char* base = (char*)d_ws;
  size_t off = 0;
  auto carve = [&](size_t bytes) {
    char* p = base + off;
    off += (bytes + 255) & ~(size_t)255;
    return p;
  };
  float* p    = (float*)carve((size_t)kB * kC * kN * 4);  // residual (fp32) 33.6 MB
  float* hacc = (float*)carve((size_t)kB * kC * kN * 4);  // dc1 accumulator 33.6 MB
  float* U    = (float*)carve((size_t)kB * kC * kN * 4);  // u/Y (in-place)  33.6 MB
  float* Qb   = (float*)carve((size_t)kB * kN * kH * 4);  // Q [B][N][64]     8.4 MB
  bf16*  Vb   = (bf16*)carve((size_t)kB * kC * kN * 2);   // V bf16          16.8 MB
  float* rmx  = (float*)carve((size_t)kB * kN * 4);
  float* rsn  = (float*)carve((size_t)kB * kN * 4);
  float* fb   = (float*)carve((size_t)kB * kC * 4);
  float* bnm  = (float*)carve(kC * 4);
  float* bnr  = (float*)carve(kC * 4);
  float* tpre = (float*)carve((size_t)kB * 3 * kN * 4);

  k_fb<<<kB * kC, 256, 0, stream>>>(feature, mlp_w, mlp_b, fb);
  k_p0<<<(kB * kC * kN) / 256, 256, 0, stream>>>(prior, mlp_w, fb, p);

  const dim3 gFC(kN / 32, kB);
  for (int l = 0; l < 4; ++l) {
    k_fc<kH, 0><<<gFC, 256, 0, stream>>>(p, qk_w + (size_t)l * kH * kC, kC,
                                         qk_b + l * kH, Qb, 0);
    k_fc<kC, 1><<<gFC, 256, 0, stream>>>(p, v_w + (size_t)l * kC * kC, kC,
                                         v_b + l * kC, Vb, 0);
    k_rowstats<<<dim3(kN / 16, kB), 256, 0, stream>>>(Qb, rmx, rsn);
    k_colpass<<<dim3(kN / 16, kB), 256, 0, stream>>>(Qb, Vb, rmx, rsn, p, U);
    k_fc<kC, 2><<<gFC, 256, 0, stream>>>(U, t_w + (size_t)l * kC * kC, kC,
                                         t_b + l * kC, U, 0);  // in-place Y
    k_bnstats<<<kC, 256, 0, stream>>>(U, kC, bnm, bnr);
    k_bnapply<<<(kB * kC * kN) / 256, 256, 0, stream>>>(
        U, p, bnm, bnr, bn_g + l * kC, bn_b + l * kC);
    k_fc<kC, 3><<<gFC, 256, 0, stream>>>(p, dc1_w + (size_t)l * kC, 4 * kC,
                                         nullptr, hacc, l == 0 ? 1 : 0);
  }

  k_bnstats<<<kC, 256, 0, stream>>>(hacc, kC, bnm, bnr);
  k_dc2<<<dim3(kN / 256, kB), 256, 0, stream>>>(hacc, bnm, bnr, dc1_bn_g, dc1_bn_b,
                                                dc2_w, dc2_b, tpre);
  k_bnstats<<<3, 256, 0, stream>>>(tpre, 3, bnm, bnr);
  k_final<<<(kB * kN) / 256, 256, 0, stream>>>(tpre, bnm, bnr, dc2_bn_g, dc2_bn_b, out);
}

// Round 4
// 5573.512 us; speedup vs baseline: 2.1921x; 2.1921x over previous
//
#include <hip/hip_runtime.h>
#include <hip/hip_bf16.h>

typedef __hip_bfloat16 bf16;

// Problem constants
constexpr int kB = 16;    // batch
constexpr int kN = 2048;  // points
constexpr int kF = 1024;  // feat dims
constexpr int kC = 256;   // channels
constexpr int kH = 64;    // head dim

__device__ __forceinline__ float us2f(unsigned short u) {
  union { unsigned int i; float f; } w;
  w.i = ((unsigned int)u) << 16;
  return w.f;
}
__device__ __forceinline__ unsigned short f2bu(float f) {
  union { bf16 h; unsigned short s; } u;
  u.h = __float2bfloat16(f);
  return u.s;
}

// ---------------------------------------------------------------------------
// fb[b,c] = mlp_b[c] + sum_f mlp_w[c,f] * feature[b,f]
// ---------------------------------------------------------------------------
__global__ __launch_bounds__(256) void k_fb(const float* __restrict__ feat,
                                            const float* __restrict__ mlp_w,
                                            const float* __restrict__ mlp_b,
                                            float* __restrict__ fb) {
  const int b = blockIdx.x >> 8;
  const int c = blockIdx.x & 255;
  const int t = threadIdx.x;
  const float* wr = mlp_w + (size_t)c * (kF + 3);
  const float* fr = feat + (size_t)b * kF;
  float s = 0.f;
  for (int f = t; f < kF; f += 256) s += wr[f] * fr[f];
  __shared__ float red[256];
  red[t] = s;
  __syncthreads();
  for (int k = 128; k > 0; k >>= 1) {
    if (t < k) red[t] += red[t + k];
    __syncthreads();
  }
  if (t == 0) fb[blockIdx.x] = red[0] + mlp_b[c];
}

// ---------------------------------------------------------------------------
// p[b,c,n] = fb[b,c] + sum_{j<3} mlp_w[c,1024+j] * prior[b,j,n]   (fp32)
// ---------------------------------------------------------------------------
__global__ __launch_bounds__(256) void k_p0(const float* __restrict__ prior,
                                            const float* __restrict__ mlp_w,
                                            const float* __restrict__ fb,
                                            float* __restrict__ p) {
  const size_t i = (size_t)blockIdx.x * 256 + threadIdx.x;  // over B*C*N
  const int n = (int)(i % kN);
  const size_t bc = i / kN;
  const int b = (int)(bc / kC);
  const int c = (int)(bc % kC);
  const float* pr = prior + (size_t)b * 3 * kN + n;
  const float* wr = mlp_w + (size_t)c * (kF + 3) + kF;
  p[i] = fb[bc] + wr[0] * pr[0] + wr[1] * pr[kN] + wr[2] * pr[2 * kN];
}

// ---------------------------------------------------------------------------
// Full-column 1x1 conv: y[b,o,n] = bias[o] + sum_{c<256} w[o,c]*x[b,c,n]
// Block owns 32 n for ALL O outputs; X panel resident in LDS (in-place safe).
// OMODE: 0 = fp32 transposed [b][n][64] (Q); 1 = bf16 [b][o][N] (V);
//        2 = fp32 [b][o][N] (T-conv, y may alias x); 3 = fp32 accumulate.
// ---------------------------------------------------------------------------
template <int O, int OMODE>
__global__ __launch_bounds__(256) void k_fc(const float* __restrict__ x,
                                            const float* __restrict__ w, int wstride,
                                            const float* __restrict__ bias,
                                            void* __restrict__ yv, int first) {
  constexpr int OT = O / 16;  // outputs per thread (16 or 4)
  __shared__ float Xs[32][257];
  __shared__ float Ws[16][O];
  const int t = threadIdx.x;
  const int b = blockIdx.y;
  const int n0 = blockIdx.x * 32;
  const float* xb = x + (size_t)b * kC * kN + n0;
  {  // load X panel [256c][32n] -> Xs[n][c]
    const int n4 = t & 7;
    const int cg = t >> 3;
#pragma unroll
    for (int it = 0; it < 8; ++it) {
      const int c = it * 32 + cg;
      const float4 v = *(const float4*)(xb + (size_t)c * kN + n4 * 4);
      Xs[n4 * 4 + 0][c] = v.x;
      Xs[n4 * 4 + 1][c] = v.y;
      Xs[n4 * 4 + 2][c] = v.z;
      Xs[n4 * 4 + 3][c] = v.w;
    }
  }
  const int tn = t & 15, to = t >> 4;
  float acc[OT][2] = {};
  for (int c0 = 0; c0 < kC; c0 += 16) {
    __syncthreads();  // protect Ws from previous chunk's readers
    if (O == 256 || t < O) {
      const float* wr = w + (size_t)t * wstride + c0;
      const float4 a = *(const float4*)(wr);
      const float4 b4 = *(const float4*)(wr + 4);
      const float4 c4 = *(const float4*)(wr + 8);
      const float4 d4 = *(const float4*)(wr + 12);
      Ws[0][t] = a.x;  Ws[1][t] = a.y;  Ws[2][t] = a.z;  Ws[3][t] = a.w;
      Ws[4][t] = b4.x; Ws[5][t] = b4.y; Ws[6][t] = b4.z; Ws[7][t] = b4.w;
      Ws[8][t] = c4.x; Ws[9][t] = c4.y; Ws[10][t] = c4.z; Ws[11][t] = c4.w;
      Ws[12][t] = d4.x; Ws[13][t] = d4.y; Ws[14][t] = d4.z; Ws[15][t] = d4.w;
    }
    __syncthreads();
#pragma unroll
    for (int cc = 0; cc < 16; ++cc) {
      const float xa = Xs[2 * tn + 0][c0 + cc];
      const float xc2 = Xs[2 * tn + 1][c0 + cc];
#pragma unroll
      for (int q = 0; q < OT / 4; ++q) {
        const float4 wv = *(const float4*)&Ws[cc][to * OT + q * 4];
        acc[q * 4 + 0][0] += wv.x * xa; acc[q * 4 + 0][1] += wv.x * xc2;
        acc[q * 4 + 1][0] += wv.y * xa; acc[q * 4 + 1][1] += wv.y * xc2;
        acc[q * 4 + 2][0] += wv.z * xa; acc[q * 4 + 2][1] += wv.z * xc2;
        acc[q * 4 + 3][0] += wv.w * xa; acc[q * 4 + 3][1] += wv.w * xc2;
      }
    }
  }
  const int n = n0 + 2 * tn;
  if (OMODE == 0) {  // Q fp32 transposed [b][n][64]
    float* y = (float*)yv;
#pragma unroll
    for (int i = 0; i < OT; ++i) {
      const int o = to * OT + i;
      const float bz = bias[o];
      y[((size_t)b * kN + n + 0) * kH + o] = acc[i][0] + bz;
      y[((size_t)b * kN + n + 1) * kH + o] = acc[i][1] + bz;
    }
  } else if (OMODE == 1) {  // V bf16 [b][o][N]
    bf16* y = (bf16*)yv;
#pragma unroll
    for (int i = 0; i < OT; ++i) {
      const int o = to * OT + i;
      const float bz = bias[o];
      ushort2 u2;
      u2.x = f2bu(acc[i][0] + bz);
      u2.y = f2bu(acc[i][1] + bz);
      *(ushort2*)(y + ((size_t)b * kC + o) * kN + n) = u2;
    }
  } else if (OMODE == 2) {  // fp32 [b][o][N], may alias x (panel is in LDS)
    float* y = (float*)yv;
#pragma unroll
    for (int i = 0; i < OT; ++i) {
      const int o = to * OT + i;
      const float bz = bias[o];
      *(float2*)(y + ((size_t)b * kC + o) * kN + n) =
          make_float2(acc[i][0] + bz, acc[i][1] + bz);
    }
  } else {  // fp32 accumulate (dc1)
    float* y = (float*)yv;
#pragma unroll
    for (int i = 0; i < OT; ++i) {
      const int o = to * OT + i;
      float2* p2 = (float2*)(y + ((size_t)b * kC + o) * kN + n);
      if (first) {
        *p2 = make_float2(acc[i][0], acc[i][1]);
      } else {
        const float2 old = *p2;
        *p2 = make_float2(old.x + acc[i][0], old.y + acc[i][1]);
      }
    }
  }
}

// ---------------------------------------------------------------------------
// Row softmax stats (TILED): e[n,m] = Q[n]·Q[m]; per row: rmx, rsn=1/sum.
// Block: 64 rows, 16x16 threads, 4x4 micro-tile, 64-col tiles staged k-major
// in LDS. Online softmax in registers; 16-lane shfl merge.
// ---------------------------------------------------------------------------
__global__ __launch_bounds__(256) void k_rowstats(const float* __restrict__ Q,
                                                  float* __restrict__ rmx,
                                                  float* __restrict__ rsn) {
  __shared__ float QrT[kH][68];  // [k][row]
  __shared__ float QcT[kH][68];  // [k][col]
  const int b = blockIdx.y, t = threadIdx.x;
  const int r0 = blockIdx.x * 64;
  const float* Qb_ = Q + (size_t)b * kN * kH;
  const int tc = t & 15, tr = t >> 4;
  {  // load row tile transposed: QrT[k][r] = Q[r0+r][k]
    const int rr = t >> 4;
    const int hh = (t & 15) * 4;
#pragma unroll
    for (int it = 0; it < 4; ++it) {
      const int r = it * 16 + rr;
      const float4 v = *(const float4*)(Qb_ + (size_t)(r0 + r) * kH + hh);
      QrT[hh + 0][r] = v.x;
      QrT[hh + 1][r] = v.y;
      QrT[hh + 2][r] = v.z;
      QrT[hh + 3][r] = v.w;
    }
  }
  float mx[4] = {-3.0e38f, -3.0e38f, -3.0e38f, -3.0e38f};
  float sm[4] = {0.f, 0.f, 0.f, 0.f};
  for (int m0 = 0; m0 < kN; m0 += 64) {
    __syncthreads();  // previous tile consumers done
    {                 // load col tile transposed
      const int rr = t >> 4;
      const int hh = (t & 15) * 4;
#pragma unroll
      for (int it = 0; it < 4; ++it) {
        const int r = it * 16 + rr;
        const float4 v = *(const float4*)(Qb_ + (size_t)(m0 + r) * kH + hh);
        QcT[hh + 0][r] = v.x;
        QcT[hh + 1][r] = v.y;
        QcT[hh + 2][r] = v.z;
        QcT[hh + 3][r] = v.w;
      }
    }
    __syncthreads();
    float acc[4][4] = {};
#pragma unroll 16
    for (int k = 0; k < kH; ++k) {
      const float4 a = *(const float4*)&QrT[k][tr * 4];
      const float4 c = *(const float4*)&QcT[k][tc * 4];
      acc[0][0] += a.x * c.x; acc[0][1] += a.x * c.y; acc[0][2] += a.x * c.z; acc[0][3] += a.x * c.w;
      acc[1][0] += a.y * c.x; acc[1][1] += a.y * c.y; acc[1][2] += a.y * c.z; acc[1][3] += a.y * c.w;
      acc[2][0] += a.z * c.x; acc[2][1] += a.z * c.y; acc[2][2] += a.z * c.z; acc[2][3] += a.z * c.w;
      acc[3][0] += a.w * c.x; acc[3][1] += a.w * c.y; acc[3][2] += a.w * c.z; acc[3][3] += a.w * c.w;
    }
#pragma unroll
    for (int i = 0; i < 4; ++i) {
      const float tmax = fmaxf(fmaxf(acc[i][0], acc[i][1]), fmaxf(acc[i][2], acc[i][3]));
      const float nm = fmaxf(mx[i], tmax);
      sm[i] = sm[i] * __expf(mx[i] - nm) + __expf(acc[i][0] - nm) + __expf(acc[i][1] - nm) +
              __expf(acc[i][2] - nm) + __expf(acc[i][3] - nm);
      mx[i] = nm;
    }
  }
  // merge across the 16 tc lanes sharing rows tr*4..tr*4+3
#pragma unroll
  for (int mask = 1; mask < 16; mask <<= 1) {
#pragma unroll
    for (int i = 0; i < 4; ++i) {
      const float om = __shfl_xor(mx[i], mask);
      const float os = __shfl_xor(sm[i], mask);
      const float nm = fmaxf(mx[i], om);
      sm[i] = sm[i] * __expf(mx[i] - nm) + os * __expf(om - nm);
      mx[i] = nm;
    }
  }
  if (tc == 0) {
#pragma unroll
    for (int i = 0; i < 4; ++i) {
      const int row = r0 + tr * 4 + i;
      rmx[(size_t)b * kN + row] = mx[i];
      rsn[(size_t)b * kN + row] = 1.f / sm[i];
    }
  }
}

// ---------------------------------------------------------------------------
// Column pass: recompute e, p = exp(e-rmx[n])*rsn[n]; colsum[m] = sum_n p;
// x_r[c,m] = (sum_n V[c,n] p[n,m]) / (1e-9+colsum[m]); u = x - x_r (fp32).
// ---------------------------------------------------------------------------
__global__ __launch_bounds__(256) void k_colpass(const float* __restrict__ Q,
                                                 const bf16* __restrict__ V,
                                                 const float* __restrict__ rmx,
                                                 const float* __restrict__ rsn,
                                                 const float* __restrict__ x,
                                                 float* __restrict__ u) {
  constexpr int MT = 16, NT = 32;
  __shared__ float Vt[NT][kC + 4];   // [n][c]
  __shared__ float QnS[NT][kH + 4];  // row-Q tile
  __shared__ float Pl[NT][MT + 4];   // p tile
  __shared__ float RmS[NT], RsS[NT];
  __shared__ float CsI[MT];
  const int t = threadIdx.x;
  const int b = blockIdx.y;
  const int mBase = blockIdx.x * MT;
  const float* Qb_ = Q + (size_t)b * kN * kH;
  const bf16* Vb_ = V + (size_t)b * kC * kN;
  const int ml = t & 15, ng = t >> 4;
  float qc[kH];
  {
    const float4* qp = (const float4*)(Qb_ + (size_t)(mBase + ml) * kH);
#pragma unroll
    for (int h4 = 0; h4 < kH / 4; ++h4) {
      const float4 v = qp[h4];
      qc[4 * h4] = v.x; qc[4 * h4 + 1] = v.y; qc[4 * h4 + 2] = v.z; qc[4 * h4 + 3] = v.w;
    }
  }
  const int cg = t & 63, mg = t >> 6;
  float acc[4][4] = {};
  float csloc = 0.f;
  const int vrow = t >> 3, vq = t & 7;
  for (int n0 = 0; n0 < kN; n0 += NT) {
    __syncthreads();
    {
      const int rr = t >> 3, hh = (t & 7) * 8;
      const float* qp = Qb_ + (size_t)(n0 + rr) * kH + hh;
      *(float4*)&QnS[rr][hh] = *(const float4*)qp;
      *(float4*)&QnS[rr][hh + 4] = *(const float4*)(qp + 4);
    }
    if (t < NT) {
      RmS[t] = rmx[(size_t)b * kN + n0 + t];
      RsS[t] = rsn[(size_t)b * kN + n0 + t];
    }
#pragma unroll
    for (int it = 0; it < 8; ++it) {
      const int cc = it * 32 + vrow;
      const ushort4 v = *(const ushort4*)(Vb_ + (size_t)cc * kN + n0 + vq * 4);
      Vt[vq * 4 + 0][cc] = us2f(v.x);
      Vt[vq * 4 + 1][cc] = us2f(v.y);
      Vt[vq * 4 + 2][cc] = us2f(v.z);
      Vt[vq * 4 + 3][cc] = us2f(v.w);
    }
    __syncthreads();
#pragma unroll
    for (int half = 0; half < 2; ++half) {
      const int n = ng + half * 16;
      float e = 0.f;
#pragma unroll
      for (int h4 = 0; h4 < kH / 4; ++h4) {
        const float4 v = *(const float4*)&QnS[n][h4 * 4];
        e += qc[4 * h4] * v.x + qc[4 * h4 + 1] * v.y + qc[4 * h4 + 2] * v.z + qc[4 * h4 + 3] * v.w;
      }
      const float p = __expf(e - RmS[n]) * RsS[n];
      Pl[n][ml] = p;
      csloc += p;
    }
    __syncthreads();
#pragma unroll 8
    for (int nn = 0; nn < NT; ++nn) {
      const float4 v4 = *(const float4*)&Vt[nn][cg * 4];
      const float4 p4 = *(const float4*)&Pl[nn][mg * 4];
      acc[0][0] += v4.x * p4.x; acc[0][1] += v4.x * p4.y; acc[0][2] += v4.x * p4.z; acc[0][3] += v4.x * p4.w;
      acc[1][0] += v4.y * p4.x; acc[1][1] += v4.y * p4.y; acc[1][2] += v4.y * p4.z; acc[1][3] += v4.y * p4.w;
      acc[2][0] += v4.z * p4.x; acc[2][1] += v4.z * p4.y; acc[2][2] += v4.z * p4.z; acc[2][3] += v4.z * p4.w;
      acc[3][0] += v4.w * p4.x; acc[3][1] += v4.w * p4.y; acc[3][2] += v4.w * p4.z; acc[3][3] += v4.w * p4.w;
    }
  }
  __syncthreads();
  Pl[ng][ml] = csloc;
  __syncthreads();
  if (t < MT) {
    float cs = 0.f;
#pragma unroll
    for (int k = 0; k < 16; ++k) cs += Pl[k][t];
    CsI[t] = 1.f / (1e-9f + cs);
  }
  __syncthreads();
  const float inv0 = CsI[mg * 4 + 0], inv1 = CsI[mg * 4 + 1];
  const float inv2 = CsI[mg * 4 + 2], inv3 = CsI[mg * 4 + 3];
  const float* xb = x + (size_t)b * kC * kN;
#pragma unroll
  for (int i = 0; i < 4; ++i) {
    const int c = cg * 4 + i;
    const float4 xv = *(const float4*)(xb + (size_t)c * kN + mBase + mg * 4);
    float4 o4;
    o4.x = xv.x - acc[i][0] * inv0;
    o4.y = xv.y - acc[i][1] * inv1;
    o4.z = xv.z - acc[i][2] * inv2;
    o4.w = xv.w - acc[i][3] * inv3;
    *(float4*)(u + (size_t)b * kC * kN + (size_t)c * kN + mBase + mg * 4) = o4;
  }
}

// ---------------------------------------------------------------------------
// BN stats per channel over (B, N), fp32 input, biased var.
// ---------------------------------------------------------------------------
__global__ __launch_bounds__(256) void k_bnstats(const float* __restrict__ y, int nch,
                                                 float* __restrict__ mean,
                                                 float* __restrict__ rsig) {
  const int c = blockIdx.x, t = threadIdx.x;
  float s = 0.f, s2 = 0.f;
  for (int b = 0; b < kB; ++b) {
    const float* p = y + ((size_t)b * nch + c) * kN;
    for (int n = t; n < kN; n += 256) {
      const float v = p[n];
      s += v;
      s2 += v * v;
    }
  }
  __shared__ float r1[256], r2[256];
  r1[t] = s;
  r2[t] = s2;
  __syncthreads();
  for (int k = 128; k > 0; k >>= 1) {
    if (t < k) {
      r1[t] += r1[t + k];
      r2[t] += r2[t + k];
    }
    __syncthreads();
  }
  if (t == 0) {
    const float im = 1.f / (float)(kB * kN);
    const float m = r1[0] * im;
    const float var = r2[0] * im - m * m;
    mean[c] = m;
    rsig[c] = rsqrtf(var + 1e-5f);
  }
}

// ---------------------------------------------------------------------------
// p += leaky(g*(y-mean)*rsig + b)    (in-place residual update, all fp32)
// ---------------------------------------------------------------------------
__global__ __launch_bounds__(256) void k_bnapply(const float* __restrict__ y,
                                                 float* __restrict__ p,
                                                 const float* __restrict__ mean,
                                                 const float* __restrict__ rsig,
                                                 const float* __restrict__ g,
                                                 const float* __restrict__ bb) {
  const size_t i = (size_t)blockIdx.x * 256 + threadIdx.x;
  const int c = (int)((i / kN) % kC);
  float z = g[c] * (y[i] - mean[c]) * rsig[c] + bb[c];
  z = z > 0.f ? z : 0.2f * z;
  p[i] = p[i] + z;
}

// ---------------------------------------------------------------------------
// dc2: tpre[b,j,n] = dc2_b[j] + sum_c dc2_w[j,c] * leaky(bn(h[b,c,n]))
// ---------------------------------------------------------------------------
__global__ __launch_bounds__(256) void k_dc2(const float* __restrict__ h,
                                             const float* __restrict__ mean,
                                             const float* __restrict__ rsig,
                                             const float* __restrict__ g,
                                             const float* __restrict__ bb,
                                             const float* __restrict__ w,
                                             const float* __restrict__ d2b,
                                             float* __restrict__ tpre) {
  __shared__ float wS[3][kC];
  __shared__ float aS[kC], cS[kC];
  const int t = threadIdx.x, b = blockIdx.y;
  const int n = blockIdx.x * 256 + t;
  {
    const float a = g[t] * rsig[t];
    aS[t] = a;
    cS[t] = bb[t] - a * mean[t];
    wS[0][t] = w[t];
    wS[1][t] = w[kC + t];
    wS[2][t] = w[2 * kC + t];
  }
  __syncthreads();
  float a0 = d2b[0], a1 = d2b[1], a2 = d2b[2];
  const float* hb = h + (size_t)b * kC * kN + n;
  for (int c = 0; c < kC; ++c) {
    float z = hb[(size_t)c * kN] * aS[c] + cS[c];
    z = z > 0.f ? z : 0.2f * z;
    a0 += wS[0][c] * z;
    a1 += wS[1][c] * z;
    a2 += wS[2][c] * z;
  }
  tpre[((size_t)b * 3 + 0) * kN + n] = a0;
  tpre[((size_t)b * 3 + 1) * kN + n] = a1;
  tpre[((size_t)b * 3 + 2) * kN + n] = a2;
}

// ---------------------------------------------------------------------------
// Final: out[b,n,j] = tanh(g[j]*(tpre[b,j,n]-mean[j])*rsig[j] + b[j])
// ---------------------------------------------------------------------------
__global__ __launch_bounds__(256) void k_final(const float* __restrict__ tpre,
                                               const float* __restrict__ mean,
                                               const float* __restrict__ rsig,
                                               const float* __restrict__ g,
                                               const float* __restrict__ bb,
                                               float* __restrict__ out) {
  const int i = blockIdx.x * 256 + threadIdx.x;  // over B*N
  const int n = i & (kN - 1), b = i >> 11;
#pragma unroll
  for (int j = 0; j < 3; ++j) {
    const float v = tpre[((size_t)b * 3 + j) * kN + n];
    const float z = g[j] * (v - mean[j]) * rsig[j] + bb[j];
    out[(size_t)i * 3 + j] = tanhf(z);
  }
}

// ---------------------------------------------------------------------------
extern "C" void kernel_launch(void* const* d_in, const int* in_sizes, int n_in,
                              void* d_out, int out_size, void* d_ws, size_t ws_size,
                              hipStream_t stream) {
  const float* feature  = (const float*)d_in[0];
  const float* prior    = (const float*)d_in[1];
  const float* mlp_w    = (const float*)d_in[2];
  const float* mlp_b    = (const float*)d_in[3];
  const float* qk_w     = (const float*)d_in[4];
  const float* qk_b     = (const float*)d_in[5];
  const float* v_w      = (const float*)d_in[6];
  const float* v_b      = (const float*)d_in[7];
  const float* t_w      = (const float*)d_in[8];
  const float* t_b      = (const float*)d_in[9];
  const float* bn_g     = (const float*)d_in[10];
  const float* bn_b     = (const float*)d_in[11];
  const float* dc1_w    = (const float*)d_in[12];
  const float* dc1_bn_g = (const float*)d_in[13];
  const float* dc1_bn_b = (const float*)d_in[14];
  const float* dc2_w    = (const float*)d_in[15];
  const float* dc2_b    = (const float*)d_in[16];
  const float* dc2_bn_g = (const float*)d_in[17];
  const float* dc2_bn_b = (const float*)d_in[18];
  float* out = (float*)d_out;

  // Workspace carve. Total ~126.6 MB (fits 128 MiB).
  char* base = (char*)d_ws;
  size_t off = 0;
  auto carve = [&](size_t bytes) {
    char* p = base + off;
    off += (bytes + 255) & ~(size_t)255;
    return p;
  };
  float* p    = (float*)carve((size_t)kB * kC * kN * 4);  // residual (fp32) 33.6 MB
  float* hacc = (float*)carve((size_t)kB * kC * kN * 4);  // dc1 accumulator 33.6 MB
  float* U    = (float*)carve((size_t)kB * kC * kN * 4);  // u/Y (in-place)  33.6 MB
  float* Qb   = (float*)carve((size_t)kB * kN * kH * 4);  // Q [B][N][64]     8.4 MB
  bf16*  Vb   = (bf16*)carve((size_t)kB * kC * kN * 2);   // V bf16          16.8 MB
  float* rmx  = (float*)carve((size_t)kB * kN * 4);
  float* rsn  = (float*)carve((size_t)kB * kN * 4);
  float* fb   = (float*)carve((size_t)kB * kC * 4);
  float* bnm  = (float*)carve(kC * 4);
  float* bnr  = (float*)carve(kC * 4);
  float* tpre = (float*)carve((size_t)kB * 3 * kN * 4);

  k_fb<<<kB * kC, 256, 0, stream>>>(feature, mlp_w, mlp_b, fb);
  k_p0<<<(kB * kC * kN) / 256, 256, 0, stream>>>(prior, mlp_w, fb, p);

  const dim3 gFC(kN / 32, kB);
  for (int l = 0; l < 4; ++l) {
    k_fc<kH, 0><<<gFC, 256, 0, stream>>>(p, qk_w + (size_t)l * kH * kC, kC,
                                         qk_b + l * kH, Qb, 0);
    k_fc<kC, 1><<<gFC, 256, 0, stream>>>(p, v_w + (size_t)l * kC * kC, kC,
                                         v_b + l * kC, Vb, 0);
    k_rowstats<<<dim3(kN / 64, kB), 256, 0, stream>>>(Qb, rmx, rsn);
    k_colpass<<<dim3(kN / 16, kB), 256, 0, stream>>>(Qb, Vb, rmx, rsn, p, U);
    k_fc<kC, 2><<<gFC, 256, 0, stream>>>(U, t_w + (size_t)l * kC * kC, kC,
                                         t_b + l * kC, U, 0);  // in-place Y
    k_bnstats<<<kC, 256, 0, stream>>>(U, kC, bnm, bnr);
    k_bnapply<<<(kB * kC * kN) / 256, 256, 0, stream>>>(
        U, p, bnm, bnr, bn_g + l * kC, bn_b + l * kC);
    k_fc<kC, 3><<<gFC, 256, 0, stream>>>(p, dc1_w + (size_t)l * kC, 4 * kC,
                                         nullptr, hacc, l == 0 ? 1 : 0);
  }

  k_bnstats<<<kC, 256, 0, stream>>>(hacc, bnm ? kC : kC, bnm, bnr);
  k_dc2<<<dim3(kN / 256, kB), 256, 0, stream>>>(hacc, bnm, bnr, dc1_bn_g, dc1_bn_b,
                                                dc2_w, dc2_b, tpre);
  k_bnstats<<<3, 256, 0, stream>>>(tpre, 3, bnm, bnr);
  k_final<<<(kB * kN) / 256, 256, 0, stream>>>(tpre, bnm, bnr, dc2_bn_g, dc2_bn_b, out);
}

// Round 5
// 3709.806 us; speedup vs baseline: 3.2933x; 1.5024x over previous
//
#include <hip/hip_runtime.h>
#include <hip/hip_bf16.h>

typedef __hip_bfloat16 bf16;

// Problem constants
constexpr int kB = 16;    // batch
constexpr int kN = 2048;  // points
constexpr int kF = 1024;  // feat dims
constexpr int kC = 256;   // channels
constexpr int kH = 64;    // head dim

using f32x4 = __attribute__((ext_vector_type(4))) float;
using bf16x8 = __attribute__((ext_vector_type(8))) short;  // 8 bf16 (4 VGPRs)

__device__ __forceinline__ float us2f(unsigned short u) {
  union { unsigned int i; float f; } w;
  w.i = ((unsigned int)u) << 16;
  return w.f;
}
__device__ __forceinline__ unsigned short f2bu(float f) {
  union { bf16 h; unsigned short s; } u;
  u.h = __float2bfloat16(f);
  return u.s;
}

// ---------------------------------------------------------------------------
// fb[b,c] = mlp_b[c] + sum_f mlp_w[c,f] * feature[b,f]
// ---------------------------------------------------------------------------
__global__ __launch_bounds__(256) void k_fb(const float* __restrict__ feat,
                                            const float* __restrict__ mlp_w,
                                            const float* __restrict__ mlp_b,
                                            float* __restrict__ fb) {
  const int b = blockIdx.x >> 8;
  const int c = blockIdx.x & 255;
  const int t = threadIdx.x;
  const float* wr = mlp_w + (size_t)c * (kF + 3);
  const float* fr = feat + (size_t)b * kF;
  float s = 0.f;
  for (int f = t; f < kF; f += 256) s += wr[f] * fr[f];
  __shared__ float red[256];
  red[t] = s;
  __syncthreads();
  for (int k = 128; k > 0; k >>= 1) {
    if (t < k) red[t] += red[t + k];
    __syncthreads();
  }
  if (t == 0) fb[blockIdx.x] = red[0] + mlp_b[c];
}

// ---------------------------------------------------------------------------
// p[b,c,n] = fb[b,c] + sum_{j<3} mlp_w[c,1024+j] * prior[b,j,n]   (fp32)
// ---------------------------------------------------------------------------
__global__ __launch_bounds__(256) void k_p0(const float* __restrict__ prior,
                                            const float* __restrict__ mlp_w,
                                            const float* __restrict__ fb,
                                            float* __restrict__ p) {
  const size_t i = (size_t)blockIdx.x * 256 + threadIdx.x;  // over B*C*N
  const int n = (int)(i % kN);
  const size_t bc = i / kN;
  const int b = (int)(bc / kC);
  const int c = (int)(bc % kC);
  const float* pr = prior + (size_t)b * 3 * kN + n;
  const float* wr = mlp_w + (size_t)c * (kF + 3) + kF;
  p[i] = fb[bc] + wr[0] * pr[0] + wr[1] * pr[kN] + wr[2] * pr[2 * kN];
}

// ---------------------------------------------------------------------------
// Full-column 1x1 conv: y[b,o,n] = bias[o] + sum_{c<256} w[o,c]*x[b,c,n]
// Block owns 32 n for ALL O outputs; X panel resident in LDS (in-place safe).
// OMODE: 0 = fp32 transposed [b][n][64] (Q); 1 = bf16 [b][o][N] (V);
//        2 = fp32 [b][o][N] (T-conv, y may alias x); 3 = fp32 accumulate.
// ---------------------------------------------------------------------------
template <int O, int OMODE>
__global__ __launch_bounds__(256) void k_fc(const float* __restrict__ x,
                                            const float* __restrict__ w, int wstride,
                                            const float* __restrict__ bias,
                                            void* __restrict__ yv, int first) {
  constexpr int OT = O / 16;  // outputs per thread (16 or 4)
  __shared__ float Xs[32][257];
  __shared__ float Ws[16][O];
  const int t = threadIdx.x;
  const int b = blockIdx.y;
  const int n0 = blockIdx.x * 32;
  const float* xb = x + (size_t)b * kC * kN + n0;
  {  // load X panel [256c][32n] -> Xs[n][c]
    const int n4 = t & 7;
    const int cg = t >> 3;
#pragma unroll
    for (int it = 0; it < 8; ++it) {
      const int c = it * 32 + cg;
      const float4 v = *(const float4*)(xb + (size_t)c * kN + n4 * 4);
      Xs[n4 * 4 + 0][c] = v.x;
      Xs[n4 * 4 + 1][c] = v.y;
      Xs[n4 * 4 + 2][c] = v.z;
      Xs[n4 * 4 + 3][c] = v.w;
    }
  }
  const int tn = t & 15, to = t >> 4;
  float acc[OT][2] = {};
  for (int c0 = 0; c0 < kC; c0 += 16) {
    __syncthreads();  // protect Ws from previous chunk's readers
    if (O == 256 || t < O) {
      const float* wr = w + (size_t)t * wstride + c0;
      const float4 a = *(const float4*)(wr);
      const float4 b4 = *(const float4*)(wr + 4);
      const float4 c4 = *(const float4*)(wr + 8);
      const float4 d4 = *(const float4*)(wr + 12);
      Ws[0][t] = a.x;  Ws[1][t] = a.y;  Ws[2][t] = a.z;  Ws[3][t] = a.w;
      Ws[4][t] = b4.x; Ws[5][t] = b4.y; Ws[6][t] = b4.z; Ws[7][t] = b4.w;
      Ws[8][t] = c4.x; Ws[9][t] = c4.y; Ws[10][t] = c4.z; Ws[11][t] = c4.w;
      Ws[12][t] = d4.x; Ws[13][t] = d4.y; Ws[14][t] = d4.z; Ws[15][t] = d4.w;
    }
    __syncthreads();
#pragma unroll
    for (int cc = 0; cc < 16; ++cc) {
      const float xa = Xs[2 * tn + 0][c0 + cc];
      const float xc2 = Xs[2 * tn + 1][c0 + cc];
#pragma unroll
      for (int q = 0; q < OT / 4; ++q) {
        const float4 wv = *(const float4*)&Ws[cc][to * OT + q * 4];
        acc[q * 4 + 0][0] += wv.x * xa; acc[q * 4 + 0][1] += wv.x * xc2;
        acc[q * 4 + 1][0] += wv.y * xa; acc[q * 4 + 1][1] += wv.y * xc2;
        acc[q * 4 + 2][0] += wv.z * xa; acc[q * 4 + 2][1] += wv.z * xc2;
        acc[q * 4 + 3][0] += wv.w * xa; acc[q * 4 + 3][1] += wv.w * xc2;
      }
    }
  }
  const int n = n0 + 2 * tn;
  if (OMODE == 0) {  // Q fp32 transposed [b][n][64]
    float* y = (float*)yv;
#pragma unroll
    for (int i = 0; i < OT; ++i) {
      const int o = to * OT + i;
      const float bz = bias[o];
      y[((size_t)b * kN + n + 0) * kH + o] = acc[i][0] + bz;
      y[((size_t)b * kN + n + 1) * kH + o] = acc[i][1] + bz;
    }
  } else if (OMODE == 1) {  // V bf16 [b][o][N]
    bf16* y = (bf16*)yv;
#pragma unroll
    for (int i = 0; i < OT; ++i) {
      const int o = to * OT + i;
      const float bz = bias[o];
      ushort2 u2;
      u2.x = f2bu(acc[i][0] + bz);
      u2.y = f2bu(acc[i][1] + bz);
      *(ushort2*)(y + ((size_t)b * kC + o) * kN + n) = u2;
    }
  } else if (OMODE == 2) {  // fp32 [b][o][N], may alias x (panel is in LDS)
    float* y = (float*)yv;
#pragma unroll
    for (int i = 0; i < OT; ++i) {
      const int o = to * OT + i;
      const float bz = bias[o];
      *(float2*)(y + ((size_t)b * kC + o) * kN + n) =
          make_float2(acc[i][0] + bz, acc[i][1] + bz);
    }
  } else {  // fp32 accumulate (dc1)
    float* y = (float*)yv;
#pragma unroll
    for (int i = 0; i < OT; ++i) {
      const int o = to * OT + i;
      float2* p2 = (float2*)(y + ((size_t)b * kC + o) * kN + n);
      if (first) {
        *p2 = make_float2(acc[i][0], acc[i][1]);
      } else {
        const float2 old = *p2;
        *p2 = make_float2(old.x + acc[i][0], old.y + acc[i][1]);
      }
    }
  }
}

// ---------------------------------------------------------------------------
// Row softmax stats (TILED): e[n,m] = Q[n]·Q[m]; per row: rmx, rsn=1/sum.
// ---------------------------------------------------------------------------
__global__ __launch_bounds__(256) void k_rowstats(const float* __restrict__ Q,
                                                  float* __restrict__ rmx,
                                                  float* __restrict__ rsn) {
  __shared__ float QrT[kH][68];  // [k][row]
  __shared__ float QcT[kH][68];  // [k][col]
  const int b = blockIdx.y, t = threadIdx.x;
  const int r0 = blockIdx.x * 64;
  const float* Qb_ = Q + (size_t)b * kN * kH;
  const int tc = t & 15, tr = t >> 4;
  {  // load row tile transposed: QrT[k][r] = Q[r0+r][k]
    const int rr = t >> 4;
    const int hh = (t & 15) * 4;
#pragma unroll
    for (int it = 0; it < 4; ++it) {
      const int r = it * 16 + rr;
      const float4 v = *(const float4*)(Qb_ + (size_t)(r0 + r) * kH + hh);
      QrT[hh + 0][r] = v.x;
      QrT[hh + 1][r] = v.y;
      QrT[hh + 2][r] = v.z;
      QrT[hh + 3][r] = v.w;
    }
  }
  float mx[4] = {-3.0e38f, -3.0e38f, -3.0e38f, -3.0e38f};
  float sm[4] = {0.f, 0.f, 0.f, 0.f};
  for (int m0 = 0; m0 < kN; m0 += 64) {
    __syncthreads();  // previous tile consumers done
    {                 // load col tile transposed
      const int rr = t >> 4;
      const int hh = (t & 15) * 4;
#pragma unroll
      for (int it = 0; it < 4; ++it) {
        const int r = it * 16 + rr;
        const float4 v = *(const float4*)(Qb_ + (size_t)(m0 + r) * kH + hh);
        QcT[hh + 0][r] = v.x;
        QcT[hh + 1][r] = v.y;
        QcT[hh + 2][r] = v.z;
        QcT[hh + 3][r] = v.w;
      }
    }
    __syncthreads();
    float acc[4][4] = {};
#pragma unroll 16
    for (int k = 0; k < kH; ++k) {
      const float4 a = *(const float4*)&QrT[k][tr * 4];
      const float4 c = *(const float4*)&QcT[k][tc * 4];
      acc[0][0] += a.x * c.x; acc[0][1] += a.x * c.y; acc[0][2] += a.x * c.z; acc[0][3] += a.x * c.w;
      acc[1][0] += a.y * c.x; acc[1][1] += a.y * c.y; acc[1][2] += a.y * c.z; acc[1][3] += a.y * c.w;
      acc[2][0] += a.z * c.x; acc[2][1] += a.z * c.y; acc[2][2] += a.z * c.z; acc[2][3] += a.z * c.w;
      acc[3][0] += a.w * c.x; acc[3][1] += a.w * c.y; acc[3][2] += a.w * c.z; acc[3][3] += a.w * c.w;
    }
#pragma unroll
    for (int i = 0; i < 4; ++i) {
      const float tmax = fmaxf(fmaxf(acc[i][0], acc[i][1]), fmaxf(acc[i][2], acc[i][3]));
      const float nm = fmaxf(mx[i], tmax);
      sm[i] = sm[i] * __expf(mx[i] - nm) + __expf(acc[i][0] - nm) + __expf(acc[i][1] - nm) +
              __expf(acc[i][2] - nm) + __expf(acc[i][3] - nm);
      mx[i] = nm;
    }
  }
  // merge across the 16 tc lanes sharing rows tr*4..tr*4+3
#pragma unroll
  for (int mask = 1; mask < 16; mask <<= 1) {
#pragma unroll
    for (int i = 0; i < 4; ++i) {
      const float om = __shfl_xor(mx[i], mask);
      const float os = __shfl_xor(sm[i], mask);
      const float nm = fmaxf(mx[i], om);
      sm[i] = sm[i] * __expf(mx[i] - nm) + os * __expf(om - nm);
      mx[i] = nm;
    }
  }
  if (tc == 0) {
#pragma unroll
    for (int i = 0; i < 4; ++i) {
      const int row = r0 + tr * 4 + i;
      rmx[(size_t)b * kN + row] = mx[i];
      rsn[(size_t)b * kN + row] = 1.f / sm[i];
    }
  }
}

// ---------------------------------------------------------------------------
// Column pass (PV via MFMA): recompute e (fp32), p = exp(e-rmx[n])*rsn[n],
// round p to bf16; colsum[m] = sum_n p; x_r = (V @ P) / (1e-9+colsum);
// u = x - x_r (fp32). Block: 16 columns m, K-loop over n in tiles of 32.
// MFMA mfma_f32_16x16x32_bf16: A=V[c][n] (LDS [c][n] bf16), B=P[n][m]
// (LDS [m][n] bf16), D[c-within-16][m].
// ---------------------------------------------------------------------------
__global__ __launch_bounds__(256) void k_colpass(const float* __restrict__ Q,
                                                 const bf16* __restrict__ V,
                                                 const float* __restrict__ rmx,
                                                 const float* __restrict__ rsn,
                                                 const float* __restrict__ x,
                                                 float* __restrict__ u) {
  constexpr int MT = 16, NT = 32;
  __shared__ __align__(16) float QnS[NT][kH + 4];      // [n][h] fp32
  __shared__ __align__(16) unsigned short Vs[kC][40];  // [c][n] bf16
  __shared__ __align__(16) unsigned short Pl[MT][40];  // [m][n] bf16
  __shared__ float RmS[NT], RsS[NT];
  __shared__ float Cs[16][17];
  __shared__ float CsI[MT];
  const int t = threadIdx.x;
  const int b = blockIdx.y;
  const int mBase = blockIdx.x * MT;
  const float* Qb_ = Q + (size_t)b * kN * kH;
  const bf16* Vb_ = V + (size_t)b * kC * kN;
  const int ml = t & 15, ng = t >> 4;   // phase-1 mapping (ng 0..15)
  const int lane = t & 63, wv = t >> 6; // wave id 0..3
  const int fr = lane & 15, fq = lane >> 4;  // fragment row/quad
  // my column's Q (fp32, registers)
  float qc[kH];
  {
    const float4* qp = (const float4*)(Qb_ + (size_t)(mBase + ml) * kH);
#pragma unroll
    for (int h4 = 0; h4 < kH / 4; ++h4) {
      const float4 v = qp[h4];
      qc[4 * h4] = v.x; qc[4 * h4 + 1] = v.y; qc[4 * h4 + 2] = v.z; qc[4 * h4 + 3] = v.w;
    }
  }
  f32x4 acc[4] = {{0.f, 0.f, 0.f, 0.f}, {0.f, 0.f, 0.f, 0.f},
                  {0.f, 0.f, 0.f, 0.f}, {0.f, 0.f, 0.f, 0.f}};
  float csloc = 0.f;
  const int vc = t >> 2, vq = t & 3;  // V staging: 4 iters x 64 c-rows
  for (int n0 = 0; n0 < kN; n0 += NT) {
    __syncthreads();  // previous tile's MFMA reads done
    {                 // stage Q tile [32n][64h] fp32
      const int rr = t >> 3, hh = (t & 7) * 8;
      const float* qp = Qb_ + (size_t)(n0 + rr) * kH + hh;
      *(float4*)&QnS[rr][hh] = *(const float4*)qp;
      *(float4*)&QnS[rr][hh + 4] = *(const float4*)(qp + 4);
    }
    if (t < NT) {
      RmS[t] = rmx[(size_t)b * kN + n0 + t];
      RsS[t] = rsn[(size_t)b * kN + n0 + t];
    }
#pragma unroll
    for (int it = 0; it < 4; ++it) {  // stage V tile [256c][32n] bf16, no transpose
      const int c = it * 64 + vc;
      const uint4 vv = *(const uint4*)(Vb_ + (size_t)c * kN + n0 + vq * 8);
      *(uint4*)&Vs[c][vq * 8] = vv;
    }
    __syncthreads();
    // phase 1: e + softmax weights for (32 n) x (16 m); write P[m][n] bf16
#pragma unroll
    for (int half = 0; half < 2; ++half) {
      const int n = ng + half * 16;
      float e = 0.f;
#pragma unroll
      for (int h4 = 0; h4 < kH / 4; ++h4) {
        const float4 v = *(const float4*)&QnS[n][h4 * 4];
        e += qc[4 * h4] * v.x + qc[4 * h4 + 1] * v.y + qc[4 * h4 + 2] * v.z + qc[4 * h4 + 3] * v.w;
      }
      const float p = __expf(e - RmS[n]) * RsS[n];
      Pl[ml][n] = f2bu(p);
      csloc += p;
    }
    __syncthreads();
    // phase 2: MFMA. wave wv covers c = wv*64 .. wv*64+63 (4 subtiles of 16)
    const bf16x8 bfrag = *(const bf16x8*)&Pl[fr][fq * 8];
#pragma unroll
    for (int s = 0; s < 4; ++s) {
      const int c = wv * 64 + s * 16 + fr;
      const bf16x8 afrag = *(const bf16x8*)&Vs[c][fq * 8];
      acc[s] = __builtin_amdgcn_mfma_f32_16x16x32_bf16(afrag, bfrag, acc[s], 0, 0, 0);
    }
  }
  // column-sum reduce across the 16 ng groups
  __syncthreads();
  Cs[ng][ml] = csloc;
  __syncthreads();
  if (t < MT) {
    float cs = 0.f;
#pragma unroll
    for (int k = 0; k < 16; ++k) cs += Cs[k][t];
    CsI[t] = 1.f / (1e-9f + cs);
  }
  __syncthreads();
  // epilogue: D layout col=lane&15 (m), row=(lane>>4)*4+reg (c within 16)
  const float inv = CsI[fr];
  const float* xb = x + (size_t)b * kC * kN;
  float* ub = u + (size_t)b * kC * kN;
#pragma unroll
  for (int s = 0; s < 4; ++s) {
#pragma unroll
    for (int r = 0; r < 4; ++r) {
      const int c = wv * 64 + s * 16 + fq * 4 + r;
      const float xv = xb[(size_t)c * kN + mBase + fr];
      ub[(size_t)c * kN + mBase + fr] = xv - acc[s][r] * inv;
    }
  }
}

// ---------------------------------------------------------------------------
// BN stats per channel over (B, N), fp32 input, biased var.
// ---------------------------------------------------------------------------
__global__ __launch_bounds__(256) void k_bnstats(const float* __restrict__ y, int nch,
                                                 float* __restrict__ mean,
                                                 float* __restrict__ rsig) {
  const int c = blockIdx.x, t = threadIdx.x;
  float s = 0.f, s2 = 0.f;
  for (int b = 0; b < kB; ++b) {
    const float* p = y + ((size_t)b * nch + c) * kN;
    for (int n = t; n < kN; n += 256) {
      const float v = p[n];
      s += v;
      s2 += v * v;
    }
  }
  __shared__ float r1[256], r2[256];
  r1[t] = s;
  r2[t] = s2;
  __syncthreads();
  for (int k = 128; k > 0; k >>= 1) {
    if (t < k) {
      r1[t] += r1[t + k];
      r2[t] += r2[t + k];
    }
    __syncthreads();
  }
  if (t == 0) {
    const float im = 1.f / (float)(kB * kN);
    const float m = r1[0] * im;
    const float var = r2[0] * im - m * m;
    mean[c] = m;
    rsig[c] = rsqrtf(var + 1e-5f);
  }
}

// ---------------------------------------------------------------------------
// p += leaky(g*(y-mean)*rsig + b)    (in-place residual update, all fp32)
// ---------------------------------------------------------------------------
__global__ __launch_bounds__(256) void k_bnapply(const float* __restrict__ y,
                                                 float* __restrict__ p,
                                                 const float* __restrict__ mean,
                                                 const float* __restrict__ rsig,
                                                 const float* __restrict__ g,
                                                 const float* __restrict__ bb) {
  const size_t i = (size_t)blockIdx.x * 256 + threadIdx.x;
  const int c = (int)((i / kN) % kC);
  float z = g[c] * (y[i] - mean[c]) * rsig[c] + bb[c];
  z = z > 0.f ? z : 0.2f * z;
  p[i] = p[i] + z;
}

// ---------------------------------------------------------------------------
// dc2: tpre[b,j,n] = dc2_b[j] + sum_c dc2_w[j,c] * leaky(bn(h[b,c,n]))
// ---------------------------------------------------------------------------
__global__ __launch_bounds__(256) void k_dc2(const float* __restrict__ h,
                                             const float* __restrict__ mean,
                                             const float* __restrict__ rsig,
                                             const float* __restrict__ g,
                                             const float* __restrict__ bb,
                                             const float* __restrict__ w,
                                             const float* __restrict__ d2b,
                                             float* __restrict__ tpre) {
  __shared__ float wS[3][kC];
  __shared__ float aS[kC], cS[kC];
  const int t = threadIdx.x, b = blockIdx.y;
  const int n = blockIdx.x * 256 + t;
  {
    const float a = g[t] * rsig[t];
    aS[t] = a;
    cS[t] = bb[t] - a * mean[t];
    wS[0][t] = w[t];
    wS[1][t] = w[kC + t];
    wS[2][t] = w[2 * kC + t];
  }
  __syncthreads();
  float a0 = d2b[0], a1 = d2b[1], a2 = d2b[2];
  const float* hb = h + (size_t)b * kC * kN + n;
  for (int c = 0; c < kC; ++c) {
    float z = hb[(size_t)c * kN] * aS[c] + cS[c];
    z = z > 0.f ? z : 0.2f * z;
    a0 += wS[0][c] * z;
    a1 += wS[1][c] * z;
    a2 += wS[2][c] * z;
  }
  tpre[((size_t)b * 3 + 0) * kN + n] = a0;
  tpre[((size_t)b * 3 + 1) * kN + n] = a1;
  tpre[((size_t)b * 3 + 2) * kN + n] = a2;
}

// ---------------------------------------------------------------------------
// Final: out[b,n,j] = tanh(g[j]*(tpre[b,j,n]-mean[j])*rsig[j] + b[j])
// ---------------------------------------------------------------------------
__global__ __launch_bounds__(256) void k_final(const float* __restrict__ tpre,
                                               const float* __restrict__ mean,
                                               const float* __restrict__ rsig,
                                               const float* __restrict__ g,
                                               const float* __restrict__ bb,
                                               float* __restrict__ out) {
  const int i = blockIdx.x * 256 + threadIdx.x;  // over B*N
  const int n = i & (kN - 1), b = i >> 11;
#pragma unroll
  for (int j = 0; j < 3; ++j) {
    const float v = tpre[((size_t)b * 3 + j) * kN + n];
    const float z = g[j] * (v - mean[j]) * rsig[j] + bb[j];
    out[(size_t)i * 3 + j] = tanhf(z);
  }
}

// ---------------------------------------------------------------------------
extern "C" void kernel_launch(void* const* d_in, const int* in_sizes, int n_in,
                              void* d_out, int out_size, void* d_ws, size_t ws_size,
                              hipStream_t stream) {
  const float* feature  = (const float*)d_in[0];
  const float* prior    = (const float*)d_in[1];
  const float* mlp_w    = (const float*)d_in[2];
  const float* mlp_b    = (const float*)d_in[3];
  const float* qk_w     = (const float*)d_in[4];
  const float* qk_b     = (const float*)d_in[5];
  const float* v_w      = (const float*)d_in[6];
  const float* v_b      = (const float*)d_in[7];
  const float* t_w      = (const float*)d_in[8];
  const float* t_b      = (const float*)d_in[9];
  const float* bn_g     = (const float*)d_in[10];
  const float* bn_b     = (const float*)d_in[11];
  const float* dc1_w    = (const float*)d_in[12];
  const float* dc1_bn_g = (const float*)d_in[13];
  const float* dc1_bn_b = (const float*)d_in[14];
  const float* dc2_w    = (const float*)d_in[15];
  const float* dc2_b    = (const float*)d_in[16];
  const float* dc2_bn_g = (const float*)d_in[17];
  const float* dc2_bn_b = (const float*)d_in[18];
  float* out = (float*)d_out;

  // Workspace carve. Total ~126.6 MB (fits 128 MiB).
  char* base = (char*)d_ws;
  size_t off = 0;
  auto carve = [&](size_t bytes) {
    char* p = base + off;
    off += (bytes + 255) & ~(size_t)255;
    return p;
  };
  float* p    = (float*)carve((size_t)kB * kC * kN * 4);  // residual (fp32) 33.6 MB
  float* hacc = (float*)carve((size_t)kB * kC * kN * 4);  // dc1 accumulator 33.6 MB
  float* U    = (float*)carve((size_t)kB * kC * kN * 4);  // u/Y (in-place)  33.6 MB
  float* Qb   = (float*)carve((size_t)kB * kN * kH * 4);  // Q [B][N][64]     8.4 MB
  bf16*  Vb   = (bf16*)carve((size_t)kB * kC * kN * 2);   // V bf16          16.8 MB
  float* rmx  = (float*)carve((size_t)kB * kN * 4);
  float* rsn  = (float*)carve((size_t)kB * kN * 4);
  float* fb   = (float*)carve((size_t)kB * kC * 4);
  float* bnm  = (float*)carve(kC * 4);
  float* bnr  = (float*)carve(kC * 4);
  float* tpre = (float*)carve((size_t)kB * 3 * kN * 4);

  k_fb<<<kB * kC, 256, 0, stream>>>(feature, mlp_w, mlp_b, fb);
  k_p0<<<(kB * kC * kN) / 256, 256, 0, stream>>>(prior, mlp_w, fb, p);

  const dim3 gFC(kN / 32, kB);
  for (int l = 0; l < 4; ++l) {
    k_fc<kH, 0><<<gFC, 256, 0, stream>>>(p, qk_w + (size_t)l * kH * kC, kC,
                                         qk_b + l * kH, Qb, 0);
    k_fc<kC, 1><<<gFC, 256, 0, stream>>>(p, v_w + (size_t)l * kC * kC, kC,
                                         v_b + l * kC, Vb, 0);
    k_rowstats<<<dim3(kN / 64, kB), 256, 0, stream>>>(Qb, rmx, rsn);
    k_colpass<<<dim3(kN / 16, kB), 256, 0, stream>>>(Qb, Vb, rmx, rsn, p, U);
    k_fc<kC, 2><<<gFC, 256, 0, stream>>>(U, t_w + (size_t)l * kC * kC, kC,
                                         t_b + l * kC, U, 0);  // in-place Y
    k_bnstats<<<kC, 256, 0, stream>>>(U, kC, bnm, bnr);
    k_bnapply<<<(kB * kC * kN) / 256, 256, 0, stream>>>(
        U, p, bnm, bnr, bn_g + l * kC, bn_b + l * kC);
    k_fc<kC, 3><<<gFC, 256, 0, stream>>>(p, dc1_w + (size_t)l * kC, 4 * kC,
                                         nullptr, hacc, l == 0 ? 1 : 0);
  }

  k_bnstats<<<kC, 256, 0, stream>>>(hacc, kC, bnm, bnr);
  k_dc2<<<dim3(kN / 256, kB), 256, 0, stream>>>(hacc, bnm, bnr, dc1_bn_g, dc1_bn_b,
                                                dc2_w, dc2_b, tpre);
  k_bnstats<<<3, 256, 0, stream>>>(tpre, 3, bnm, bnr);
  k_final<<<(kB * kN) / 256, 256, 0, stream>>>(tpre, bnm, bnr, dc2_bn_g, dc2_bn_b, out);
}

// Round 6
// 2903.702 us; speedup vs baseline: 4.2076x; 1.2776x over previous
//
#include <hip/hip_runtime.h>
#include <hip/hip_bf16.h>

typedef __hip_bfloat16 bf16;
typedef unsigned short ushort_t;

// Problem constants
constexpr int kB = 16;    // batch
constexpr int kN = 2048;  // points
constexpr int kF = 1024;  // feat dims
constexpr int kC = 256;   // channels
constexpr int kH = 64;    // head dim

using f32x4 = __attribute__((ext_vector_type(4))) float;
using bf16x8 = __attribute__((ext_vector_type(8))) short;  // 8 bf16 (4 VGPRs)

__device__ __forceinline__ float us2f(unsigned short u) {
  union { unsigned int i; float f; } w;
  w.i = ((unsigned int)u) << 16;
  return w.f;
}
__device__ __forceinline__ unsigned short f2bu(float f) {
  union { bf16 h; unsigned short s; } u;
  u.h = __float2bfloat16(f);
  return u.s;
}

// ---------------------------------------------------------------------------
// fb[b,c] = mlp_b[c] + sum_f mlp_w[c,f] * feature[b,f]
// ---------------------------------------------------------------------------
__global__ __launch_bounds__(256) void k_fb(const float* __restrict__ feat,
                                            const float* __restrict__ mlp_w,
                                            const float* __restrict__ mlp_b,
                                            float* __restrict__ fb) {
  const int b = blockIdx.x >> 8;
  const int c = blockIdx.x & 255;
  const int t = threadIdx.x;
  const float* wr = mlp_w + (size_t)c * (kF + 3);
  const float* fr = feat + (size_t)b * kF;
  float s = 0.f;
  for (int f = t; f < kF; f += 256) s += wr[f] * fr[f];
  __shared__ float red[256];
  red[t] = s;
  __syncthreads();
  for (int k = 128; k > 0; k >>= 1) {
    if (t < k) red[t] += red[t + k];
    __syncthreads();
  }
  if (t == 0) fb[blockIdx.x] = red[0] + mlp_b[c];
}

// ---------------------------------------------------------------------------
// p[b,c,n] = fb[b,c] + sum_{j<3} mlp_w[c,1024+j] * prior[b,j,n]   (fp32)
// ---------------------------------------------------------------------------
__global__ __launch_bounds__(256) void k_p0(const float* __restrict__ prior,
                                            const float* __restrict__ mlp_w,
                                            const float* __restrict__ fb,
                                            float* __restrict__ p) {
  const size_t i = (size_t)blockIdx.x * 256 + threadIdx.x;  // over B*C*N
  const int n = (int)(i % kN);
  const size_t bc = i / kN;
  const int b = (int)(bc / kC);
  const int c = (int)(bc % kC);
  const float* pr = prior + (size_t)b * 3 * kN + n;
  const float* wr = mlp_w + (size_t)c * (kF + 3) + kF;
  p[i] = fb[bc] + wr[0] * pr[0] + wr[1] * pr[kN] + wr[2] * pr[2 * kN];
}

// ---------------------------------------------------------------------------
// Full-column 1x1 conv: y[b,o,n] = bias[o] + sum_{c<256} w[o,c]*x[b,c,n]
// OMODE: 0 = split-bf16 Q transposed [b][n][64] hi+lo; 1 = bf16 [b][o][N];
//        2 = fp32 [b][o][N] (may alias x); 3 = fp32 accumulate.
// ---------------------------------------------------------------------------
template <int O, int OMODE>
__global__ __launch_bounds__(256) void k_fc(const float* __restrict__ x,
                                            const float* __restrict__ w, int wstride,
                                            const float* __restrict__ bias,
                                            void* __restrict__ yv,
                                            void* __restrict__ yv2, int first) {
  constexpr int OT = O / 16;  // outputs per thread (16 or 4)
  __shared__ float Xs[32][257];
  __shared__ float Ws[16][O];
  const int t = threadIdx.x;
  const int b = blockIdx.y;
  const int n0 = blockIdx.x * 32;
  const float* xb = x + (size_t)b * kC * kN + n0;
  {  // load X panel [256c][32n] -> Xs[n][c]
    const int n4 = t & 7;
    const int cg = t >> 3;
#pragma unroll
    for (int it = 0; it < 8; ++it) {
      const int c = it * 32 + cg;
      const float4 v = *(const float4*)(xb + (size_t)c * kN + n4 * 4);
      Xs[n4 * 4 + 0][c] = v.x;
      Xs[n4 * 4 + 1][c] = v.y;
      Xs[n4 * 4 + 2][c] = v.z;
      Xs[n4 * 4 + 3][c] = v.w;
    }
  }
  const int tn = t & 15, to = t >> 4;
  float acc[OT][2] = {};
  for (int c0 = 0; c0 < kC; c0 += 16) {
    __syncthreads();  // protect Ws from previous chunk's readers
    if (O == 256 || t < O) {
      const float* wr = w + (size_t)t * wstride + c0;
      const float4 a = *(const float4*)(wr);
      const float4 b4 = *(const float4*)(wr + 4);
      const float4 c4 = *(const float4*)(wr + 8);
      const float4 d4 = *(const float4*)(wr + 12);
      Ws[0][t] = a.x;  Ws[1][t] = a.y;  Ws[2][t] = a.z;  Ws[3][t] = a.w;
      Ws[4][t] = b4.x; Ws[5][t] = b4.y; Ws[6][t] = b4.z; Ws[7][t] = b4.w;
      Ws[8][t] = c4.x; Ws[9][t] = c4.y; Ws[10][t] = c4.z; Ws[11][t] = c4.w;
      Ws[12][t] = d4.x; Ws[13][t] = d4.y; Ws[14][t] = d4.z; Ws[15][t] = d4.w;
    }
    __syncthreads();
#pragma unroll
    for (int cc = 0; cc < 16; ++cc) {
      const float xa = Xs[2 * tn + 0][c0 + cc];
      const float xc2 = Xs[2 * tn + 1][c0 + cc];
#pragma unroll
      for (int q = 0; q < OT / 4; ++q) {
        const float4 wv = *(const float4*)&Ws[cc][to * OT + q * 4];
        acc[q * 4 + 0][0] += wv.x * xa; acc[q * 4 + 0][1] += wv.x * xc2;
        acc[q * 4 + 1][0] += wv.y * xa; acc[q * 4 + 1][1] += wv.y * xc2;
        acc[q * 4 + 2][0] += wv.z * xa; acc[q * 4 + 2][1] += wv.z * xc2;
        acc[q * 4 + 3][0] += wv.w * xa; acc[q * 4 + 3][1] += wv.w * xc2;
      }
    }
  }
  const int n = n0 + 2 * tn;
  if (OMODE == 0) {  // Q split-bf16 transposed [b][n][64]
    ushort_t* yh = (ushort_t*)yv;
    ushort_t* yl = (ushort_t*)yv2;
#pragma unroll
    for (int i = 0; i < OT; ++i) {
      const int o = to * OT + i;
      const float bz = bias[o];
#pragma unroll
      for (int j = 0; j < 2; ++j) {
        const float v = acc[i][j] + bz;
        const ushort_t h = f2bu(v);
        const ushort_t l = f2bu(v - us2f(h));
        yh[((size_t)b * kN + n + j) * kH + o] = h;
        yl[((size_t)b * kN + n + j) * kH + o] = l;
      }
    }
  } else if (OMODE == 1) {  // V bf16 [b][o][N]
    bf16* y = (bf16*)yv;
#pragma unroll
    for (int i = 0; i < OT; ++i) {
      const int o = to * OT + i;
      const float bz = bias[o];
      ushort2 u2;
      u2.x = f2bu(acc[i][0] + bz);
      u2.y = f2bu(acc[i][1] + bz);
      *(ushort2*)(y + ((size_t)b * kC + o) * kN + n) = u2;
    }
  } else if (OMODE == 2) {  // fp32 [b][o][N], may alias x (panel is in LDS)
    float* y = (float*)yv;
#pragma unroll
    for (int i = 0; i < OT; ++i) {
      const int o = to * OT + i;
      const float bz = bias[o];
      *(float2*)(y + ((size_t)b * kC + o) * kN + n) =
          make_float2(acc[i][0] + bz, acc[i][1] + bz);
    }
  } else {  // fp32 accumulate (dc1)
    float* y = (float*)yv;
#pragma unroll
    for (int i = 0; i < OT; ++i) {
      const int o = to * OT + i;
      float2* p2 = (float2*)(y + ((size_t)b * kC + o) * kN + n);
      if (first) {
        *p2 = make_float2(acc[i][0], acc[i][1]);
      } else {
        const float2 old = *p2;
        *p2 = make_float2(old.x + acc[i][0], old.y + acc[i][1]);
      }
    }
  }
}

// ---------------------------------------------------------------------------
// Row softmax stats via split-bf16 MFMA: e = Qhi·Qhi^T + Qhi·Qlo^T + Qlo·Qhi^T.
// Block: 64 rows (4 waves x 16), col tiles of 64 staged in LDS, online softmax.
// ---------------------------------------------------------------------------
__global__ __launch_bounds__(256) void k_rowstats(const ushort_t* __restrict__ Qhi,
                                                  const ushort_t* __restrict__ Qlo,
                                                  float* __restrict__ rmx,
                                                  float* __restrict__ rsn) {
  __shared__ __align__(16) ushort_t Bh[64][72];
  __shared__ __align__(16) ushort_t Bl[64][72];
  const int b = blockIdx.y, t = threadIdx.x;
  const int r0 = blockIdx.x * 64;
  const int lane = t & 63, w = t >> 6;
  const int fr = lane & 15, fq = lane >> 4;
  const size_t qbase = (size_t)b * kN * kH;
  // A fragments: rows r0 + w*16 + fr, two K=32 steps
  bf16x8 ah0, ah1, al0, al1;
  {
    const ushort_t* qh = Qhi + qbase + (size_t)(r0 + w * 16 + fr) * kH;
    const ushort_t* ql = Qlo + qbase + (size_t)(r0 + w * 16 + fr) * kH;
    ah0 = *(const bf16x8*)(qh + fq * 8);
    ah1 = *(const bf16x8*)(qh + 32 + fq * 8);
    al0 = *(const bf16x8*)(ql + fq * 8);
    al1 = *(const bf16x8*)(ql + 32 + fq * 8);
  }
  float mx[4] = {-3.0e38f, -3.0e38f, -3.0e38f, -3.0e38f};
  float sm[4] = {0.f, 0.f, 0.f, 0.f};
  const int srow = t >> 2, scol = (t & 3) * 16;  // staging map
  for (int m0 = 0; m0 < kN; m0 += 64) {
    __syncthreads();  // previous tile's consumers done
    {                 // stage col tile hi/lo: 64 rows x 64 k
      const ushort_t* qh = Qhi + qbase + (size_t)(m0 + srow) * kH + scol;
      const ushort_t* ql = Qlo + qbase + (size_t)(m0 + srow) * kH + scol;
      *(uint4*)&Bh[srow][scol] = *(const uint4*)qh;
      *(uint4*)&Bh[srow][scol + 8] = *(const uint4*)(qh + 8);
      *(uint4*)&Bl[srow][scol] = *(const uint4*)ql;
      *(uint4*)&Bl[srow][scol + 8] = *(const uint4*)(ql + 8);
    }
    __syncthreads();
    float ev[4][4];  // [cs][r]
#pragma unroll
    for (int cs = 0; cs < 4; ++cs) {
      const bf16x8 bh0 = *(const bf16x8*)&Bh[cs * 16 + fr][fq * 8];
      const bf16x8 bh1 = *(const bf16x8*)&Bh[cs * 16 + fr][32 + fq * 8];
      const bf16x8 bl0 = *(const bf16x8*)&Bl[cs * 16 + fr][fq * 8];
      const bf16x8 bl1 = *(const bf16x8*)&Bl[cs * 16 + fr][32 + fq * 8];
      f32x4 e = {0.f, 0.f, 0.f, 0.f};
      e = __builtin_amdgcn_mfma_f32_16x16x32_bf16(ah0, bh0, e, 0, 0, 0);
      e = __builtin_amdgcn_mfma_f32_16x16x32_bf16(ah1, bh1, e, 0, 0, 0);
      e = __builtin_amdgcn_mfma_f32_16x16x32_bf16(ah0, bl0, e, 0, 0, 0);
      e = __builtin_amdgcn_mfma_f32_16x16x32_bf16(ah1, bl1, e, 0, 0, 0);
      e = __builtin_amdgcn_mfma_f32_16x16x32_bf16(al0, bh0, e, 0, 0, 0);
      e = __builtin_amdgcn_mfma_f32_16x16x32_bf16(al1, bh1, e, 0, 0, 0);
      ev[cs][0] = e[0]; ev[cs][1] = e[1]; ev[cs][2] = e[2]; ev[cs][3] = e[3];
    }
#pragma unroll
    for (int r = 0; r < 4; ++r) {
      const float tmax = fmaxf(fmaxf(ev[0][r], ev[1][r]), fmaxf(ev[2][r], ev[3][r]));
      const float nm = fmaxf(mx[r], tmax);
      sm[r] = sm[r] * __expf(mx[r] - nm) + __expf(ev[0][r] - nm) + __expf(ev[1][r] - nm) +
              __expf(ev[2][r] - nm) + __expf(ev[3][r] - nm);
      mx[r] = nm;
    }
  }
  // merge across the 16 fr lanes (same fq group shares rows)
#pragma unroll
  for (int mask = 1; mask < 16; mask <<= 1) {
#pragma unroll
    for (int r = 0; r < 4; ++r) {
      const float om = __shfl_xor(mx[r], mask);
      const float os = __shfl_xor(sm[r], mask);
      const float nm = fmaxf(mx[r], om);
      sm[r] = sm[r] * __expf(mx[r] - nm) + os * __expf(om - nm);
      mx[r] = nm;
    }
  }
  if (fr == 0) {
#pragma unroll
    for (int r = 0; r < 4; ++r) {
      const int row = r0 + w * 16 + fq * 4 + r;
      rmx[(size_t)b * kN + row] = mx[r];
      rsn[(size_t)b * kN + row] = 1.f / sm[r];
    }
  }
}

// ---------------------------------------------------------------------------
// Column pass, fully MFMA: E via split-bf16 MFMA (waves 0-1), p=exp(e-rm)*rs
// (bf16), colsum; PV via bf16 MFMA (all 4 waves); u = x - x_r (fp32).
// ---------------------------------------------------------------------------
__global__ __launch_bounds__(256) void k_colpass(const ushort_t* __restrict__ Qhi,
                                                 const ushort_t* __restrict__ Qlo,
                                                 const bf16* __restrict__ V,
                                                 const float* __restrict__ rmx,
                                                 const float* __restrict__ rsn,
                                                 const float* __restrict__ x,
                                                 float* __restrict__ u) {
  constexpr int MT = 16, NT = 32;
  __shared__ __align__(16) ushort_t Anh[NT][72];   // Qn hi
  __shared__ __align__(16) ushort_t Anl[NT][72];   // Qn lo
  __shared__ __align__(16) ushort_t Vs[kC][40];    // V [c][n] bf16
  __shared__ __align__(16) ushort_t Pl[MT][40];    // P [m][n] bf16
  __shared__ float Cs[8][17];
  __shared__ float CsI[MT];
  const int t = threadIdx.x;
  const int b = blockIdx.y;
  const int mBase = blockIdx.x * MT;
  const size_t qbase = (size_t)b * kN * kH;
  const bf16* Vb_ = V + (size_t)b * kC * kN;
  const int lane = t & 63, wv = t >> 6;
  const int fr = lane & 15, fq = lane >> 4;
  // B fragments for the block's 16 m-columns (col = fr), two K=32 steps
  bf16x8 bmh0, bmh1, bml0, bml1;
  {
    const ushort_t* qh = Qhi + qbase + (size_t)(mBase + fr) * kH;
    const ushort_t* ql = Qlo + qbase + (size_t)(mBase + fr) * kH;
    bmh0 = *(const bf16x8*)(qh + fq * 8);
    bmh1 = *(const bf16x8*)(qh + 32 + fq * 8);
    bml0 = *(const bf16x8*)(ql + fq * 8);
    bml1 = *(const bf16x8*)(ql + 32 + fq * 8);
  }
  f32x4 acc[4] = {{0.f, 0.f, 0.f, 0.f}, {0.f, 0.f, 0.f, 0.f},
                  {0.f, 0.f, 0.f, 0.f}, {0.f, 0.f, 0.f, 0.f}};
  float csloc = 0.f;
  const int arow = t >> 3, acol = (t & 7) * 8;  // Qn staging map
  const int vc = t >> 2, vq = t & 3;            // V staging map
  for (int n0 = 0; n0 < kN; n0 += NT) {
    __syncthreads();  // previous tile's MFMA reads done
    {                 // stage Qn tile hi/lo [32n][64k]
      *(uint4*)&Anh[arow][acol] = *(const uint4*)(Qhi + qbase + (size_t)(n0 + arow) * kH + acol);
      *(uint4*)&Anl[arow][acol] = *(const uint4*)(Qlo + qbase + (size_t)(n0 + arow) * kH + acol);
    }
#pragma unroll
    for (int it = 0; it < 4; ++it) {  // stage V tile [256c][32n] bf16
      const int c = it * 64 + vc;
      *(uint4*)&Vs[c][vq * 8] = *(const uint4*)(Vb_ + (size_t)c * kN + n0 + vq * 8);
    }
    __syncthreads();
    // phase 1 (waves 0,1): E[n-half][m] via 6 MFMA, then p
    if (wv < 2) {
      const bf16x8 ah0 = *(const bf16x8*)&Anh[wv * 16 + fr][fq * 8];
      const bf16x8 ah1 = *(const bf16x8*)&Anh[wv * 16 + fr][32 + fq * 8];
      const bf16x8 al0 = *(const bf16x8*)&Anl[wv * 16 + fr][fq * 8];
      const bf16x8 al1 = *(const bf16x8*)&Anl[wv * 16 + fr][32 + fq * 8];
      f32x4 e = {0.f, 0.f, 0.f, 0.f};
      e = __builtin_amdgcn_mfma_f32_16x16x32_bf16(ah0, bmh0, e, 0, 0, 0);
      e = __builtin_amdgcn_mfma_f32_16x16x32_bf16(ah1, bmh1, e, 0, 0, 0);
      e = __builtin_amdgcn_mfma_f32_16x16x32_bf16(ah0, bml0, e, 0, 0, 0);
      e = __builtin_amdgcn_mfma_f32_16x16x32_bf16(ah1, bml1, e, 0, 0, 0);
      e = __builtin_amdgcn_mfma_f32_16x16x32_bf16(al0, bmh0, e, 0, 0, 0);
      e = __builtin_amdgcn_mfma_f32_16x16x32_bf16(al1, bmh1, e, 0, 0, 0);
      // D: col m = mBase+fr, row n-local = wv*16 + fq*4 + r
#pragma unroll
      for (int r = 0; r < 4; ++r) {
        const int nl = wv * 16 + fq * 4 + r;
        const size_t gn = (size_t)b * kN + n0 + nl;
        const float p = __expf(e[r] - rmx[gn]) * rsn[gn];
        Pl[fr][nl] = f2bu(p);
        csloc += p;
      }
    }
    __syncthreads();
    // phase 2 (all waves): PV. wave wv covers c = wv*64 .. +63
    const bf16x8 bfrag = *(const bf16x8*)&Pl[fr][fq * 8];
#pragma unroll
    for (int s = 0; s < 4; ++s) {
      const int c = wv * 64 + s * 16 + fr;
      const bf16x8 afrag = *(const bf16x8*)&Vs[c][fq * 8];
      acc[s] = __builtin_amdgcn_mfma_f32_16x16x32_bf16(afrag, bfrag, acc[s], 0, 0, 0);
    }
  }
  // column-sum reduce: waves 0-1 lanes hold partials for col fr
  __syncthreads();
  if (wv < 2) Cs[wv * 4 + fq][fr] = csloc;
  __syncthreads();
  if (t < MT) {
    float cs = 0.f;
#pragma unroll
    for (int k = 0; k < 8; ++k) cs += Cs[k][t];
    CsI[t] = 1.f / (1e-9f + cs);
  }
  __syncthreads();
  // epilogue: D layout col m = fr, row c-local = fq*4 + r
  const float inv = CsI[fr];
  const float* xb = x + (size_t)b * kC * kN;
  float* ub = u + (size_t)b * kC * kN;
#pragma unroll
  for (int s = 0; s < 4; ++s) {
#pragma unroll
    for (int r = 0; r < 4; ++r) {
      const int c = wv * 64 + s * 16 + fq * 4 + r;
      const float xv = xb[(size_t)c * kN + mBase + fr];
      ub[(size_t)c * kN + mBase + fr] = xv - acc[s][r] * inv;
    }
  }
}

// ---------------------------------------------------------------------------
// BN stats per channel over (B, N), fp32 input, biased var.
// ---------------------------------------------------------------------------
__global__ __launch_bounds__(256) void k_bnstats(const float* __restrict__ y, int nch,
                                                 float* __restrict__ mean,
                                                 float* __restrict__ rsig) {
  const int c = blockIdx.x, t = threadIdx.x;
  float s = 0.f, s2 = 0.f;
  for (int b = 0; b < kB; ++b) {
    const float* p = y + ((size_t)b * nch + c) * kN;
    for (int n = t; n < kN; n += 256) {
      const float v = p[n];
      s += v;
      s2 += v * v;
    }
  }
  __shared__ float r1[256], r2[256];
  r1[t] = s;
  r2[t] = s2;
  __syncthreads();
  for (int k = 128; k > 0; k >>= 1) {
    if (t < k) {
      r1[t] += r1[t + k];
      r2[t] += r2[t + k];
    }
    __syncthreads();
  }
  if (t == 0) {
    const float im = 1.f / (float)(kB * kN);
    const float m = r1[0] * im;
    const float var = r2[0] * im - m * m;
    mean[c] = m;
    rsig[c] = rsqrtf(var + 1e-5f);
  }
}

// ---------------------------------------------------------------------------
// p += leaky(g*(y-mean)*rsig + b)    (in-place residual update, all fp32)
// ---------------------------------------------------------------------------
__global__ __launch_bounds__(256) void k_bnapply(const float* __restrict__ y,
                                                 float* __restrict__ p,
                                                 const float* __restrict__ mean,
                                                 const float* __restrict__ rsig,
                                                 const float* __restrict__ g,
                                                 const float* __restrict__ bb) {
  const size_t i = (size_t)blockIdx.x * 256 + threadIdx.x;
  const int c = (int)((i / kN) % kC);
  float z = g[c] * (y[i] - mean[c]) * rsig[c] + bb[c];
  z = z > 0.f ? z : 0.2f * z;
  p[i] = p[i] + z;
}

// ---------------------------------------------------------------------------
// dc2: tpre[b,j,n] = dc2_b[j] + sum_c dc2_w[j,c] * leaky(bn(h[b,c,n]))
// ---------------------------------------------------------------------------
__global__ __launch_bounds__(256) void k_dc2(const float* __restrict__ h,
                                             const float* __restrict__ mean,
                                             const float* __restrict__ rsig,
                                             const float* __restrict__ g,
                                             const float* __restrict__ bb,
                                             const float* __restrict__ w,
                                             const float* __restrict__ d2b,
                                             float* __restrict__ tpre) {
  __shared__ float wS[3][kC];
  __shared__ float aS[kC], cS[kC];
  const int t = threadIdx.x, b = blockIdx.y;
  const int n = blockIdx.x * 256 + t;
  {
    const float a = g[t] * rsig[t];
    aS[t] = a;
    cS[t] = bb[t] - a * mean[t];
    wS[0][t] = w[t];
    wS[1][t] = w[kC + t];
    wS[2][t] = w[2 * kC + t];
  }
  __syncthreads();
  float a0 = d2b[0], a1 = d2b[1], a2 = d2b[2];
  const float* hb = h + (size_t)b * kC * kN + n;
  for (int c = 0; c < kC; ++c) {
    float z = hb[(size_t)c * kN] * aS[c] + cS[c];
    z = z > 0.f ? z : 0.2f * z;
    a0 += wS[0][c] * z;
    a1 += wS[1][c] * z;
    a2 += wS[2][c] * z;
  }
  tpre[((size_t)b * 3 + 0) * kN + n] = a0;
  tpre[((size_t)b * 3 + 1) * kN + n] = a1;
  tpre[((size_t)b * 3 + 2) * kN + n] = a2;
}

// ---------------------------------------------------------------------------
// Final: out[b,n,j] = tanh(g[j]*(tpre[b,j,n]-mean[j])*rsig[j] + b[j])
// ---------------------------------------------------------------------------
__global__ __launch_bounds__(256) void k_final(const float* __restrict__ tpre,
                                               const float* __restrict__ mean,
                                               const float* __restrict__ rsig,
                                               const float* __restrict__ g,
                                               const float* __restrict__ bb,
                                               float* __restrict__ out) {
  const int i = blockIdx.x * 256 + threadIdx.x;  // over B*N
  const int n = i & (kN - 1), b = i >> 11;
#pragma unroll
  for (int j = 0; j < 3; ++j) {
    const float v = tpre[((size_t)b * 3 + j) * kN + n];
    const float z = g[j] * (v - mean[j]) * rsig[j] + bb[j];
    out[(size_t)i * 3 + j] = tanhf(z);
  }
}

// ---------------------------------------------------------------------------
extern "C" void kernel_launch(void* const* d_in, const int* in_sizes, int n_in,
                              void* d_out, int out_size, void* d_ws, size_t ws_size,
                              hipStream_t stream) {
  const float* feature  = (const float*)d_in[0];
  const float* prior    = (const float*)d_in[1];
  const float* mlp_w    = (const float*)d_in[2];
  const float* mlp_b    = (const float*)d_in[3];
  const float* qk_w     = (const float*)d_in[4];
  const float* qk_b     = (const float*)d_in[5];
  const float* v_w      = (const float*)d_in[6];
  const float* v_b      = (const float*)d_in[7];
  const float* t_w      = (const float*)d_in[8];
  const float* t_b      = (const float*)d_in[9];
  const float* bn_g     = (const float*)d_in[10];
  const float* bn_b     = (const float*)d_in[11];
  const float* dc1_w    = (const float*)d_in[12];
  const float* dc1_bn_g = (const float*)d_in[13];
  const float* dc1_bn_b = (const float*)d_in[14];
  const float* dc2_w    = (const float*)d_in[15];
  const float* dc2_b    = (const float*)d_in[16];
  const float* dc2_bn_g = (const float*)d_in[17];
  const float* dc2_bn_b = (const float*)d_in[18];
  float* out = (float*)d_out;

  // Workspace carve. Total ~126.5 MB (fits 128 MiB).
  char* base = (char*)d_ws;
  size_t off = 0;
  auto carve = [&](size_t bytes) {
    char* p = base + off;
    off += (bytes + 255) & ~(size_t)255;
    return p;
  };
  float*    p    = (float*)carve((size_t)kB * kC * kN * 4);   // residual     33.6 MB
  float*    hacc = (float*)carve((size_t)kB * kC * kN * 4);   // dc1 acc      33.6 MB
  float*    U    = (float*)carve((size_t)kB * kC * kN * 4);   // u/Y inplace  33.6 MB
  ushort_t* Qhi  = (ushort_t*)carve((size_t)kB * kN * kH * 2);// Q hi bf16     4.2 MB
  ushort_t* Qlo  = (ushort_t*)carve((size_t)kB * kN * kH * 2);// Q lo bf16     4.2 MB
  bf16*     Vb   = (bf16*)carve((size_t)kB * kC * kN * 2);    // V bf16       16.8 MB
  float*    rmx  = (float*)carve((size_t)kB * kN * 4);
  float*    rsn  = (float*)carve((size_t)kB * kN * 4);
  float*    fb   = (float*)carve((size_t)kB * kC * 4);
  float*    bnm  = (float*)carve(kC * 4);
  float*    bnr  = (float*)carve(kC * 4);
  float*    tpre = (float*)carve((size_t)kB * 3 * kN * 4);

  k_fb<<<kB * kC, 256, 0, stream>>>(feature, mlp_w, mlp_b, fb);
  k_p0<<<(kB * kC * kN) / 256, 256, 0, stream>>>(prior, mlp_w, fb, p);

  const dim3 gFC(kN / 32, kB);
  for (int l = 0; l < 4; ++l) {
    k_fc<kH, 0><<<gFC, 256, 0, stream>>>(p, qk_w + (size_t)l * kH * kC, kC,
                                         qk_b + l * kH, Qhi, Qlo, 0);
    k_fc<kC, 1><<<gFC, 256, 0, stream>>>(p, v_w + (size_t)l * kC * kC, kC,
                                         v_b + l * kC, Vb, nullptr, 0);
    k_rowstats<<<dim3(kN / 64, kB), 256, 0, stream>>>(Qhi, Qlo, rmx, rsn);
    k_colpass<<<dim3(kN / 16, kB), 256, 0, stream>>>(Qhi, Qlo, Vb, rmx, rsn, p, U);
    k_fc<kC, 2><<<gFC, 256, 0, stream>>>(U, t_w + (size_t)l * kC * kC, kC,
                                         t_b + l * kC, U, nullptr, 0);  // in-place
    k_bnstats<<<kC, 256, 0, stream>>>(U, kC, bnm, bnr);
    k_bnapply<<<(kB * kC * kN) / 256, 256, 0, stream>>>(
        U, p, bnm, bnr, bn_g + l * kC, bn_b + l * kC);
    k_fc<kC, 3><<<gFC, 256, 0, stream>>>(p, dc1_w + (size_t)l * kC, 4 * kC,
                                         nullptr, hacc, nullptr, l == 0 ? 1 : 0);
  }

  k_bnstats<<<kC, 256, 0, stream>>>(hacc, kC, bnm, bnr);
  k_dc2<<<dim3(kN / 256, kB), 256, 0, stream>>>(hacc, bnm, bnr, dc1_bn_g, dc1_bn_b,
                                                dc2_w, dc2_b, tpre);
  k_bnstats<<<3, 256, 0, stream>>>(tpre, 3, bnm, bnr);
  k_final<<<(kB * kN) / 256, 256, 0, stream>>>(tpre, bnm, bnr, dc2_bn_g, dc2_bn_b, out);
}

// Round 7
// 2170.173 us; speedup vs baseline: 5.6298x; 1.3380x over previous
//
#include <hip/hip_runtime.h>
#include <hip/hip_bf16.h>

typedef __hip_bfloat16 bf16;
typedef unsigned short ushort_t;

// Problem constants
constexpr int kB = 16;    // batch
constexpr int kN = 2048;  // points
constexpr int kF = 1024;  // feat dims
constexpr int kC = 256;   // channels
constexpr int kH = 64;    // head dim

using f32x4 = __attribute__((ext_vector_type(4))) float;
using bf16x8 = __attribute__((ext_vector_type(8))) short;  // 8 bf16 (4 VGPRs)

__device__ __forceinline__ float us2f(unsigned short u) {
  union { unsigned int i; float f; } w;
  w.i = ((unsigned int)u) << 16;
  return w.f;
}
__device__ __forceinline__ unsigned short f2bu(float f) {
  union { bf16 h; unsigned short s; } u;
  u.h = __float2bfloat16(f);
  return u.s;
}

// ---------------------------------------------------------------------------
// fb[b,c] = mlp_b[c] + sum_f mlp_w[c,f] * feature[b,f]
// ---------------------------------------------------------------------------
__global__ __launch_bounds__(256) void k_fb(const float* __restrict__ feat,
                                            const float* __restrict__ mlp_w,
                                            const float* __restrict__ mlp_b,
                                            float* __restrict__ fb) {
  const int b = blockIdx.x >> 8;
  const int c = blockIdx.x & 255;
  const int t = threadIdx.x;
  const float* wr = mlp_w + (size_t)c * (kF + 3);
  const float* fr = feat + (size_t)b * kF;
  float s = 0.f;
  for (int f = t; f < kF; f += 256) s += wr[f] * fr[f];
  __shared__ float red[256];
  red[t] = s;
  __syncthreads();
  for (int k = 128; k > 0; k >>= 1) {
    if (t < k) red[t] += red[t + k];
    __syncthreads();
  }
  if (t == 0) fb[blockIdx.x] = red[0] + mlp_b[c];
}

// ---------------------------------------------------------------------------
// p[b,c,n] = fb[b,c] + sum_{j<3} mlp_w[c,1024+j] * prior[b,j,n]   (fp32)
// ---------------------------------------------------------------------------
__global__ __launch_bounds__(256) void k_p0(const float* __restrict__ prior,
                                            const float* __restrict__ mlp_w,
                                            const float* __restrict__ fb,
                                            float* __restrict__ p) {
  const size_t i = (size_t)blockIdx.x * 256 + threadIdx.x;  // over B*C*N
  const int n = (int)(i % kN);
  const size_t bc = i / kN;
  const int b = (int)(bc / kC);
  const int c = (int)(bc % kC);
  const float* pr = prior + (size_t)b * 3 * kN + n;
  const float* wr = mlp_w + (size_t)c * (kF + 3) + kF;
  p[i] = fb[bc] + wr[0] * pr[0] + wr[1] * pr[kN] + wr[2] * pr[2 * kN];
}

// ---------------------------------------------------------------------------
// Full-column 1x1 conv: y[b,o,n] = bias[o] + sum_{c<256} w[o,c]*x[b,c,n]
// OMODE: 0 = split-bf16 Q transposed [b][n][64] hi+lo; 1 = bf16 [b][o][N];
//        2 = fp32 [b][o][N] (may alias x); 3 = fp32 accumulate.
// ---------------------------------------------------------------------------
template <int O, int OMODE>
__global__ __launch_bounds__(256) void k_fc(const float* __restrict__ x,
                                            const float* __restrict__ w, int wstride,
                                            const float* __restrict__ bias,
                                            void* __restrict__ yv,
                                            void* __restrict__ yv2, int first) {
  constexpr int OT = O / 16;  // outputs per thread (16 or 4)
  __shared__ float Xs[32][257];
  __shared__ float Ws[16][O];
  const int t = threadIdx.x;
  const int b = blockIdx.y;
  const int n0 = blockIdx.x * 32;
  const float* xb = x + (size_t)b * kC * kN + n0;
  {  // load X panel [256c][32n] -> Xs[n][c]
    const int n4 = t & 7;
    const int cg = t >> 3;
#pragma unroll
    for (int it = 0; it < 8; ++it) {
      const int c = it * 32 + cg;
      const float4 v = *(const float4*)(xb + (size_t)c * kN + n4 * 4);
      Xs[n4 * 4 + 0][c] = v.x;
      Xs[n4 * 4 + 1][c] = v.y;
      Xs[n4 * 4 + 2][c] = v.z;
      Xs[n4 * 4 + 3][c] = v.w;
    }
  }
  const int tn = t & 15, to = t >> 4;
  float acc[OT][2] = {};
  for (int c0 = 0; c0 < kC; c0 += 16) {
    __syncthreads();  // protect Ws from previous chunk's readers
    if (O == 256 || t < O) {
      const float* wr = w + (size_t)t * wstride + c0;
      const float4 a = *(const float4*)(wr);
      const float4 b4 = *(const float4*)(wr + 4);
      const float4 c4 = *(const float4*)(wr + 8);
      const float4 d4 = *(const float4*)(wr + 12);
      Ws[0][t] = a.x;  Ws[1][t] = a.y;  Ws[2][t] = a.z;  Ws[3][t] = a.w;
      Ws[4][t] = b4.x; Ws[5][t] = b4.y; Ws[6][t] = b4.z; Ws[7][t] = b4.w;
      Ws[8][t] = c4.x; Ws[9][t] = c4.y; Ws[10][t] = c4.z; Ws[11][t] = c4.w;
      Ws[12][t] = d4.x; Ws[13][t] = d4.y; Ws[14][t] = d4.z; Ws[15][t] = d4.w;
    }
    __syncthreads();
#pragma unroll
    for (int cc = 0; cc < 16; ++cc) {
      const float xa = Xs[2 * tn + 0][c0 + cc];
      const float xc2 = Xs[2 * tn + 1][c0 + cc];
#pragma unroll
      for (int q = 0; q < OT / 4; ++q) {
        const float4 wv = *(const float4*)&Ws[cc][to * OT + q * 4];
        acc[q * 4 + 0][0] += wv.x * xa; acc[q * 4 + 0][1] += wv.x * xc2;
        acc[q * 4 + 1][0] += wv.y * xa; acc[q * 4 + 1][1] += wv.y * xc2;
        acc[q * 4 + 2][0] += wv.z * xa; acc[q * 4 + 2][1] += wv.z * xc2;
        acc[q * 4 + 3][0] += wv.w * xa; acc[q * 4 + 3][1] += wv.w * xc2;
      }
    }
  }
  const int n = n0 + 2 * tn;
  if (OMODE == 0) {  // Q split-bf16 transposed [b][n][64]
    ushort_t* yh = (ushort_t*)yv;
    ushort_t* yl = (ushort_t*)yv2;
#pragma unroll
    for (int i = 0; i < OT; ++i) {
      const int o = to * OT + i;
      const float bz = bias[o];
#pragma unroll
      for (int j = 0; j < 2; ++j) {
        const float v = acc[i][j] + bz;
        const ushort_t h = f2bu(v);
        const ushort_t l = f2bu(v - us2f(h));
        yh[((size_t)b * kN + n + j) * kH + o] = h;
        yl[((size_t)b * kN + n + j) * kH + o] = l;
      }
    }
  } else if (OMODE == 1) {  // V bf16 [b][o][N]
    bf16* y = (bf16*)yv;
#pragma unroll
    for (int i = 0; i < OT; ++i) {
      const int o = to * OT + i;
      const float bz = bias[o];
      ushort2 u2;
      u2.x = f2bu(acc[i][0] + bz);
      u2.y = f2bu(acc[i][1] + bz);
      *(ushort2*)(y + ((size_t)b * kC + o) * kN + n) = u2;
    }
  } else if (OMODE == 2) {  // fp32 [b][o][N], may alias x (panel is in LDS)
    float* y = (float*)yv;
#pragma unroll
    for (int i = 0; i < OT; ++i) {
      const int o = to * OT + i;
      const float bz = bias[o];
      *(float2*)(y + ((size_t)b * kC + o) * kN + n) =
          make_float2(acc[i][0] + bz, acc[i][1] + bz);
    }
  } else {  // fp32 accumulate (dc1)
    float* y = (float*)yv;
#pragma unroll
    for (int i = 0; i < OT; ++i) {
      const int o = to * OT + i;
      float2* p2 = (float2*)(y + ((size_t)b * kC + o) * kN + n);
      if (first) {
        *p2 = make_float2(acc[i][0], acc[i][1]);
      } else {
        const float2 old = *p2;
        *p2 = make_float2(old.x + acc[i][0], old.y + acc[i][1]);
      }
    }
  }
}

// ---------------------------------------------------------------------------
// Row softmax stats via split-bf16 MFMA: e = Qhi·Qhi^T + Qhi·Qlo^T + Qlo·Qhi^T.
// Block: 64 rows (4 waves x 16), col tiles of 64 staged in LDS, online softmax.
// ---------------------------------------------------------------------------
__global__ __launch_bounds__(256) void k_rowstats(const ushort_t* __restrict__ Qhi,
                                                  const ushort_t* __restrict__ Qlo,
                                                  float* __restrict__ rmx,
                                                  float* __restrict__ rsn) {
  __shared__ __align__(16) ushort_t Bh[64][72];
  __shared__ __align__(16) ushort_t Bl[64][72];
  const int b = blockIdx.y, t = threadIdx.x;
  const int r0 = blockIdx.x * 64;
  const int lane = t & 63, w = t >> 6;
  const int fr = lane & 15, fq = lane >> 4;
  const size_t qbase = (size_t)b * kN * kH;
  // A fragments: rows r0 + w*16 + fr, two K=32 steps
  bf16x8 ah0, ah1, al0, al1;
  {
    const ushort_t* qh = Qhi + qbase + (size_t)(r0 + w * 16 + fr) * kH;
    const ushort_t* ql = Qlo + qbase + (size_t)(r0 + w * 16 + fr) * kH;
    ah0 = *(const bf16x8*)(qh + fq * 8);
    ah1 = *(const bf16x8*)(qh + 32 + fq * 8);
    al0 = *(const bf16x8*)(ql + fq * 8);
    al1 = *(const bf16x8*)(ql + 32 + fq * 8);
  }
  float mx[4] = {-3.0e38f, -3.0e38f, -3.0e38f, -3.0e38f};
  float sm[4] = {0.f, 0.f, 0.f, 0.f};
  const int srow = t >> 2, scol = (t & 3) * 16;  // staging map
  for (int m0 = 0; m0 < kN; m0 += 64) {
    __syncthreads();  // previous tile's consumers done
    {                 // stage col tile hi/lo: 64 rows x 64 k
      const ushort_t* qh = Qhi + qbase + (size_t)(m0 + srow) * kH + scol;
      const ushort_t* ql = Qlo + qbase + (size_t)(m0 + srow) * kH + scol;
      *(uint4*)&Bh[srow][scol] = *(const uint4*)qh;
      *(uint4*)&Bh[srow][scol + 8] = *(const uint4*)(qh + 8);
      *(uint4*)&Bl[srow][scol] = *(const uint4*)ql;
      *(uint4*)&Bl[srow][scol + 8] = *(const uint4*)(ql + 8);
    }
    __syncthreads();
    float ev[4][4];  // [cs][r]
#pragma unroll
    for (int cs = 0; cs < 4; ++cs) {
      const bf16x8 bh0 = *(const bf16x8*)&Bh[cs * 16 + fr][fq * 8];
      const bf16x8 bh1 = *(const bf16x8*)&Bh[cs * 16 + fr][32 + fq * 8];
      const bf16x8 bl0 = *(const bf16x8*)&Bl[cs * 16 + fr][fq * 8];
      const bf16x8 bl1 = *(const bf16x8*)&Bl[cs * 16 + fr][32 + fq * 8];
      f32x4 e = {0.f, 0.f, 0.f, 0.f};
      e = __builtin_amdgcn_mfma_f32_16x16x32_bf16(ah0, bh0, e, 0, 0, 0);
      e = __builtin_amdgcn_mfma_f32_16x16x32_bf16(ah1, bh1, e, 0, 0, 0);
      e = __builtin_amdgcn_mfma_f32_16x16x32_bf16(ah0, bl0, e, 0, 0, 0);
      e = __builtin_amdgcn_mfma_f32_16x16x32_bf16(ah1, bl1, e, 0, 0, 0);
      e = __builtin_amdgcn_mfma_f32_16x16x32_bf16(al0, bh0, e, 0, 0, 0);
      e = __builtin_amdgcn_mfma_f32_16x16x32_bf16(al1, bh1, e, 0, 0, 0);
      ev[cs][0] = e[0]; ev[cs][1] = e[1]; ev[cs][2] = e[2]; ev[cs][3] = e[3];
    }
#pragma unroll
    for (int r = 0; r < 4; ++r) {
      const float tmax = fmaxf(fmaxf(ev[0][r], ev[1][r]), fmaxf(ev[2][r], ev[3][r]));
      const float nm = fmaxf(mx[r], tmax);
      sm[r] = sm[r] * __expf(mx[r] - nm) + __expf(ev[0][r] - nm) + __expf(ev[1][r] - nm) +
              __expf(ev[2][r] - nm) + __expf(ev[3][r] - nm);
      mx[r] = nm;
    }
  }
  // merge across the 16 fr lanes (same fq group shares rows)
#pragma unroll
  for (int mask = 1; mask < 16; mask <<= 1) {
#pragma unroll
    for (int r = 0; r < 4; ++r) {
      const float om = __shfl_xor(mx[r], mask);
      const float os = __shfl_xor(sm[r], mask);
      const float nm = fmaxf(mx[r], om);
      sm[r] = sm[r] * __expf(mx[r] - nm) + os * __expf(om - nm);
      mx[r] = nm;
    }
  }
  if (fr == 0) {
#pragma unroll
    for (int r = 0; r < 4; ++r) {
      const int row = r0 + w * 16 + fq * 4 + r;
      rmx[(size_t)b * kN + row] = mx[r];
      rsn[(size_t)b * kN + row] = 1.f / sm[r];
    }
  }
}

// ---------------------------------------------------------------------------
// Column pass, MT=64: E via split-bf16 MFMA (all 4 waves, each owns a 16-m
// slice), p=exp(e-rm)*rs (bf16), colsum; PV via bf16 MFMA (each wave owns a
// 64-c slice x all 64 m); u = x - x_r (fp32). Grid: (kN/64, kB).
// ---------------------------------------------------------------------------
__global__ __launch_bounds__(256) void k_colpass(const ushort_t* __restrict__ Qhi,
                                                 const ushort_t* __restrict__ Qlo,
                                                 const bf16* __restrict__ V,
                                                 const float* __restrict__ rmx,
                                                 const float* __restrict__ rsn,
                                                 const float* __restrict__ x,
                                                 float* __restrict__ u) {
  constexpr int MT = 64, NT = 32;
  __shared__ __align__(16) ushort_t Anh[NT][72];   // Qn hi [n][k]
  __shared__ __align__(16) ushort_t Anl[NT][72];   // Qn lo [n][k]
  __shared__ __align__(16) ushort_t Vs[kC][40];    // V [c][n] bf16
  __shared__ __align__(16) ushort_t Pl[MT][40];    // P [m][n] bf16
  __shared__ float CsI[MT];
  const int t = threadIdx.x;
  const int b = blockIdx.y;
  const int mBase = blockIdx.x * MT;
  const size_t qbase = (size_t)b * kN * kH;
  const bf16* Vb_ = V + (size_t)b * kC * kN;
  const int lane = t & 63, wv = t >> 6;
  const int fr = lane & 15, fq = lane >> 4;
  // B fragments for E: my wave's m-slice, m = mBase + wv*16 + fr
  bf16x8 bmh0, bmh1, bml0, bml1;
  {
    const ushort_t* qh = Qhi + qbase + (size_t)(mBase + wv * 16 + fr) * kH;
    const ushort_t* ql = Qlo + qbase + (size_t)(mBase + wv * 16 + fr) * kH;
    bmh0 = *(const bf16x8*)(qh + fq * 8);
    bmh1 = *(const bf16x8*)(qh + 32 + fq * 8);
    bml0 = *(const bf16x8*)(ql + fq * 8);
    bml1 = *(const bf16x8*)(ql + 32 + fq * 8);
  }
  f32x4 acc[4][4];  // [cs][ms]; wave's c-slice = wv*64..+63, all 64 m
#pragma unroll
  for (int i = 0; i < 4; ++i)
#pragma unroll
    for (int j = 0; j < 4; ++j) acc[i][j] = (f32x4){0.f, 0.f, 0.f, 0.f};
  float csloc = 0.f;
  const int arow = t >> 3, acol = (t & 7) * 8;  // Qn staging map
  const int vc = t >> 2, vq = t & 3;            // V staging map
  for (int n0 = 0; n0 < kN; n0 += NT) {
    __syncthreads();  // previous tile's MFMA reads done
    {                 // stage Qn tile hi/lo [32n][64k]
      *(uint4*)&Anh[arow][acol] = *(const uint4*)(Qhi + qbase + (size_t)(n0 + arow) * kH + acol);
      *(uint4*)&Anl[arow][acol] = *(const uint4*)(Qlo + qbase + (size_t)(n0 + arow) * kH + acol);
    }
#pragma unroll
    for (int it = 0; it < 4; ++it) {  // stage V tile [256c][32n] bf16
      const int c = it * 64 + vc;
      *(uint4*)&Vs[c][vq * 8] = *(const uint4*)(Vb_ + (size_t)c * kN + n0 + vq * 8);
    }
    __syncthreads();
    // E phase: wave wv computes E for its m-slice x 32 n (2 n-subtiles)
#pragma unroll
    for (int ns = 0; ns < 2; ++ns) {
      const bf16x8 ah0 = *(const bf16x8*)&Anh[ns * 16 + fr][fq * 8];
      const bf16x8 ah1 = *(const bf16x8*)&Anh[ns * 16 + fr][32 + fq * 8];
      const bf16x8 al0 = *(const bf16x8*)&Anl[ns * 16 + fr][fq * 8];
      const bf16x8 al1 = *(const bf16x8*)&Anl[ns * 16 + fr][32 + fq * 8];
      f32x4 e = {0.f, 0.f, 0.f, 0.f};
      e = __builtin_amdgcn_mfma_f32_16x16x32_bf16(ah0, bmh0, e, 0, 0, 0);
      e = __builtin_amdgcn_mfma_f32_16x16x32_bf16(ah1, bmh1, e, 0, 0, 0);
      e = __builtin_amdgcn_mfma_f32_16x16x32_bf16(ah0, bml0, e, 0, 0, 0);
      e = __builtin_amdgcn_mfma_f32_16x16x32_bf16(ah1, bml1, e, 0, 0, 0);
      e = __builtin_amdgcn_mfma_f32_16x16x32_bf16(al0, bmh0, e, 0, 0, 0);
      e = __builtin_amdgcn_mfma_f32_16x16x32_bf16(al1, bmh1, e, 0, 0, 0);
      // D: col m-local = wv*16 + fr, row n-local = ns*16 + fq*4 + r
#pragma unroll
      for (int r = 0; r < 4; ++r) {
        const int nl = ns * 16 + fq * 4 + r;
        const size_t gn = (size_t)b * kN + n0 + nl;
        const float p = __expf(e[r] - rmx[gn]) * rsn[gn];
        Pl[wv * 16 + fr][nl] = f2bu(p);
        csloc += p;
      }
    }
    __syncthreads();  // Pl complete
    // PV phase: wave wv: c = wv*64 + cs*16, all 4 m-subtiles
    bf16x8 af[4], bfm[4];
#pragma unroll
    for (int cs = 0; cs < 4; ++cs)
      af[cs] = *(const bf16x8*)&Vs[wv * 64 + cs * 16 + fr][fq * 8];
#pragma unroll
    for (int ms = 0; ms < 4; ++ms)
      bfm[ms] = *(const bf16x8*)&Pl[ms * 16 + fr][fq * 8];
#pragma unroll
    for (int cs = 0; cs < 4; ++cs)
#pragma unroll
      for (int ms = 0; ms < 4; ++ms)
        acc[cs][ms] = __builtin_amdgcn_mfma_f32_16x16x32_bf16(af[cs], bfm[ms], acc[cs][ms], 0, 0, 0);
  }
  // colsum: csloc per lane covers m = wv*16+fr, partial over fq; reduce fq
  csloc += __shfl_xor(csloc, 16);
  csloc += __shfl_xor(csloc, 32);
  __syncthreads();
  if (fq == 0) CsI[wv * 16 + fr] = 1.f / (1e-9f + csloc);
  __syncthreads();
  // epilogue: D col = m-local ms*16+fr, row = c-local cs*16 + fq*4 + r
  const float* xb = x + (size_t)b * kC * kN;
  float* ub = u + (size_t)b * kC * kN;
#pragma unroll
  for (int ms = 0; ms < 4; ++ms) {
    const float inv = CsI[ms * 16 + fr];
    const int m = mBase + ms * 16 + fr;
#pragma unroll
    for (int cs = 0; cs < 4; ++cs) {
#pragma unroll
      for (int r = 0; r < 4; ++r) {
        const int c = wv * 64 + cs * 16 + fq * 4 + r;
        const float xv = xb[(size_t)c * kN + m];
        ub[(size_t)c * kN + m] = xv - acc[cs][ms][r] * inv;
      }
    }
  }
}

// ---------------------------------------------------------------------------
// BN stats per channel over (B, N), fp32 input, biased var.
// ---------------------------------------------------------------------------
__global__ __launch_bounds__(256) void k_bnstats(const float* __restrict__ y, int nch,
                                                 float* __restrict__ mean,
                                                 float* __restrict__ rsig) {
  const int c = blockIdx.x, t = threadIdx.x;
  float s = 0.f, s2 = 0.f;
  for (int b = 0; b < kB; ++b) {
    const float* p = y + ((size_t)b * nch + c) * kN;
    for (int n = t; n < kN; n += 256) {
      const float v = p[n];
      s += v;
      s2 += v * v;
    }
  }
  __shared__ float r1[256], r2[256];
  r1[t] = s;
  r2[t] = s2;
  __syncthreads();
  for (int k = 128; k > 0; k >>= 1) {
    if (t < k) {
      r1[t] += r1[t + k];
      r2[t] += r2[t + k];
    }
    __syncthreads();
  }
  if (t == 0) {
    const float im = 1.f / (float)(kB * kN);
    const float m = r1[0] * im;
    const float var = r2[0] * im - m * m;
    mean[c] = m;
    rsig[c] = rsqrtf(var + 1e-5f);
  }
}

// ---------------------------------------------------------------------------
// p += leaky(g*(y-mean)*rsig + b)    (in-place residual update, all fp32)
// ---------------------------------------------------------------------------
__global__ __launch_bounds__(256) void k_bnapply(const float* __restrict__ y,
                                                 float* __restrict__ p,
                                                 const float* __restrict__ mean,
                                                 const float* __restrict__ rsig,
                                                 const float* __restrict__ g,
                                                 const float* __restrict__ bb) {
  const size_t i = (size_t)blockIdx.x * 256 + threadIdx.x;
  const int c = (int)((i / kN) % kC);
  float z = g[c] * (y[i] - mean[c]) * rsig[c] + bb[c];
  z = z > 0.f ? z : 0.2f * z;
  p[i] = p[i] + z;
}

// ---------------------------------------------------------------------------
// dc2: tpre[b,j,n] = dc2_b[j] + sum_c dc2_w[j,c] * leaky(bn(h[b,c,n]))
// ---------------------------------------------------------------------------
__global__ __launch_bounds__(256) void k_dc2(const float* __restrict__ h,
                                             const float* __restrict__ mean,
                                             const float* __restrict__ rsig,
                                             const float* __restrict__ g,
                                             const float* __restrict__ bb,
                                             const float* __restrict__ w,
                                             const float* __restrict__ d2b,
                                             float* __restrict__ tpre) {
  __shared__ float wS[3][kC];
  __shared__ float aS[kC], cS[kC];
  const int t = threadIdx.x, b = blockIdx.y;
  const int n = blockIdx.x * 256 + t;
  {
    const float a = g[t] * rsig[t];
    aS[t] = a;
    cS[t] = bb[t] - a * mean[t];
    wS[0][t] = w[t];
    wS[1][t] = w[kC + t];
    wS[2][t] = w[2 * kC + t];
  }
  __syncthreads();
  float a0 = d2b[0], a1 = d2b[1], a2 = d2b[2];
  const float* hb = h + (size_t)b * kC * kN + n;
  for (int c = 0; c < kC; ++c) {
    float z = hb[(size_t)c * kN] * aS[c] + cS[c];
    z = z > 0.f ? z : 0.2f * z;
    a0 += wS[0][c] * z;
    a1 += wS[1][c] * z;
    a2 += wS[2][c] * z;
  }
  tpre[((size_t)b * 3 + 0) * kN + n] = a0;
  tpre[((size_t)b * 3 + 1) * kN + n] = a1;
  tpre[((size_t)b * 3 + 2) * kN + n] = a2;
}

// ---------------------------------------------------------------------------
// Final: out[b,n,j] = tanh(g[j]*(tpre[b,j,n]-mean[j])*rsig[j] + b[j])
// ---------------------------------------------------------------------------
__global__ __launch_bounds__(256) void k_final(const float* __restrict__ tpre,
                                               const float* __restrict__ mean,
                                               const float* __restrict__ rsig,
                                               const float* __restrict__ g,
                                               const float* __restrict__ bb,
                                               float* __restrict__ out) {
  const int i = blockIdx.x * 256 + threadIdx.x;  // over B*N
  const int n = i & (kN - 1), b = i >> 11;
#pragma unroll
  for (int j = 0; j < 3; ++j) {
    const float v = tpre[((size_t)b * 3 + j) * kN + n];
    const float z = g[j] * (v - mean[j]) * rsig[j] + bb[j];
    out[(size_t)i * 3 + j] = tanhf(z);
  }
}

// ---------------------------------------------------------------------------
extern "C" void kernel_launch(void* const* d_in, const int* in_sizes, int n_in,
                              void* d_out, int out_size, void* d_ws, size_t ws_size,
                              hipStream_t stream) {
  const float* feature  = (const float*)d_in[0];
  const float* prior    = (const float*)d_in[1];
  const float* mlp_w    = (const float*)d_in[2];
  const float* mlp_b    = (const float*)d_in[3];
  const float* qk_w     = (const float*)d_in[4];
  const float* qk_b     = (const float*)d_in[5];
  const float* v_w      = (const float*)d_in[6];
  const float* v_b      = (const float*)d_in[7];
  const float* t_w      = (const float*)d_in[8];
  const float* t_b      = (const float*)d_in[9];
  const float* bn_g     = (const float*)d_in[10];
  const float* bn_b     = (const float*)d_in[11];
  const float* dc1_w    = (const float*)d_in[12];
  const float* dc1_bn_g = (const float*)d_in[13];
  const float* dc1_bn_b = (const float*)d_in[14];
  const float* dc2_w    = (const float*)d_in[15];
  const float* dc2_b    = (const float*)d_in[16];
  const float* dc2_bn_g = (const float*)d_in[17];
  const float* dc2_bn_b = (const float*)d_in[18];
  float* out = (float*)d_out;

  // Workspace carve. Total ~126.5 MB (fits 128 MiB).
  char* base = (char*)d_ws;
  size_t off = 0;
  auto carve = [&](size_t bytes) {
    char* p = base + off;
    off += (bytes + 255) & ~(size_t)255;
    return p;
  };
  float*    p    = (float*)carve((size_t)kB * kC * kN * 4);   // residual     33.6 MB
  float*    hacc = (float*)carve((size_t)kB * kC * kN * 4);   // dc1 acc      33.6 MB
  float*    U    = (float*)carve((size_t)kB * kC * kN * 4);   // u/Y inplace  33.6 MB
  ushort_t* Qhi  = (ushort_t*)carve((size_t)kB * kN * kH * 2);// Q hi bf16     4.2 MB
  ushort_t* Qlo  = (ushort_t*)carve((size_t)kB * kN * kH * 2);// Q lo bf16     4.2 MB
  bf16*     Vb   = (bf16*)carve((size_t)kB * kC * kN * 2);    // V bf16       16.8 MB
  float*    rmx  = (float*)carve((size_t)kB * kN * 4);
  float*    rsn  = (float*)carve((size_t)kB * kN * 4);
  float*    fb   = (float*)carve((size_t)kB * kC * 4);
  float*    bnm  = (float*)carve(kC * 4);
  float*    bnr  = (float*)carve(kC * 4);
  float*    tpre = (float*)carve((size_t)kB * 3 * kN * 4);

  k_fb<<<kB * kC, 256, 0, stream>>>(feature, mlp_w, mlp_b, fb);
  k_p0<<<(kB * kC * kN) / 256, 256, 0, stream>>>(prior, mlp_w, fb, p);

  const dim3 gFC(kN / 32, kB);
  for (int l = 0; l < 4; ++l) {
    k_fc<kH, 0><<<gFC, 256, 0, stream>>>(p, qk_w + (size_t)l * kH * kC, kC,
                                         qk_b + l * kH, Qhi, Qlo, 0);
    k_fc<kC, 1><<<gFC, 256, 0, stream>>>(p, v_w + (size_t)l * kC * kC, kC,
                                         v_b + l * kC, Vb, nullptr, 0);
    k_rowstats<<<dim3(kN / 64, kB), 256, 0, stream>>>(Qhi, Qlo, rmx, rsn);
    k_colpass<<<dim3(kN / 64, kB), 256, 0, stream>>>(Qhi, Qlo, Vb, rmx, rsn, p, U);
    k_fc<kC, 2><<<gFC, 256, 0, stream>>>(U, t_w + (size_t)l * kC * kC, kC,
                                         t_b + l * kC, U, nullptr, 0);  // in-place
    k_bnstats<<<kC, 256, 0, stream>>>(U, kC, bnm, bnr);
    k_bnapply<<<(kB * kC * kN) / 256, 256, 0, stream>>>(
        U, p, bnm, bnr, bn_g + l * kC, bn_b + l * kC);
    k_fc<kC, 3><<<gFC, 256, 0, stream>>>(p, dc1_w + (size_t)l * kC, 4 * kC,
                                         nullptr, hacc, nullptr, l == 0 ? 1 : 0);
  }

  k_bnstats<<<kC, 256, 0, stream>>>(hacc, kC, bnm, bnr);
  k_dc2<<<dim3(kN / 256, kB), 256, 0, stream>>>(hacc, bnm, bnr, dc1_bn_g, dc1_bn_b,
                                                dc2_w, dc2_b, tpre);
  k_bnstats<<<3, 256, 0, stream>>>(tpre, 3, bnm, bnr);
  k_final<<<(kB * kN) / 256, 256, 0, stream>>>(tpre, bnm, bnr, dc2_bn_g, dc2_bn_b, out);
}

// Round 8
// 1407.417 us; speedup vs baseline: 8.6808x; 1.5420x over previous
//
#include <hip/hip_runtime.h>
#include <hip/hip_bf16.h>

typedef __hip_bfloat16 bf16;
typedef unsigned short ushort_t;

// Problem constants
constexpr int kB = 16;    // batch
constexpr int kN = 2048;  // points
constexpr int kF = 1024;  // feat dims
constexpr int kC = 256;   // channels
constexpr int kH = 64;    // head dim

using f32x4 = __attribute__((ext_vector_type(4))) float;
using bf16x8 = __attribute__((ext_vector_type(8))) short;  // 8 bf16 (4 VGPRs)

__device__ __forceinline__ float us2f(unsigned short u) {
  union { unsigned int i; float f; } w;
  w.i = ((unsigned int)u) << 16;
  return w.f;
}
__device__ __forceinline__ unsigned short f2bu(float f) {
  union { bf16 h; unsigned short s; } u;
  u.h = __float2bfloat16(f);
  return u.s;
}

// ---------------------------------------------------------------------------
// fb[b,c] = mlp_b[c] + sum_f mlp_w[c,f] * feature[b,f]
// ---------------------------------------------------------------------------
__global__ __launch_bounds__(256) void k_fb(const float* __restrict__ feat,
                                            const float* __restrict__ mlp_w,
                                            const float* __restrict__ mlp_b,
                                            float* __restrict__ fb) {
  const int b = blockIdx.x >> 8;
  const int c = blockIdx.x & 255;
  const int t = threadIdx.x;
  const float* wr = mlp_w + (size_t)c * (kF + 3);
  const float* fr = feat + (size_t)b * kF;
  float s = 0.f;
  for (int f = t; f < kF; f += 256) s += wr[f] * fr[f];
  __shared__ float red[256];
  red[t] = s;
  __syncthreads();
  for (int k = 128; k > 0; k >>= 1) {
    if (t < k) red[t] += red[t + k];
    __syncthreads();
  }
  if (t == 0) fb[blockIdx.x] = red[0] + mlp_b[c];
}

// ---------------------------------------------------------------------------
// p[b,n,c] = fb[b,c] + sum_{j<3} mlp_w[c,1024+j] * prior[b,j,n]  (split bf16)
// ---------------------------------------------------------------------------
__global__ __launch_bounds__(256) void k_p0(const float* __restrict__ prior,
                                            const float* __restrict__ mlp_w,
                                            const float* __restrict__ fb,
                                            ushort_t* __restrict__ psh,
                                            ushort_t* __restrict__ psl) {
  const size_t i = (size_t)blockIdx.x * 256 + threadIdx.x;  // over B*N*C
  const int c = (int)(i & 255);
  const int n = (int)((i >> 8) & 2047);
  const int b = (int)(i >> 19);
  const float* wr = mlp_w + (size_t)c * (kF + 3) + kF;
  const float* pr = prior + (size_t)b * 3 * kN + n;
  const float v = fb[b * kC + c] + wr[0] * pr[0] + wr[1] * pr[kN] + wr[2] * pr[2 * kN];
  const ushort_t h = f2bu(v);
  psh[i] = h;
  psl[i] = f2bu(v - us2f(h));
}

// ---------------------------------------------------------------------------
// Pre-split weights into MFMA A-fragment order (hi/lo bf16):
// frag element (kk, osub, lane, j) <- W[osub*16+(lane&15)][kk*32+(lane>>4)*8+j]
// Regions (group = 8 elems): qk 4x2048 | v 4x8192 | t 4x8192 | dc1 4x8192
// ---------------------------------------------------------------------------
__global__ __launch_bounds__(256) void k_wsplit(const float* __restrict__ qk_w,
                                                const float* __restrict__ v_w,
                                                const float* __restrict__ t_w,
                                                const float* __restrict__ dc1_w,
                                                ushort_t* __restrict__ wfh,
                                                ushort_t* __restrict__ wfl) {
  const int idx = blockIdx.x * 256 + threadIdx.x;  // group index
  const float* src;
  int stride, OS_;
  size_t dstoff;
  int g;
  if (idx < 8192) {
    const int l = idx >> 11; g = idx & 2047;
    src = qk_w + (size_t)l * 64 * 256; stride = 256; OS_ = 4;
    dstoff = (size_t)l * 16384;
  } else if (idx < 40960) {
    const int i2 = idx - 8192; const int l = i2 >> 13; g = i2 & 8191;
    src = v_w + (size_t)l * 256 * 256; stride = 256; OS_ = 16;
    dstoff = 65536 + (size_t)l * 65536;
  } else if (idx < 73728) {
    const int i2 = idx - 40960; const int l = i2 >> 13; g = i2 & 8191;
    src = t_w + (size_t)l * 256 * 256; stride = 256; OS_ = 16;
    dstoff = 327680 + (size_t)l * 65536;
  } else {
    const int i2 = idx - 73728; const int l = i2 >> 13; g = i2 & 8191;
    src = dc1_w + (size_t)l * 256; stride = 1024; OS_ = 16;
    dstoff = 589824 + (size_t)l * 65536;
  }
  const int kk = g / (OS_ * 64);
  const int rem = g % (OS_ * 64);
  const int osub = rem >> 6;
  const int lane = rem & 63;
  const int o = osub * 16 + (lane & 15);
  const int c = kk * 32 + (lane >> 4) * 8;
  const float* sp = src + (size_t)o * stride + c;
  ushort_t h[8], l8[8];
#pragma unroll
  for (int j = 0; j < 8; ++j) {
    const float v = sp[j];
    h[j] = f2bu(v);
    l8[j] = f2bu(v - us2f(h[j]));
  }
  *(uint4*)(wfh + dstoff + (size_t)g * 8) = *(const uint4*)h;
  *(uint4*)(wfl + dstoff + (size_t)g * 8) = *(const uint4*)l8;
}

// ---------------------------------------------------------------------------
// Unified MFMA 1x1 conv: y[o][n] = bias[o] + sum_c W[o][c] x[n][c], split-bf16
// (3 MFMAs per product: xh*wh + xh*wl + xl*wh). x: [b][n][256] split bf16.
// Block: 64 n x O outputs, 4 waves (wave owns O/4 outputs x all 64 n).
// MODE 0: Q split out [b][n][64]   MODE 1: V bf16 out [b][o][N]
// MODE 2: BN partial stats only    MODE 3: fused BN+leaky+residual into p
// MODE 4: fp32 accumulate [b][o][N] (dc1)
// ---------------------------------------------------------------------------
template <int O, int MODE>
__global__ __launch_bounds__(256) void k_conv(
    const ushort_t* __restrict__ xh, const ushort_t* __restrict__ xl,
    const ushort_t* __restrict__ wfh, const ushort_t* __restrict__ wfl,
    const float* __restrict__ bias,
    ushort_t* __restrict__ o1, ushort_t* __restrict__ o2,  // Q hi/lo or psh/psl
    bf16* __restrict__ ov,                                 // V out
    float* __restrict__ of,                                // part or hacc
    const float* __restrict__ mean, const float* __restrict__ rsig,
    const float* __restrict__ g, const float* __restrict__ bb, int first) {
  constexpr int KK = 8;
  constexpr int OS = O / 16;
  constexpr int OSW = OS / 4;
  const int t = threadIdx.x;
  const int b = blockIdx.y;
  const int n0 = blockIdx.x * 64;
  const int lane = t & 63, wv = t >> 6;
  const int fr = lane & 15, fq = lane >> 4;
  const ushort_t* xbh = xh + ((size_t)b * kN + n0) * kC;
  const ushort_t* xbl = xl + ((size_t)b * kN + n0) * kC;
  f32x4 acc[OSW][4];
#pragma unroll
  for (int s = 0; s < OSW; ++s)
#pragma unroll
    for (int ns = 0; ns < 4; ++ns) acc[s][ns] = (f32x4){0.f, 0.f, 0.f, 0.f};
  for (int kk = 0; kk < KK; ++kk) {
    bf16x8 bh[4], bl[4];
#pragma unroll
    for (int ns = 0; ns < 4; ++ns) {
      const size_t xi = (size_t)(ns * 16 + fr) * kC + kk * 32 + fq * 8;
      bh[ns] = *(const bf16x8*)(xbh + xi);
      bl[ns] = *(const bf16x8*)(xbl + xi);
    }
#pragma unroll
    for (int s = 0; s < OSW; ++s) {
      const size_t wi = (((size_t)kk * OS + wv * OSW + s) * 64 + lane) * 8;
      const bf16x8 ah = *(const bf16x8*)(wfh + wi);
      const bf16x8 al = *(const bf16x8*)(wfl + wi);
#pragma unroll
      for (int ns = 0; ns < 4; ++ns) {
        acc[s][ns] = __builtin_amdgcn_mfma_f32_16x16x32_bf16(ah, bh[ns], acc[s][ns], 0, 0, 0);
        acc[s][ns] = __builtin_amdgcn_mfma_f32_16x16x32_bf16(ah, bl[ns], acc[s][ns], 0, 0, 0);
        acc[s][ns] = __builtin_amdgcn_mfma_f32_16x16x32_bf16(al, bh[ns], acc[s][ns], 0, 0, 0);
      }
    }
  }
  // D: col = n (lane&15), row = o = osub*16 + fq*4 + r
  if (MODE == 0) {
    const int o0 = wv * 16 + fq * 4;
#pragma unroll
    for (int ns = 0; ns < 4; ++ns) {
      const int n = n0 + ns * 16 + fr;
      ushort_t h4[4], l4[4];
#pragma unroll
      for (int r = 0; r < 4; ++r) {
        const float v = acc[0][ns][r] + bias[o0 + r];
        h4[r] = f2bu(v);
        l4[r] = f2bu(v - us2f(h4[r]));
      }
      *(ushort4*)(o1 + ((size_t)b * kN + n) * kH + o0) = *(const ushort4*)h4;
      *(ushort4*)(o2 + ((size_t)b * kN + n) * kH + o0) = *(const ushort4*)l4;
    }
  } else if (MODE == 1) {
#pragma unroll
    for (int s = 0; s < OSW; ++s) {
      const int o0 = (wv * OSW + s) * 16 + fq * 4;
#pragma unroll
      for (int ns = 0; ns < 4; ++ns) {
        const int n = n0 + ns * 16 + fr;
#pragma unroll
        for (int r = 0; r < 4; ++r)
          ov[((size_t)b * kC + o0 + r) * kN + n] = __float2bfloat16(acc[s][ns][r] + bias[o0 + r]);
      }
    }
  } else if (MODE == 2) {
    const int blk = blockIdx.y * gridDim.x + blockIdx.x;  // 0..511
#pragma unroll
    for (int s = 0; s < OSW; ++s) {
      const int o0 = (wv * OSW + s) * 16 + fq * 4;
#pragma unroll
      for (int r = 0; r < 4; ++r) {
        const float bz = bias[o0 + r];
        float s1 = 0.f, s2 = 0.f;
#pragma unroll
        for (int ns = 0; ns < 4; ++ns) {
          const float y = acc[s][ns][r] + bz;
          s1 += y;
          s2 += y * y;
        }
#pragma unroll
        for (int mask = 1; mask < 16; mask <<= 1) {
          s1 += __shfl_xor(s1, mask);
          s2 += __shfl_xor(s2, mask);
        }
        if (fr == 0) {
          of[(size_t)(o0 + r) * 512 + blk] = s1;
          of[131072 + (size_t)(o0 + r) * 512 + blk] = s2;
        }
      }
    }
  } else if (MODE == 3) {
#pragma unroll
    for (int s = 0; s < OSW; ++s) {
      const int o0 = (wv * OSW + s) * 16 + fq * 4;
      float av[4], cv[4];
#pragma unroll
      for (int r = 0; r < 4; ++r) {
        const float a = g[o0 + r] * rsig[o0 + r];
        av[r] = a;
        cv[r] = bb[o0 + r] + a * (bias[o0 + r] - mean[o0 + r]);
      }
#pragma unroll
      for (int ns = 0; ns < 4; ++ns) {
        const int n = n0 + ns * 16 + fr;
        const size_t idx = ((size_t)b * kN + n) * kC + o0;
        ushort_t ph4[4], pl4[4], nh4[4], nl4[4];
        *(ushort4*)ph4 = *(const ushort4*)(o1 + idx);
        *(ushort4*)pl4 = *(const ushort4*)(o2 + idx);
#pragma unroll
        for (int r = 0; r < 4; ++r) {
          float z = av[r] * acc[s][ns][r] + cv[r];
          z = z > 0.f ? z : 0.2f * z;
          const float pv = us2f(ph4[r]) + us2f(pl4[r]) + z;
          nh4[r] = f2bu(pv);
          nl4[r] = f2bu(pv - us2f(nh4[r]));
        }
        *(ushort4*)(o1 + idx) = *(const ushort4*)nh4;
        *(ushort4*)(o2 + idx) = *(const ushort4*)nl4;
      }
    }
  } else {  // MODE 4: accumulate into hacc [b][o][N]
#pragma unroll
    for (int s = 0; s < OSW; ++s) {
      const int o0 = (wv * OSW + s) * 16 + fq * 4;
#pragma unroll
      for (int ns = 0; ns < 4; ++ns) {
        const int n = n0 + ns * 16 + fr;
#pragma unroll
        for (int r = 0; r < 4; ++r) {
          float* pp = of + ((size_t)b * kC + o0 + r) * kN + n;
          *pp = (first ? 0.f : *pp) + acc[s][ns][r];
        }
      }
    }
  }
}

// ---------------------------------------------------------------------------
// Reduce BN partials (part [c][512] sums + [c][512] sumsq at offset 131072)
// ---------------------------------------------------------------------------
__global__ __launch_bounds__(128) void k_bnred(const float* __restrict__ part,
                                               float* __restrict__ mean,
                                               float* __restrict__ rsig) {
  const int c = blockIdx.x, t = threadIdx.x;
  const float4 v1 = *(const float4*)&part[(size_t)c * 512 + t * 4];
  const float4 v2 = *(const float4*)&part[131072 + (size_t)c * 512 + t * 4];
  float s1 = v1.x + v1.y + v1.z + v1.w;
  float s2 = v2.x + v2.y + v2.z + v2.w;
  __shared__ float r1[128], r2[128];
  r1[t] = s1;
  r2[t] = s2;
  __syncthreads();
  for (int k = 64; k > 0; k >>= 1) {
    if (t < k) {
      r1[t] += r1[t + k];
      r2[t] += r2[t + k];
    }
    __syncthreads();
  }
  if (t == 0) {
    const float im = 1.f / (float)(kB * kN);
    const float m = r1[0] * im;
    const float var = r2[0] * im - m * m;
    mean[c] = m;
    rsig[c] = rsqrtf(var + 1e-5f);
  }
}

// ---------------------------------------------------------------------------
// Row softmax stats via split-bf16 MFMA (unchanged from round 7).
// ---------------------------------------------------------------------------
__global__ __launch_bounds__(256) void k_rowstats(const ushort_t* __restrict__ Qhi,
                                                  const ushort_t* __restrict__ Qlo,
                                                  float* __restrict__ rmx,
                                                  float* __restrict__ rsn) {
  __shared__ __align__(16) ushort_t Bh[64][72];
  __shared__ __align__(16) ushort_t Bl[64][72];
  const int b = blockIdx.y, t = threadIdx.x;
  const int r0 = blockIdx.x * 64;
  const int lane = t & 63, w = t >> 6;
  const int fr = lane & 15, fq = lane >> 4;
  const size_t qbase = (size_t)b * kN * kH;
  bf16x8 ah0, ah1, al0, al1;
  {
    const ushort_t* qh = Qhi + qbase + (size_t)(r0 + w * 16 + fr) * kH;
    const ushort_t* ql = Qlo + qbase + (size_t)(r0 + w * 16 + fr) * kH;
    ah0 = *(const bf16x8*)(qh + fq * 8);
    ah1 = *(const bf16x8*)(qh + 32 + fq * 8);
    al0 = *(const bf16x8*)(ql + fq * 8);
    al1 = *(const bf16x8*)(ql + 32 + fq * 8);
  }
  float mx[4] = {-3.0e38f, -3.0e38f, -3.0e38f, -3.0e38f};
  float sm[4] = {0.f, 0.f, 0.f, 0.f};
  const int srow = t >> 2, scol = (t & 3) * 16;
  for (int m0 = 0; m0 < kN; m0 += 64) {
    __syncthreads();
    {
      const ushort_t* qh = Qhi + qbase + (size_t)(m0 + srow) * kH + scol;
      const ushort_t* ql = Qlo + qbase + (size_t)(m0 + srow) * kH + scol;
      *(uint4*)&Bh[srow][scol] = *(const uint4*)qh;
      *(uint4*)&Bh[srow][scol + 8] = *(const uint4*)(qh + 8);
      *(uint4*)&Bl[srow][scol] = *(const uint4*)ql;
      *(uint4*)&Bl[srow][scol + 8] = *(const uint4*)(ql + 8);
    }
    __syncthreads();
    float ev[4][4];
#pragma unroll
    for (int cs = 0; cs < 4; ++cs) {
      const bf16x8 bh0 = *(const bf16x8*)&Bh[cs * 16 + fr][fq * 8];
      const bf16x8 bh1 = *(const bf16x8*)&Bh[cs * 16 + fr][32 + fq * 8];
      const bf16x8 bl0 = *(const bf16x8*)&Bl[cs * 16 + fr][fq * 8];
      const bf16x8 bl1 = *(const bf16x8*)&Bl[cs * 16 + fr][32 + fq * 8];
      f32x4 e = {0.f, 0.f, 0.f, 0.f};
      e = __builtin_amdgcn_mfma_f32_16x16x32_bf16(ah0, bh0, e, 0, 0, 0);
      e = __builtin_amdgcn_mfma_f32_16x16x32_bf16(ah1, bh1, e, 0, 0, 0);
      e = __builtin_amdgcn_mfma_f32_16x16x32_bf16(ah0, bl0, e, 0, 0, 0);
      e = __builtin_amdgcn_mfma_f32_16x16x32_bf16(ah1, bl1, e, 0, 0, 0);
      e = __builtin_amdgcn_mfma_f32_16x16x32_bf16(al0, bh0, e, 0, 0, 0);
      e = __builtin_amdgcn_mfma_f32_16x16x32_bf16(al1, bh1, e, 0, 0, 0);
      ev[cs][0] = e[0]; ev[cs][1] = e[1]; ev[cs][2] = e[2]; ev[cs][3] = e[3];
    }
#pragma unroll
    for (int r = 0; r < 4; ++r) {
      const float tmax = fmaxf(fmaxf(ev[0][r], ev[1][r]), fmaxf(ev[2][r], ev[3][r]));
      const float nm = fmaxf(mx[r], tmax);
      sm[r] = sm[r] * __expf(mx[r] - nm) + __expf(ev[0][r] - nm) + __expf(ev[1][r] - nm) +
              __expf(ev[2][r] - nm) + __expf(ev[3][r] - nm);
      mx[r] = nm;
    }
  }
#pragma unroll
  for (int mask = 1; mask < 16; mask <<= 1) {
#pragma unroll
    for (int r = 0; r < 4; ++r) {
      const float om = __shfl_xor(mx[r], mask);
      const float os = __shfl_xor(sm[r], mask);
      const float nm = fmaxf(mx[r], om);
      sm[r] = sm[r] * __expf(mx[r] - nm) + os * __expf(om - nm);
      mx[r] = nm;
    }
  }
  if (fr == 0) {
#pragma unroll
    for (int r = 0; r < 4; ++r) {
      const int row = r0 + w * 16 + fq * 4 + r;
      rmx[(size_t)b * kN + row] = mx[r];
      rsn[(size_t)b * kN + row] = 1.f / sm[r];
    }
  }
}

// ---------------------------------------------------------------------------
// Column pass, MT=64: E via split-bf16 MFMA; PV with A=P (rows=m), B=V
// (cols=c) so D maps to [m][c] -> epilogue writes U^T split bf16 [n][c]
// coalesced. x input read from p-split. Grid: (kN/64, kB).
// ---------------------------------------------------------------------------
__global__ __launch_bounds__(256) void k_colpass(const ushort_t* __restrict__ Qhi,
                                                 const ushort_t* __restrict__ Qlo,
                                                 const bf16* __restrict__ V,
                                                 const float* __restrict__ rmx,
                                                 const float* __restrict__ rsn,
                                                 const ushort_t* __restrict__ psh,
                                                 const ushort_t* __restrict__ psl,
                                                 ushort_t* __restrict__ ush,
                                                 ushort_t* __restrict__ usl) {
  constexpr int MT = 64, NT = 32;
  __shared__ __align__(16) ushort_t Anh[NT][72];  // Qn hi [n][k]
  __shared__ __align__(16) ushort_t Anl[NT][72];  // Qn lo [n][k]
  __shared__ __align__(16) ushort_t Vs[kC][40];   // V [c][n] bf16
  __shared__ __align__(16) ushort_t Pl[MT][40];   // P [m][n] bf16
  __shared__ float CsI[MT];
  const int t = threadIdx.x;
  const int b = blockIdx.y;
  const int mBase = blockIdx.x * MT;
  const size_t qbase = (size_t)b * kN * kH;
  const bf16* Vb_ = V + (size_t)b * kC * kN;
  const int lane = t & 63, wv = t >> 6;
  const int fr = lane & 15, fq = lane >> 4;
  // B fragments for E: my wave's m-slice, m = mBase + wv*16 + fr
  bf16x8 bmh0, bmh1, bml0, bml1;
  {
    const ushort_t* qh = Qhi + qbase + (size_t)(mBase + wv * 16 + fr) * kH;
    const ushort_t* ql = Qlo + qbase + (size_t)(mBase + wv * 16 + fr) * kH;
    bmh0 = *(const bf16x8*)(qh + fq * 8);
    bmh1 = *(const bf16x8*)(qh + 32 + fq * 8);
    bml0 = *(const bf16x8*)(ql + fq * 8);
    bml1 = *(const bf16x8*)(ql + 32 + fq * 8);
  }
  f32x4 acc[4][4];  // [ms][cs]: D row=m (ms), col=c (wave's c-slice)
#pragma unroll
  for (int i = 0; i < 4; ++i)
#pragma unroll
    for (int j = 0; j < 4; ++j) acc[i][j] = (f32x4){0.f, 0.f, 0.f, 0.f};
  float csloc = 0.f;
  const int arow = t >> 3, acol = (t & 7) * 8;  // Qn staging map
  const int vc = t >> 2, vq = t & 3;            // V staging map
  for (int n0 = 0; n0 < kN; n0 += NT) {
    __syncthreads();
    {
      *(uint4*)&Anh[arow][acol] = *(const uint4*)(Qhi + qbase + (size_t)(n0 + arow) * kH + acol);
      *(uint4*)&Anl[arow][acol] = *(const uint4*)(Qlo + qbase + (size_t)(n0 + arow) * kH + acol);
    }
#pragma unroll
    for (int it = 0; it < 4; ++it) {
      const int c = it * 64 + vc;
      *(uint4*)&Vs[c][vq * 8] = *(const uint4*)(Vb_ + (size_t)c * kN + n0 + vq * 8);
    }
    __syncthreads();
    // E phase: wave wv computes E for its m-slice x 32 n
#pragma unroll
    for (int ns = 0; ns < 2; ++ns) {
      const bf16x8 ah0 = *(const bf16x8*)&Anh[ns * 16 + fr][fq * 8];
      const bf16x8 ah1 = *(const bf16x8*)&Anh[ns * 16 + fr][32 + fq * 8];
      const bf16x8 al0 = *(const bf16x8*)&Anl[ns * 16 + fr][fq * 8];
      const bf16x8 al1 = *(const bf16x8*)&Anl[ns * 16 + fr][32 + fq * 8];
      f32x4 e = {0.f, 0.f, 0.f, 0.f};
      e = __builtin_amdgcn_mfma_f32_16x16x32_bf16(ah0, bmh0, e, 0, 0, 0);
      e = __builtin_amdgcn_mfma_f32_16x16x32_bf16(ah1, bmh1, e, 0, 0, 0);
      e = __builtin_amdgcn_mfma_f32_16x16x32_bf16(ah0, bml0, e, 0, 0, 0);
      e = __builtin_amdgcn_mfma_f32_16x16x32_bf16(ah1, bml1, e, 0, 0, 0);
      e = __builtin_amdgcn_mfma_f32_16x16x32_bf16(al0, bmh0, e, 0, 0, 0);
      e = __builtin_amdgcn_mfma_f32_16x16x32_bf16(al1, bmh1, e, 0, 0, 0);
#pragma unroll
      for (int r = 0; r < 4; ++r) {
        const int nl = ns * 16 + fq * 4 + r;
        const size_t gn = (size_t)b * kN + n0 + nl;
        const float p = __expf(e[r] - rmx[gn]) * rsn[gn];
        Pl[wv * 16 + fr][nl] = f2bu(p);
        csloc += p;
      }
    }
    __syncthreads();  // Pl complete
    // PV: A = Pl (rows m), B = Vs (cols c = wave's 64-c slice)
    bf16x8 am[4], bv[4];
#pragma unroll
    for (int ms = 0; ms < 4; ++ms)
      am[ms] = *(const bf16x8*)&Pl[ms * 16 + fr][fq * 8];
#pragma unroll
    for (int cs = 0; cs < 4; ++cs)
      bv[cs] = *(const bf16x8*)&Vs[wv * 64 + cs * 16 + fr][fq * 8];
#pragma unroll
    for (int ms = 0; ms < 4; ++ms)
#pragma unroll
      for (int cs = 0; cs < 4; ++cs)
        acc[ms][cs] = __builtin_amdgcn_mfma_f32_16x16x32_bf16(am[ms], bv[cs], acc[ms][cs], 0, 0, 0);
  }
  // colsum reduce over fq
  csloc += __shfl_xor(csloc, 16);
  csloc += __shfl_xor(csloc, 32);
  __syncthreads();
  if (fq == 0) CsI[wv * 16 + fr] = 1.f / (1e-9f + csloc);
  __syncthreads();
  // epilogue: row = m = ms*16+fq*4+r, col = c = wv*64+cs*16+fr
#pragma unroll
  for (int ms = 0; ms < 4; ++ms) {
#pragma unroll
    for (int r = 0; r < 4; ++r) {
      const int ml = ms * 16 + fq * 4 + r;
      const float inv = CsI[ml];
      const size_t row = ((size_t)b * kN + mBase + ml) * kC;
#pragma unroll
      for (int cs = 0; cs < 4; ++cs) {
        const int c = wv * 64 + cs * 16 + fr;
        const float xv = us2f(psh[row + c]) + us2f(psl[row + c]);
        const float u = xv - acc[ms][cs][r] * inv;
        const ushort_t h = f2bu(u);
        ush[row + c] = h;
        usl[row + c] = f2bu(u - us2f(h));
      }
    }
  }
}

// ---------------------------------------------------------------------------
// BN stats per channel over (B, N), fp32 [b][nch][N] input, biased var.
// ---------------------------------------------------------------------------
__global__ __launch_bounds__(256) void k_bnstats(const float* __restrict__ y, int nch,
                                                 float* __restrict__ mean,
                                                 float* __restrict__ rsig) {
  const int c = blockIdx.x, t = threadIdx.x;
  float s = 0.f, s2 = 0.f;
  for (int b = 0; b < kB; ++b) {
    const float* p = y + ((size_t)b * nch + c) * kN;
    for (int n = t; n < kN; n += 256) {
      const float v = p[n];
      s += v;
      s2 += v * v;
    }
  }
  __shared__ float r1[256], r2[256];
  r1[t] = s;
  r2[t] = s2;
  __syncthreads();
  for (int k = 128; k > 0; k >>= 1) {
    if (t < k) {
      r1[t] += r1[t + k];
      r2[t] += r2[t + k];
    }
    __syncthreads();
  }
  if (t == 0) {
    const float im = 1.f / (float)(kB * kN);
    const float m = r1[0] * im;
    const float var = r2[0] * im - m * m;
    mean[c] = m;
    rsig[c] = rsqrtf(var + 1e-5f);
  }
}

// ---------------------------------------------------------------------------
// dc2: tpre[b,j,n] = dc2_b[j] + sum_c dc2_w[j,c] * leaky(bn(h[b,c,n]))
// ---------------------------------------------------------------------------
__global__ __launch_bounds__(256) void k_dc2(const float* __restrict__ h,
                                             const float* __restrict__ mean,
                                             const float* __restrict__ rsig,
                                             const float* __restrict__ g,
                                             const float* __restrict__ bb,
                                             const float* __restrict__ w,
                                             const float* __restrict__ d2b,
                                             float* __restrict__ tpre) {
  __shared__ float wS[3][kC];
  __shared__ float aS[kC], cS[kC];
  const int t = threadIdx.x, b = blockIdx.y;
  const int n = blockIdx.x * 256 + t;
  {
    const float a = g[t] * rsig[t];
    aS[t] = a;
    cS[t] = bb[t] - a * mean[t];
    wS[0][t] = w[t];
    wS[1][t] = w[kC + t];
    wS[2][t] = w[2 * kC + t];
  }
  __syncthreads();
  float a0 = d2b[0], a1 = d2b[1], a2 = d2b[2];
  const float* hb = h + (size_t)b * kC * kN + n;
  for (int c = 0; c < kC; ++c) {
    float z = hb[(size_t)c * kN] * aS[c] + cS[c];
    z = z > 0.f ? z : 0.2f * z;
    a0 += wS[0][c] * z;
    a1 += wS[1][c] * z;
    a2 += wS[2][c] * z;
  }
  tpre[((size_t)b * 3 + 0) * kN + n] = a0;
  tpre[((size_t)b * 3 + 1) * kN + n] = a1;
  tpre[((size_t)b * 3 + 2) * kN + n] = a2;
}

// ---------------------------------------------------------------------------
// Final: out[b,n,j] = tanh(g[j]*(tpre[b,j,n]-mean[j])*rsig[j] + b[j])
// ---------------------------------------------------------------------------
__global__ __launch_bounds__(256) void k_final(const float* __restrict__ tpre,
                                               const float* __restrict__ mean,
                                               const float* __restrict__ rsig,
                                               const float* __restrict__ g,
                                               const float* __restrict__ bb,
                                               float* __restrict__ out) {
  const int i = blockIdx.x * 256 + threadIdx.x;  // over B*N
  const int n = i & (kN - 1), b = i >> 11;
#pragma unroll
  for (int j = 0; j < 3; ++j) {
    const float v = tpre[((size_t)b * 3 + j) * kN + n];
    const float z = g[j] * (v - mean[j]) * rsig[j] + bb[j];
    out[(size_t)i * 3 + j] = tanhf(z);
  }
}

// ---------------------------------------------------------------------------
extern "C" void kernel_launch(void* const* d_in, const int* in_sizes, int n_in,
                              void* d_out, int out_size, void* d_ws, size_t ws_size,
                              hipStream_t stream) {
  const float* feature  = (const float*)d_in[0];
  const float* prior    = (const float*)d_in[1];
  const float* mlp_w    = (const float*)d_in[2];
  const float* mlp_b    = (const float*)d_in[3];
  const float* qk_w     = (const float*)d_in[4];
  const float* qk_b     = (const float*)d_in[5];
  const float* v_w      = (const float*)d_in[6];
  const float* v_b      = (const float*)d_in[7];
  const float* t_w      = (const float*)d_in[8];
  const float* t_b      = (const float*)d_in[9];
  const float* bn_g     = (const float*)d_in[10];
  const float* bn_b     = (const float*)d_in[11];
  const float* dc1_w    = (const float*)d_in[12];
  const float* dc1_bn_g = (const float*)d_in[13];
  const float* dc1_bn_b = (const float*)d_in[14];
  const float* dc2_w    = (const float*)d_in[15];
  const float* dc2_b    = (const float*)d_in[16];
  const float* dc2_bn_g = (const float*)d_in[17];
  const float* dc2_bn_b = (const float*)d_in[18];
  float* out = (float*)d_out;

  // Workspace carve. Total ~125 MiB.
  char* base = (char*)d_ws;
  size_t off = 0;
  auto carve = [&](size_t bytes) {
    char* p = base + off;
    off += (bytes + 255) & ~(size_t)255;
    return p;
  };
  const size_t ne = (size_t)kB * kN * kC;                 // 8,388,608
  ushort_t* psh  = (ushort_t*)carve(ne * 2);              // p hi   16 MiB
  ushort_t* psl  = (ushort_t*)carve(ne * 2);              // p lo   16 MiB
  ushort_t* ush  = (ushort_t*)carve(ne * 2);              // u hi   16 MiB
  ushort_t* usl  = (ushort_t*)carve(ne * 2);              // u lo   16 MiB
  float*    hacc = (float*)carve(ne * 4);                 // dc1    32 MiB
  ushort_t* Qhi  = (ushort_t*)carve((size_t)kB * kN * kH * 2);  // 4 MiB
  ushort_t* Qlo  = (ushort_t*)carve((size_t)kB * kN * kH * 2);  // 4 MiB
  bf16*     Vb   = (bf16*)carve(ne * 2);                  // V      16 MiB
  ushort_t* wfh  = (ushort_t*)carve((size_t)851968 * 2);  // 1.63 MiB
  ushort_t* wfl  = (ushort_t*)carve((size_t)851968 * 2);  // 1.63 MiB
  float*    part = (float*)carve((size_t)2 * 131072 * 4); // 1 MiB
  float*    rmx  = (float*)carve((size_t)kB * kN * 4);
  float*    rsn  = (float*)carve((size_t)kB * kN * 4);
  float*    fb   = (float*)carve((size_t)kB * kC * 4);
  float*    bnm  = (float*)carve(kC * 4);
  float*    bnr  = (float*)carve(kC * 4);
  float*    tpre = (float*)carve((size_t)kB * 3 * kN * 4);

  k_wsplit<<<416, 256, 0, stream>>>(qk_w, v_w, t_w, dc1_w, wfh, wfl);
  k_fb<<<kB * kC, 256, 0, stream>>>(feature, mlp_w, mlp_b, fb);
  k_p0<<<(int)(ne / 256), 256, 0, stream>>>(prior, mlp_w, fb, psh, psl);

  const dim3 gC(kN / 64, kB);
  for (int l = 0; l < 4; ++l) {
    const size_t qk_off  = (size_t)l * 16384;
    const size_t v_off   = 65536 + (size_t)l * 65536;
    const size_t t_off   = 327680 + (size_t)l * 65536;
    const size_t dc1_off = 589824 + (size_t)l * 65536;
    k_conv<64, 0><<<gC, 256, 0, stream>>>(psh, psl, wfh + qk_off, wfl + qk_off,
                                          qk_b + l * kH, Qhi, Qlo, nullptr, nullptr,
                                          nullptr, nullptr, nullptr, nullptr, 0);
    k_conv<256, 1><<<gC, 256, 0, stream>>>(psh, psl, wfh + v_off, wfl + v_off,
                                           v_b + l * kC, nullptr, nullptr, Vb, nullptr,
                                           nullptr, nullptr, nullptr, nullptr, 0);
    k_rowstats<<<gC, 256, 0, stream>>>(Qhi, Qlo, rmx, rsn);
    k_colpass<<<gC, 256, 0, stream>>>(Qhi, Qlo, Vb, rmx, rsn, psh, psl, ush, usl);
    k_conv<256, 2><<<gC, 256, 0, stream>>>(ush, usl, wfh + t_off, wfl + t_off,
                                           t_b + l * kC, nullptr, nullptr, nullptr, part,
                                           nullptr, nullptr, nullptr, nullptr, 0);
    k_bnred<<<kC, 128, 0, stream>>>(part, bnm, bnr);
    k_conv<256, 3><<<gC, 256, 0, stream>>>(ush, usl, wfh + t_off, wfl + t_off,
                                           t_b + l * kC, psh, psl, nullptr, nullptr,
                                           bnm, bnr, bn_g + l * kC, bn_b + l * kC, 0);
    k_conv<256, 4><<<gC, 256, 0, stream>>>(psh, psl, wfh + dc1_off, wfl + dc1_off,
                                           nullptr, nullptr, nullptr, nullptr, hacc,
                                           nullptr, nullptr, nullptr, nullptr, l == 0 ? 1 : 0);
  }

  k_bnstats<<<kC, 256, 0, stream>>>(hacc, kC, bnm, bnr);
  k_dc2<<<dim3(kN / 256, kB), 256, 0, stream>>>(hacc, bnm, bnr, dc1_bn_g, dc1_bn_b,
                                                dc2_w, dc2_b, tpre);
  k_bnstats<<<3, 256, 0, stream>>>(tpre, 3, bnm, bnr);
  k_final<<<(kB * kN) / 256, 256, 0, stream>>>(tpre, bnm, bnr, dc2_bn_g, dc2_bn_b, out);
}

// Round 9
// 1270.025 us; speedup vs baseline: 9.6199x; 1.1082x over previous
//
#include <hip/hip_runtime.h>
#include <hip/hip_bf16.h>

typedef __hip_bfloat16 bf16;
typedef unsigned short ushort_t;

// Problem constants
constexpr int kB = 16;    // batch
constexpr int kN = 2048;  // points
constexpr int kF = 1024;  // feat dims
constexpr int kC = 256;   // channels
constexpr int kH = 64;    // head dim

using f32x4 = __attribute__((ext_vector_type(4))) float;
using bf16x8 = __attribute__((ext_vector_type(8))) short;  // 8 bf16 (4 VGPRs)

__device__ __forceinline__ float us2f(unsigned short u) {
  union { unsigned int i; float f; } w;
  w.i = ((unsigned int)u) << 16;
  return w.f;
}
__device__ __forceinline__ unsigned short f2bu(float f) {
  union { bf16 h; unsigned short s; } u;
  u.h = __float2bfloat16(f);
  return u.s;
}

// ---------------------------------------------------------------------------
// fb[b,c] = mlp_b[c] + sum_f mlp_w[c,f] * feature[b,f]
// ---------------------------------------------------------------------------
__global__ __launch_bounds__(256) void k_fb(const float* __restrict__ feat,
                                            const float* __restrict__ mlp_w,
                                            const float* __restrict__ mlp_b,
                                            float* __restrict__ fb) {
  const int b = blockIdx.x >> 8;
  const int c = blockIdx.x & 255;
  const int t = threadIdx.x;
  const float* wr = mlp_w + (size_t)c * (kF + 3);
  const float* fr = feat + (size_t)b * kF;
  float s = 0.f;
  for (int f = t; f < kF; f += 256) s += wr[f] * fr[f];
  __shared__ float red[256];
  red[t] = s;
  __syncthreads();
  for (int k = 128; k > 0; k >>= 1) {
    if (t < k) red[t] += red[t + k];
    __syncthreads();
  }
  if (t == 0) fb[blockIdx.x] = red[0] + mlp_b[c];
}

// ---------------------------------------------------------------------------
// p[b,n,c] = fb[b,c] + sum_{j<3} mlp_w[c,1024+j] * prior[b,j,n]  (split bf16)
// ---------------------------------------------------------------------------
__global__ __launch_bounds__(256) void k_p0(const float* __restrict__ prior,
                                            const float* __restrict__ mlp_w,
                                            const float* __restrict__ fb,
                                            ushort_t* __restrict__ psh,
                                            ushort_t* __restrict__ psl) {
  const size_t i = (size_t)blockIdx.x * 256 + threadIdx.x;  // over B*N*C
  const int c = (int)(i & 255);
  const int n = (int)((i >> 8) & 2047);
  const int b = (int)(i >> 19);
  const float* wr = mlp_w + (size_t)c * (kF + 3) + kF;
  const float* pr = prior + (size_t)b * 3 * kN + n;
  const float v = fb[b * kC + c] + wr[0] * pr[0] + wr[1] * pr[kN] + wr[2] * pr[2 * kN];
  const ushort_t h = f2bu(v);
  psh[i] = h;
  psl[i] = f2bu(v - us2f(h));
}

// ---------------------------------------------------------------------------
// Pre-split weights into MFMA A-fragment order (hi/lo bf16).
// Regions (group = 8 elems): qk 4x2048 | v 4x8192 | t 4x8192 | dc1 4x8192
// ---------------------------------------------------------------------------
__global__ __launch_bounds__(256) void k_wsplit(const float* __restrict__ qk_w,
                                                const float* __restrict__ v_w,
                                                const float* __restrict__ t_w,
                                                const float* __restrict__ dc1_w,
                                                ushort_t* __restrict__ wfh,
                                                ushort_t* __restrict__ wfl) {
  const int idx = blockIdx.x * 256 + threadIdx.x;  // group index
  const float* src;
  int stride, OS_;
  size_t dstoff;
  int g;
  if (idx < 8192) {
    const int l = idx >> 11; g = idx & 2047;
    src = qk_w + (size_t)l * 64 * 256; stride = 256; OS_ = 4;
    dstoff = (size_t)l * 16384;
  } else if (idx < 40960) {
    const int i2 = idx - 8192; const int l = i2 >> 13; g = i2 & 8191;
    src = v_w + (size_t)l * 256 * 256; stride = 256; OS_ = 16;
    dstoff = 65536 + (size_t)l * 65536;
  } else if (idx < 73728) {
    const int i2 = idx - 40960; const int l = i2 >> 13; g = i2 & 8191;
    src = t_w + (size_t)l * 256 * 256; stride = 256; OS_ = 16;
    dstoff = 327680 + (size_t)l * 65536;
  } else {
    const int i2 = idx - 73728; const int l = i2 >> 13; g = i2 & 8191;
    src = dc1_w + (size_t)l * 256; stride = 1024; OS_ = 16;
    dstoff = 589824 + (size_t)l * 65536;
  }
  const int kk = g / (OS_ * 64);
  const int rem = g % (OS_ * 64);
  const int osub = rem >> 6;
  const int lane = rem & 63;
  const int o = osub * 16 + (lane & 15);
  const int c = kk * 32 + (lane >> 4) * 8;
  const float* sp = src + (size_t)o * stride + c;
  ushort_t h[8], l8[8];
#pragma unroll
  for (int j = 0; j < 8; ++j) {
    const float v = sp[j];
    h[j] = f2bu(v);
    l8[j] = f2bu(v - us2f(h[j]));
  }
  *(uint4*)(wfh + dstoff + (size_t)g * 8) = *(const uint4*)h;
  *(uint4*)(wfl + dstoff + (size_t)g * 8) = *(const uint4*)l8;
}

// ---------------------------------------------------------------------------
// Fused Q+V conv (split-bf16 MFMA, x read once). Block: 64 n, 4 waves.
// Wave wv: Q subtile wv (16 out) + V subtiles wv*4..+3 (64 out).
// Q out: split [b][n][64]; V out: bf16 [b][o][N].
// ---------------------------------------------------------------------------
__global__ __launch_bounds__(256) void k_qv(
    const ushort_t* __restrict__ xh, const ushort_t* __restrict__ xl,
    const ushort_t* __restrict__ wqh, const ushort_t* __restrict__ wql,
    const ushort_t* __restrict__ wvh, const ushort_t* __restrict__ wvl,
    const float* __restrict__ qbias, const float* __restrict__ vbias,
    ushort_t* __restrict__ Qh, ushort_t* __restrict__ Ql,
    bf16* __restrict__ Vo) {
  const int t = threadIdx.x;
  const int b = blockIdx.y;
  const int n0 = blockIdx.x * 64;
  const int lane = t & 63, wv = t >> 6;
  const int fr = lane & 15, fq = lane >> 4;
  const ushort_t* xbh = xh + ((size_t)b * kN + n0) * kC;
  const ushort_t* xbl = xl + ((size_t)b * kN + n0) * kC;
  f32x4 accq[4];
  f32x4 accv[4][4];
#pragma unroll
  for (int ns = 0; ns < 4; ++ns) {
    accq[ns] = (f32x4){0.f, 0.f, 0.f, 0.f};
#pragma unroll
    for (int s = 0; s < 4; ++s) accv[s][ns] = (f32x4){0.f, 0.f, 0.f, 0.f};
  }
  for (int kk = 0; kk < 8; ++kk) {
    bf16x8 bh[4], bl[4];
#pragma unroll
    for (int ns = 0; ns < 4; ++ns) {
      const size_t xi = (size_t)(ns * 16 + fr) * kC + kk * 32 + fq * 8;
      bh[ns] = *(const bf16x8*)(xbh + xi);
      bl[ns] = *(const bf16x8*)(xbl + xi);
    }
    {  // Q weights: region OS=4
      const size_t wi = (((size_t)kk * 4 + wv) * 64 + lane) * 8;
      const bf16x8 ah = *(const bf16x8*)(wqh + wi);
      const bf16x8 al = *(const bf16x8*)(wql + wi);
#pragma unroll
      for (int ns = 0; ns < 4; ++ns) {
        accq[ns] = __builtin_amdgcn_mfma_f32_16x16x32_bf16(ah, bh[ns], accq[ns], 0, 0, 0);
        accq[ns] = __builtin_amdgcn_mfma_f32_16x16x32_bf16(ah, bl[ns], accq[ns], 0, 0, 0);
        accq[ns] = __builtin_amdgcn_mfma_f32_16x16x32_bf16(al, bh[ns], accq[ns], 0, 0, 0);
      }
    }
#pragma unroll
    for (int s = 0; s < 4; ++s) {  // V weights: region OS=16
      const size_t wi = (((size_t)kk * 16 + wv * 4 + s) * 64 + lane) * 8;
      const bf16x8 ah = *(const bf16x8*)(wvh + wi);
      const bf16x8 al = *(const bf16x8*)(wvl + wi);
#pragma unroll
      for (int ns = 0; ns < 4; ++ns) {
        accv[s][ns] = __builtin_amdgcn_mfma_f32_16x16x32_bf16(ah, bh[ns], accv[s][ns], 0, 0, 0);
        accv[s][ns] = __builtin_amdgcn_mfma_f32_16x16x32_bf16(ah, bl[ns], accv[s][ns], 0, 0, 0);
        accv[s][ns] = __builtin_amdgcn_mfma_f32_16x16x32_bf16(al, bh[ns], accv[s][ns], 0, 0, 0);
      }
    }
  }
  // Q epilogue: o = wv*16 + fq*4 + r, n = n0 + ns*16 + fr (split bf16)
  {
    const int o0 = wv * 16 + fq * 4;
#pragma unroll
    for (int ns = 0; ns < 4; ++ns) {
      const int n = n0 + ns * 16 + fr;
      ushort_t h4[4], l4[4];
#pragma unroll
      for (int r = 0; r < 4; ++r) {
        const float v = accq[ns][r] + qbias[o0 + r];
        h4[r] = f2bu(v);
        l4[r] = f2bu(v - us2f(h4[r]));
      }
      *(ushort4*)(Qh + ((size_t)b * kN + n) * kH + o0) = *(const ushort4*)h4;
      *(ushort4*)(Ql + ((size_t)b * kN + n) * kH + o0) = *(const ushort4*)l4;
    }
  }
  // V epilogue: o = (wv*4+s)*16 + fq*4 + r
#pragma unroll
  for (int s = 0; s < 4; ++s) {
    const int o0 = (wv * 4 + s) * 16 + fq * 4;
#pragma unroll
    for (int ns = 0; ns < 4; ++ns) {
      const int n = n0 + ns * 16 + fr;
#pragma unroll
      for (int r = 0; r < 4; ++r)
        Vo[((size_t)b * kC + o0 + r) * kN + n] = __float2bfloat16(accv[s][ns][r] + vbias[o0 + r]);
    }
  }
}

// ---------------------------------------------------------------------------
// MFMA 1x1 conv (split-bf16). x: [b][n][256] split. Block: 64 n, 4 waves.
// MODE 2: BN partial stats only    MODE 3: fused BN+leaky+residual into p
// MODE 4: fp32 accumulate [b][o][N] (dc1)
// ---------------------------------------------------------------------------
template <int O, int MODE>
__global__ __launch_bounds__(256) void k_conv(
    const ushort_t* __restrict__ xh, const ushort_t* __restrict__ xl,
    const ushort_t* __restrict__ wfh, const ushort_t* __restrict__ wfl,
    const float* __restrict__ bias,
    ushort_t* __restrict__ o1, ushort_t* __restrict__ o2,  // psh/psl (MODE3)
    float* __restrict__ of,                                // part or hacc
    const float* __restrict__ mean, const float* __restrict__ rsig,
    const float* __restrict__ g, const float* __restrict__ bb, int first) {
  constexpr int KK = 8;
  constexpr int OS = O / 16;
  constexpr int OSW = OS / 4;
  const int t = threadIdx.x;
  const int b = blockIdx.y;
  const int n0 = blockIdx.x * 64;
  const int lane = t & 63, wv = t >> 6;
  const int fr = lane & 15, fq = lane >> 4;
  const ushort_t* xbh = xh + ((size_t)b * kN + n0) * kC;
  const ushort_t* xbl = xl + ((size_t)b * kN + n0) * kC;
  f32x4 acc[OSW][4];
#pragma unroll
  for (int s = 0; s < OSW; ++s)
#pragma unroll
    for (int ns = 0; ns < 4; ++ns) acc[s][ns] = (f32x4){0.f, 0.f, 0.f, 0.f};
  for (int kk = 0; kk < KK; ++kk) {
    bf16x8 bh[4], bl[4];
#pragma unroll
    for (int ns = 0; ns < 4; ++ns) {
      const size_t xi = (size_t)(ns * 16 + fr) * kC + kk * 32 + fq * 8;
      bh[ns] = *(const bf16x8*)(xbh + xi);
      bl[ns] = *(const bf16x8*)(xbl + xi);
    }
#pragma unroll
    for (int s = 0; s < OSW; ++s) {
      const size_t wi = (((size_t)kk * OS + wv * OSW + s) * 64 + lane) * 8;
      const bf16x8 ah = *(const bf16x8*)(wfh + wi);
      const bf16x8 al = *(const bf16x8*)(wfl + wi);
#pragma unroll
      for (int ns = 0; ns < 4; ++ns) {
        acc[s][ns] = __builtin_amdgcn_mfma_f32_16x16x32_bf16(ah, bh[ns], acc[s][ns], 0, 0, 0);
        acc[s][ns] = __builtin_amdgcn_mfma_f32_16x16x32_bf16(ah, bl[ns], acc[s][ns], 0, 0, 0);
        acc[s][ns] = __builtin_amdgcn_mfma_f32_16x16x32_bf16(al, bh[ns], acc[s][ns], 0, 0, 0);
      }
    }
  }
  if (MODE == 2) {
    const int blk = blockIdx.y * gridDim.x + blockIdx.x;  // 0..511
#pragma unroll
    for (int s = 0; s < OSW; ++s) {
      const int o0 = (wv * OSW + s) * 16 + fq * 4;
#pragma unroll
      for (int r = 0; r < 4; ++r) {
        const float bz = bias[o0 + r];
        float s1 = 0.f, s2 = 0.f;
#pragma unroll
        for (int ns = 0; ns < 4; ++ns) {
          const float y = acc[s][ns][r] + bz;
          s1 += y;
          s2 += y * y;
        }
#pragma unroll
        for (int mask = 1; mask < 16; mask <<= 1) {
          s1 += __shfl_xor(s1, mask);
          s2 += __shfl_xor(s2, mask);
        }
        if (fr == 0) {
          of[(size_t)(o0 + r) * 512 + blk] = s1;
          of[131072 + (size_t)(o0 + r) * 512 + blk] = s2;
        }
      }
    }
  } else if (MODE == 3) {
#pragma unroll
    for (int s = 0; s < OSW; ++s) {
      const int o0 = (wv * OSW + s) * 16 + fq * 4;
      float av[4], cv[4];
#pragma unroll
      for (int r = 0; r < 4; ++r) {
        const float a = g[o0 + r] * rsig[o0 + r];
        av[r] = a;
        cv[r] = bb[o0 + r] + a * (bias[o0 + r] - mean[o0 + r]);
      }
#pragma unroll
      for (int ns = 0; ns < 4; ++ns) {
        const int n = n0 + ns * 16 + fr;
        const size_t idx = ((size_t)b * kN + n) * kC + o0;
        ushort_t ph4[4], pl4[4], nh4[4], nl4[4];
        *(ushort4*)ph4 = *(const ushort4*)(o1 + idx);
        *(ushort4*)pl4 = *(const ushort4*)(o2 + idx);
#pragma unroll
        for (int r = 0; r < 4; ++r) {
          float z = av[r] * acc[s][ns][r] + cv[r];
          z = z > 0.f ? z : 0.2f * z;
          const float pv = us2f(ph4[r]) + us2f(pl4[r]) + z;
          nh4[r] = f2bu(pv);
          nl4[r] = f2bu(pv - us2f(nh4[r]));
        }
        *(ushort4*)(o1 + idx) = *(const ushort4*)nh4;
        *(ushort4*)(o2 + idx) = *(const ushort4*)nl4;
      }
    }
  } else {  // MODE 4: accumulate into hacc [b][o][N]
#pragma unroll
    for (int s = 0; s < OSW; ++s) {
      const int o0 = (wv * OSW + s) * 16 + fq * 4;
#pragma unroll
      for (int ns = 0; ns < 4; ++ns) {
        const int n = n0 + ns * 16 + fr;
#pragma unroll
        for (int r = 0; r < 4; ++r) {
          float* pp = of + ((size_t)b * kC + o0 + r) * kN + n;
          *pp = (first ? 0.f : *pp) + acc[s][ns][r];
        }
      }
    }
  }
}

// ---------------------------------------------------------------------------
// Reduce BN partials (part [c][512] sums + [c][512] sumsq at offset 131072)
// ---------------------------------------------------------------------------
__global__ __launch_bounds__(128) void k_bnred(const float* __restrict__ part,
                                               float* __restrict__ mean,
                                               float* __restrict__ rsig) {
  const int c = blockIdx.x, t = threadIdx.x;
  const float4 v1 = *(const float4*)&part[(size_t)c * 512 + t * 4];
  const float4 v2 = *(const float4*)&part[131072 + (size_t)c * 512 + t * 4];
  float s1 = v1.x + v1.y + v1.z + v1.w;
  float s2 = v2.x + v2.y + v2.z + v2.w;
  __shared__ float r1[128], r2[128];
  r1[t] = s1;
  r2[t] = s2;
  __syncthreads();
  for (int k = 64; k > 0; k >>= 1) {
    if (t < k) {
      r1[t] += r1[t + k];
      r2[t] += r2[t + k];
    }
    __syncthreads();
  }
  if (t == 0) {
    const float im = 1.f / (float)(kB * kN);
    const float m = r1[0] * im;
    const float var = r2[0] * im - m * m;
    mean[c] = m;
    rsig[c] = rsqrtf(var + 1e-5f);
  }
}

// ---------------------------------------------------------------------------
// Row softmax stats via split-bf16 MFMA, LDS double-buffered staging.
// Block: 64 rows (4 waves x 16), col tiles of 64, online softmax.
// ---------------------------------------------------------------------------
__global__ __launch_bounds__(256) void k_rowstats(const ushort_t* __restrict__ Qhi,
                                                  const ushort_t* __restrict__ Qlo,
                                                  float* __restrict__ rmx,
                                                  float* __restrict__ rsn) {
  __shared__ __align__(16) ushort_t Bh[2][64][72];
  __shared__ __align__(16) ushort_t Bl[2][64][72];
  const int b = blockIdx.y, t = threadIdx.x;
  const int r0 = blockIdx.x * 64;
  const int lane = t & 63, w = t >> 6;
  const int fr = lane & 15, fq = lane >> 4;
  const size_t qbase = (size_t)b * kN * kH;
  bf16x8 ah0, ah1, al0, al1;
  {
    const ushort_t* qh = Qhi + qbase + (size_t)(r0 + w * 16 + fr) * kH;
    const ushort_t* ql = Qlo + qbase + (size_t)(r0 + w * 16 + fr) * kH;
    ah0 = *(const bf16x8*)(qh + fq * 8);
    ah1 = *(const bf16x8*)(qh + 32 + fq * 8);
    al0 = *(const bf16x8*)(ql + fq * 8);
    al1 = *(const bf16x8*)(ql + 32 + fq * 8);
  }
  float mx[4] = {-3.0e38f, -3.0e38f, -3.0e38f, -3.0e38f};
  float sm[4] = {0.f, 0.f, 0.f, 0.f};
  const int srow = t >> 2, scol = (t & 3) * 16;
  auto stage = [&](int buf, int m0) {
    const ushort_t* qh = Qhi + qbase + (size_t)(m0 + srow) * kH + scol;
    const ushort_t* ql = Qlo + qbase + (size_t)(m0 + srow) * kH + scol;
    *(uint4*)&Bh[buf][srow][scol] = *(const uint4*)qh;
    *(uint4*)&Bh[buf][srow][scol + 8] = *(const uint4*)(qh + 8);
    *(uint4*)&Bl[buf][srow][scol] = *(const uint4*)ql;
    *(uint4*)&Bl[buf][srow][scol + 8] = *(const uint4*)(ql + 8);
  };
  stage(0, 0);
  __syncthreads();
  int cur = 0;
  for (int m0 = 0; m0 < kN; m0 += 64) {
    if (m0 + 64 < kN) stage(cur ^ 1, m0 + 64);
    float ev[4][4];
#pragma unroll
    for (int cs = 0; cs < 4; ++cs) {
      const bf16x8 bh0 = *(const bf16x8*)&Bh[cur][cs * 16 + fr][fq * 8];
      const bf16x8 bh1 = *(const bf16x8*)&Bh[cur][cs * 16 + fr][32 + fq * 8];
      const bf16x8 bl0 = *(const bf16x8*)&Bl[cur][cs * 16 + fr][fq * 8];
      const bf16x8 bl1 = *(const bf16x8*)&Bl[cur][cs * 16 + fr][32 + fq * 8];
      f32x4 e = {0.f, 0.f, 0.f, 0.f};
      e = __builtin_amdgcn_mfma_f32_16x16x32_bf16(ah0, bh0, e, 0, 0, 0);
      e = __builtin_amdgcn_mfma_f32_16x16x32_bf16(ah1, bh1, e, 0, 0, 0);
      e = __builtin_amdgcn_mfma_f32_16x16x32_bf16(ah0, bl0, e, 0, 0, 0);
      e = __builtin_amdgcn_mfma_f32_16x16x32_bf16(ah1, bl1, e, 0, 0, 0);
      e = __builtin_amdgcn_mfma_f32_16x16x32_bf16(al0, bh0, e, 0, 0, 0);
      e = __builtin_amdgcn_mfma_f32_16x16x32_bf16(al1, bh1, e, 0, 0, 0);
      ev[cs][0] = e[0]; ev[cs][1] = e[1]; ev[cs][2] = e[2]; ev[cs][3] = e[3];
    }
#pragma unroll
    for (int r = 0; r < 4; ++r) {
      const float tmax = fmaxf(fmaxf(ev[0][r], ev[1][r]), fmaxf(ev[2][r], ev[3][r]));
      const float nm = fmaxf(mx[r], tmax);
      sm[r] = sm[r] * __expf(mx[r] - nm) + __expf(ev[0][r] - nm) + __expf(ev[1][r] - nm) +
              __expf(ev[2][r] - nm) + __expf(ev[3][r] - nm);
      mx[r] = nm;
    }
    __syncthreads();  // compute reads of cur done + stage of cur^1 complete
    cur ^= 1;
  }
#pragma unroll
  for (int mask = 1; mask < 16; mask <<= 1) {
#pragma unroll
    for (int r = 0; r < 4; ++r) {
      const float om = __shfl_xor(mx[r], mask);
      const float os = __shfl_xor(sm[r], mask);
      const float nm = fmaxf(mx[r], om);
      sm[r] = sm[r] * __expf(mx[r] - nm) + os * __expf(om - nm);
      mx[r] = nm;
    }
  }
  if (fr == 0) {
#pragma unroll
    for (int r = 0; r < 4; ++r) {
      const int row = r0 + w * 16 + fq * 4 + r;
      rmx[(size_t)b * kN + row] = mx[r];
      rsn[(size_t)b * kN + row] = 1.f / sm[r];
    }
  }
}

// ---------------------------------------------------------------------------
// Column pass, MT=64, LDS double-buffered staging (stage t+1 overlaps
// compute t). E via split-bf16 MFMA; PV A=P B=V -> U^T split [n][c].
// ---------------------------------------------------------------------------
__global__ __launch_bounds__(256) void k_colpass(const ushort_t* __restrict__ Qhi,
                                                 const ushort_t* __restrict__ Qlo,
                                                 const bf16* __restrict__ V,
                                                 const float* __restrict__ rmx,
                                                 const float* __restrict__ rsn,
                                                 const ushort_t* __restrict__ psh,
                                                 const ushort_t* __restrict__ psl,
                                                 ushort_t* __restrict__ ush,
                                                 ushort_t* __restrict__ usl) {
  constexpr int MT = 64, NT = 32;
  __shared__ __align__(16) ushort_t Anh[2][NT][72];
  __shared__ __align__(16) ushort_t Anl[2][NT][72];
  __shared__ __align__(16) ushort_t Vs[2][kC][40];
  __shared__ __align__(16) ushort_t Pl[MT][40];
  __shared__ float CsI[MT];
  const int t = threadIdx.x;
  const int b = blockIdx.y;
  const int mBase = blockIdx.x * MT;
  const size_t qbase = (size_t)b * kN * kH;
  const ushort_t* Vb_ = (const ushort_t*)V + (size_t)b * kC * kN;
  const int lane = t & 63, wv = t >> 6;
  const int fr = lane & 15, fq = lane >> 4;
  bf16x8 bmh0, bmh1, bml0, bml1;
  {
    const ushort_t* qh = Qhi + qbase + (size_t)(mBase + wv * 16 + fr) * kH;
    const ushort_t* ql = Qlo + qbase + (size_t)(mBase + wv * 16 + fr) * kH;
    bmh0 = *(const bf16x8*)(qh + fq * 8);
    bmh1 = *(const bf16x8*)(qh + 32 + fq * 8);
    bml0 = *(const bf16x8*)(ql + fq * 8);
    bml1 = *(const bf16x8*)(ql + 32 + fq * 8);
  }
  f32x4 acc[4][4];
#pragma unroll
  for (int i = 0; i < 4; ++i)
#pragma unroll
    for (int j = 0; j < 4; ++j) acc[i][j] = (f32x4){0.f, 0.f, 0.f, 0.f};
  float csloc = 0.f;
  const int arow = t >> 3, acol = (t & 7) * 8;  // Qn staging map
  const int vc = t >> 2, vq = t & 3;            // V staging map
  auto stage = [&](int buf, int n0) {
    *(uint4*)&Anh[buf][arow][acol] =
        *(const uint4*)(Qhi + qbase + (size_t)(n0 + arow) * kH + acol);
    *(uint4*)&Anl[buf][arow][acol] =
        *(const uint4*)(Qlo + qbase + (size_t)(n0 + arow) * kH + acol);
#pragma unroll
    for (int it = 0; it < 4; ++it) {
      const int c = it * 64 + vc;
      *(uint4*)&Vs[buf][c][vq * 8] = *(const uint4*)(Vb_ + (size_t)c * kN + n0 + vq * 8);
    }
  };
  stage(0, 0);
  __syncthreads();
  int cur = 0;
  for (int n0 = 0; n0 < kN; n0 += NT) {
    if (n0 + NT < kN) stage(cur ^ 1, n0 + NT);  // overlaps compute below
    // E phase: wave wv computes E for its m-slice x 32 n
#pragma unroll
    for (int ns = 0; ns < 2; ++ns) {
      const bf16x8 ah0 = *(const bf16x8*)&Anh[cur][ns * 16 + fr][fq * 8];
      const bf16x8 ah1 = *(const bf16x8*)&Anh[cur][ns * 16 + fr][32 + fq * 8];
      const bf16x8 al0 = *(const bf16x8*)&Anl[cur][ns * 16 + fr][fq * 8];
      const bf16x8 al1 = *(const bf16x8*)&Anl[cur][ns * 16 + fr][32 + fq * 8];
      f32x4 e = {0.f, 0.f, 0.f, 0.f};
      e = __builtin_amdgcn_mfma_f32_16x16x32_bf16(ah0, bmh0, e, 0, 0, 0);
      e = __builtin_amdgcn_mfma_f32_16x16x32_bf16(ah1, bmh1, e, 0, 0, 0);
      e = __builtin_amdgcn_mfma_f32_16x16x32_bf16(ah0, bml0, e, 0, 0, 0);
      e = __builtin_amdgcn_mfma_f32_16x16x32_bf16(ah1, bml1, e, 0, 0, 0);
      e = __builtin_amdgcn_mfma_f32_16x16x32_bf16(al0, bmh0, e, 0, 0, 0);
      e = __builtin_amdgcn_mfma_f32_16x16x32_bf16(al1, bmh1, e, 0, 0, 0);
#pragma unroll
      for (int r = 0; r < 4; ++r) {
        const int nl = ns * 16 + fq * 4 + r;
        const size_t gn = (size_t)b * kN + n0 + nl;
        const float p = __expf(e[r] - rmx[gn]) * rsn[gn];
        Pl[wv * 16 + fr][nl] = f2bu(p);
        csloc += p;
      }
    }
    __syncthreads();  // Pl visible
    // PV: A = Pl (rows m), B = Vs (cols c = wave's 64-c slice)
    bf16x8 am[4], bv[4];
#pragma unroll
    for (int ms = 0; ms < 4; ++ms)
      am[ms] = *(const bf16x8*)&Pl[ms * 16 + fr][fq * 8];
#pragma unroll
    for (int cs = 0; cs < 4; ++cs)
      bv[cs] = *(const bf16x8*)&Vs[cur][wv * 64 + cs * 16 + fr][fq * 8];
#pragma unroll
    for (int ms = 0; ms < 4; ++ms)
#pragma unroll
      for (int cs = 0; cs < 4; ++cs)
        acc[ms][cs] = __builtin_amdgcn_mfma_f32_16x16x32_bf16(am[ms], bv[cs], acc[ms][cs], 0, 0, 0);
    __syncthreads();  // compute reads of cur & Pl done; stage of cur^1 done
    cur ^= 1;
  }
  // colsum reduce over fq
  csloc += __shfl_xor(csloc, 16);
  csloc += __shfl_xor(csloc, 32);
  if (fq == 0) CsI[wv * 16 + fr] = 1.f / (1e-9f + csloc);
  __syncthreads();
  // epilogue: row = m = ms*16+fq*4+r, col = c = wv*64+cs*16+fr
#pragma unroll
  for (int ms = 0; ms < 4; ++ms) {
#pragma unroll
    for (int r = 0; r < 4; ++r) {
      const int ml = ms * 16 + fq * 4 + r;
      const float inv = CsI[ml];
      const size_t row = ((size_t)b * kN + mBase + ml) * kC;
#pragma unroll
      for (int cs = 0; cs < 4; ++cs) {
        const int c = wv * 64 + cs * 16 + fr;
        const float xv = us2f(psh[row + c]) + us2f(psl[row + c]);
        const float u = xv - acc[ms][cs][r] * inv;
        const ushort_t h = f2bu(u);
        ush[row + c] = h;
        usl[row + c] = f2bu(u - us2f(h));
      }
    }
  }
}

// ---------------------------------------------------------------------------
// BN stats per channel over (B, N), fp32 [b][nch][N] input, biased var.
// ---------------------------------------------------------------------------
__global__ __launch_bounds__(256) void k_bnstats(const float* __restrict__ y, int nch,
                                                 float* __restrict__ mean,
                                                 float* __restrict__ rsig) {
  const int c = blockIdx.x, t = threadIdx.x;
  float s = 0.f, s2 = 0.f;
  for (int b = 0; b < kB; ++b) {
    const float* p = y + ((size_t)b * nch + c) * kN;
    for (int n = t; n < kN; n += 256) {
      const float v = p[n];
      s += v;
      s2 += v * v;
    }
  }
  __shared__ float r1[256], r2[256];
  r1[t] = s;
  r2[t] = s2;
  __syncthreads();
  for (int k = 128; k > 0; k >>= 1) {
    if (t < k) {
      r1[t] += r1[t + k];
      r2[t] += r2[t + k];
    }
    __syncthreads();
  }
  if (t == 0) {
    const float im = 1.f / (float)(kB * kN);
    const float m = r1[0] * im;
    const float var = r2[0] * im - m * m;
    mean[c] = m;
    rsig[c] = rsqrtf(var + 1e-5f);
  }
}

// ---------------------------------------------------------------------------
// dc2: tpre[b,j,n] = dc2_b[j] + sum_c dc2_w[j,c] * leaky(bn(h[b,c,n]))
// ---------------------------------------------------------------------------
__global__ __launch_bounds__(256) void k_dc2(const float* __restrict__ h,
                                             const float* __restrict__ mean,
                                             const float* __restrict__ rsig,
                                             const float* __restrict__ g,
                                             const float* __restrict__ bb,
                                             const float* __restrict__ w,
                                             const float* __restrict__ d2b,
                                             float* __restrict__ tpre) {
  __shared__ float wS[3][kC];
  __shared__ float aS[kC], cS[kC];
  const int t = threadIdx.x, b = blockIdx.y;
  const int n = blockIdx.x * 256 + t;
  {
    const float a = g[t] * rsig[t];
    aS[t] = a;
    cS[t] = bb[t] - a * mean[t];
    wS[0][t] = w[t];
    wS[1][t] = w[kC + t];
    wS[2][t] = w[2 * kC + t];
  }
  __syncthreads();
  float a0 = d2b[0], a1 = d2b[1], a2 = d2b[2];
  const float* hb = h + (size_t)b * kC * kN + n;
  for (int c = 0; c < kC; ++c) {
    float z = hb[(size_t)c * kN] * aS[c] + cS[c];
    z = z > 0.f ? z : 0.2f * z;
    a0 += wS[0][c] * z;
    a1 += wS[1][c] * z;
    a2 += wS[2][c] * z;
  }
  tpre[((size_t)b * 3 + 0) * kN + n] = a0;
  tpre[((size_t)b * 3 + 1) * kN + n] = a1;
  tpre[((size_t)b * 3 + 2) * kN + n] = a2;
}

// ---------------------------------------------------------------------------
// Final: out[b,n,j] = tanh(g[j]*(tpre[b,j,n]-mean[j])*rsig[j] + b[j])
// ---------------------------------------------------------------------------
__global__ __launch_bounds__(256) void k_final(const float* __restrict__ tpre,
                                               const float* __restrict__ mean,
                                               const float* __restrict__ rsig,
                                               const float* __restrict__ g,
                                               const float* __restrict__ bb,
                                               float* __restrict__ out) {
  const int i = blockIdx.x * 256 + threadIdx.x;  // over B*N
  const int n = i & (kN - 1), b = i >> 11;
#pragma unroll
  for (int j = 0; j < 3; ++j) {
    const float v = tpre[((size_t)b * 3 + j) * kN + n];
    const float z = g[j] * (v - mean[j]) * rsig[j] + bb[j];
    out[(size_t)i * 3 + j] = tanhf(z);
  }
}

// ---------------------------------------------------------------------------
extern "C" void kernel_launch(void* const* d_in, const int* in_sizes, int n_in,
                              void* d_out, int out_size, void* d_ws, size_t ws_size,
                              hipStream_t stream) {
  const float* feature  = (const float*)d_in[0];
  const float* prior    = (const float*)d_in[1];
  const float* mlp_w    = (const float*)d_in[2];
  const float* mlp_b    = (const float*)d_in[3];
  const float* qk_w     = (const float*)d_in[4];
  const float* qk_b     = (const float*)d_in[5];
  const float* v_w      = (const float*)d_in[6];
  const float* v_b      = (const float*)d_in[7];
  const float* t_w      = (const float*)d_in[8];
  const float* t_b      = (const float*)d_in[9];
  const float* bn_g     = (const float*)d_in[10];
  const float* bn_b     = (const float*)d_in[11];
  const float* dc1_w    = (const float*)d_in[12];
  const float* dc1_bn_g = (const float*)d_in[13];
  const float* dc1_bn_b = (const float*)d_in[14];
  const float* dc2_w    = (const float*)d_in[15];
  const float* dc2_b    = (const float*)d_in[16];
  const float* dc2_bn_g = (const float*)d_in[17];
  const float* dc2_bn_b = (const float*)d_in[18];
  float* out = (float*)d_out;

  // Workspace carve. Total ~125 MiB.
  char* base = (char*)d_ws;
  size_t off = 0;
  auto carve = [&](size_t bytes) {
    char* p = base + off;
    off += (bytes + 255) & ~(size_t)255;
    return p;
  };
  const size_t ne = (size_t)kB * kN * kC;                 // 8,388,608
  ushort_t* psh  = (ushort_t*)carve(ne * 2);              // p hi   16 MiB
  ushort_t* psl  = (ushort_t*)carve(ne * 2);              // p lo   16 MiB
  ushort_t* ush  = (ushort_t*)carve(ne * 2);              // u hi   16 MiB
  ushort_t* usl  = (ushort_t*)carve(ne * 2);              // u lo   16 MiB
  float*    hacc = (float*)carve(ne * 4);                 // dc1    32 MiB
  ushort_t* Qhi  = (ushort_t*)carve((size_t)kB * kN * kH * 2);  // 4 MiB
  ushort_t* Qlo  = (ushort_t*)carve((size_t)kB * kN * kH * 2);  // 4 MiB
  bf16*     Vb   = (bf16*)carve(ne * 2);                  // V      16 MiB
  ushort_t* wfh  = (ushort_t*)carve((size_t)851968 * 2);  // 1.63 MiB
  ushort_t* wfl  = (ushort_t*)carve((size_t)851968 * 2);  // 1.63 MiB
  float*    part = (float*)carve((size_t)2 * 131072 * 4); // 1 MiB
  float*    rmx  = (float*)carve((size_t)kB * kN * 4);
  float*    rsn  = (float*)carve((size_t)kB * kN * 4);
  float*    fb   = (float*)carve((size_t)kB * kC * 4);
  float*    bnm  = (float*)carve(kC * 4);
  float*    bnr  = (float*)carve(kC * 4);
  float*    tpre = (float*)carve((size_t)kB * 3 * kN * 4);

  k_wsplit<<<416, 256, 0, stream>>>(qk_w, v_w, t_w, dc1_w, wfh, wfl);
  k_fb<<<kB * kC, 256, 0, stream>>>(feature, mlp_w, mlp_b, fb);
  k_p0<<<(int)(ne / 256), 256, 0, stream>>>(prior, mlp_w, fb, psh, psl);

  const dim3 gC(kN / 64, kB);
  for (int l = 0; l < 4; ++l) {
    const size_t qk_off  = (size_t)l * 16384;
    const size_t v_off   = 65536 + (size_t)l * 65536;
    const size_t t_off   = 327680 + (size_t)l * 65536;
    const size_t dc1_off = 589824 + (size_t)l * 65536;
    k_qv<<<gC, 256, 0, stream>>>(psh, psl, wfh + qk_off, wfl + qk_off,
                                 wfh + v_off, wfl + v_off,
                                 qk_b + l * kH, v_b + l * kC, Qhi, Qlo, Vb);
    k_rowstats<<<gC, 256, 0, stream>>>(Qhi, Qlo, rmx, rsn);
    k_colpass<<<gC, 256, 0, stream>>>(Qhi, Qlo, Vb, rmx, rsn, psh, psl, ush, usl);
    k_conv<256, 2><<<gC, 256, 0, stream>>>(ush, usl, wfh + t_off, wfl + t_off,
                                           t_b + l * kC, nullptr, nullptr, part,
                                           nullptr, nullptr, nullptr, nullptr, 0);
    k_bnred<<<kC, 128, 0, stream>>>(part, bnm, bnr);
    k_conv<256, 3><<<gC, 256, 0, stream>>>(ush, usl, wfh + t_off, wfl + t_off,
                                           t_b + l * kC, psh, psl, nullptr,
                                           bnm, bnr, bn_g + l * kC, bn_b + l * kC, 0);
    k_conv<256, 4><<<gC, 256, 0, stream>>>(psh, psl, wfh + dc1_off, wfl + dc1_off,
                                           nullptr, nullptr, nullptr, hacc,
                                           nullptr, nullptr, nullptr, nullptr, l == 0 ? 1 : 0);
  }

  k_bnstats<<<kC, 256, 0, stream>>>(hacc, kC, bnm, bnr);
  k_dc2<<<dim3(kN / 256, kB), 256, 0, stream>>>(hacc, bnm, bnr, dc1_bn_g, dc1_bn_b,
                                                dc2_w, dc2_b, tpre);
  k_bnstats<<<3, 256, 0, stream>>>(tpre, 3, bnm, bnr);
  k_final<<<(kB * kN) / 256, 256, 0, stream>>>(tpre, bnm, bnr, dc2_bn_g, dc2_bn_b, out);
}